// Round 1
// baseline (1101.062 us; speedup 1.0000x reference)
//
#include <hip/hip_runtime.h>
#include <math.h>

#define B_   8
#define N_   4096
#define M_   256
#define KNN_ 3

// ---- workspace layout (float element offsets) ----
#define OFF_COUNTS   0          // [8][256]
#define OFF_SUMS     2048       // [8][256][3]
#define OFF_CM       8192       // [8][3][256]
#define OFF_NODEMAX  14336      // [8][256][384]  (float, atomicMax as int)
#define OFF_FIRST0   800768     // [8][384]
#define OFF_FINALIN  803840     // [8][388][256]  (row 387 stays zero)
#define ZERO_COUNT   1598464
#define OFF_KNN      1598464    // int region, [8][4096][3]
#define OFF_WPAD     1696768
// padded-weight sub-offsets (relative to OFF_WPAD)
#define WP_FP0 0        // 64  x 4
#define WP_FP1 256      // 128 x 64
#define WP_FP2 8448     // 256 x 128
#define WP_FP3 41216    // 384 x 260
#define WP_FN0 141056   // 512 x 388
#define WP_FN1 339712   // 512 x 512
#define WP_FN2 601856   // 768 x 512
#define WP_FN3 995072   // 1024 x 1156
// total ws floats = 1696768 + 2178816 = 3,875,584  (~15.5 MB)

__global__ void zero_f(float* __restrict__ p, int n) {
    int i = blockIdx.x * blockDim.x + threadIdx.x;
    int st = gridDim.x * blockDim.x;
    for (; i < n; i += st) p[i] = 0.f;
}

__global__ void pad_w(const float* __restrict__ src, float* __restrict__ dst,
                      int cout, int cin, int cinp) {
    int i = blockIdx.x * blockDim.x + threadIdx.x;
    int st = gridDim.x * blockDim.x;
    int tot = cout * cinp;
    for (; i < tot; i += st) {
        int co = i / cinp, k = i - co * cinp;
        dst[i] = (k < cin) ? src[co * cin + k] : 0.f;
    }
}

// one thread per point: top-3 nearest nodes + atomic counts/sums
__global__ __launch_bounds__(256) void knn_assign(
        const float* __restrict__ x, const float* __restrict__ node,
        int* __restrict__ knn, float* __restrict__ counts, float* __restrict__ sums) {
    __shared__ float nd0[M_], nd1[M_], nd2[M_], nn2[M_];
    int b = blockIdx.y, t = threadIdx.x;
    {
        float c0 = node[(b * 3 + 0) * M_ + t];
        float c1 = node[(b * 3 + 1) * M_ + t];
        float c2 = node[(b * 3 + 2) * M_ + t];
        nd0[t] = c0; nd1[t] = c1; nd2[t] = c2;
        nn2[t] = c0 * c0 + c1 * c1 + c2 * c2;
    }
    __syncthreads();
    int n = blockIdx.x * 256 + t;
    float x0 = x[(b * 3 + 0) * N_ + n];
    float x1 = x[(b * 3 + 1) * N_ + n];
    float x2 = x[(b * 3 + 2) * N_ + n];
    float xx = x0 * x0 + x1 * x1 + x2 * x2;
    float d0 = 1e30f, d1 = 1e30f, d2b = 1e30f;
    int i0 = 0, i1 = 0, i2 = 0;
    for (int m = 0; m < M_; m++) {
        float cross = x0 * nd0[m] + x1 * nd1[m] + x2 * nd2[m];
        float d = xx + nn2[m] - 2.f * cross;
        if (d < d0)       { d2b = d1; i2 = i1; d1 = d0; i1 = i0; d0 = d; i0 = m; }
        else if (d < d1)  { d2b = d1; i2 = i1; d1 = d;  i1 = m; }
        else if (d < d2b) { d2b = d;  i2 = m; }
    }
    int base = (b * N_ + n) * 3;
    knn[base + 0] = i0; knn[base + 1] = i1; knn[base + 2] = i2;
    int mm[3] = {i0, i1, i2};
    #pragma unroll
    for (int k = 0; k < 3; k++) {
        int m = mm[k];
        atomicAdd(&counts[b * M_ + m], 1.f);
        atomicAdd(&sums[(b * M_ + m) * 3 + 0], x0);
        atomicAdd(&sums[(b * M_ + m) * 3 + 1], x1);
        atomicAdd(&sums[(b * M_ + m) * 3 + 2], x2);
    }
}

__global__ void cmean(const float* __restrict__ counts, const float* __restrict__ sums,
                      float* __restrict__ cm) {
    int i = blockIdx.x * 256 + threadIdx.x;
    if (i >= B_ * M_) return;
    int b = i >> 8, m = i & 255;
    float inv = 1.f / (counts[i] + 1e-5f);
    #pragma unroll
    for (int c = 0; c < 3; c++)
        cm[(b * 3 + c) * M_ + m] = sums[i * 3 + c] * inv;
}

// accumulate acc[4co][4p] += Wrow0[i*wstride + k] * in[k*P + p4 + j] over k<cink
template <int P>
__device__ __forceinline__ void gemm_acc(float acc[4][4],
        const float* __restrict__ Wrow0, int wstride, int cink,
        const float* __restrict__ in, int p4) {
    for (int kk = 0; kk < cink; kk += 4) {
        float av[4][4];
        #pragma unroll
        for (int k2 = 0; k2 < 4; k2++)
            *(float4*)av[k2] = *(const float4*)&in[(kk + k2) * P + p4];
        #pragma unroll
        for (int i = 0; i < 4; i++) {
            float wv[4];
            *(float4*)wv = *(const float4*)&Wrow0[i * wstride + kk];
            #pragma unroll
            for (int j = 0; j < 4; j++)
                acc[i][j] += wv[0] * av[0][j] + wv[1] * av[1][j]
                           + wv[2] * av[2][j] + wv[3] * av[3][j];
        }
    }
}

// fused point-MLP: 3->64->128->256->(concat 259)->384, P=32 points/block
__global__ __launch_bounds__(256) void mlp1(
        const float* __restrict__ x, const float* __restrict__ cm,
        const int* __restrict__ knn, const float* __restrict__ wp,
        const float* __restrict__ bb0, const float* __restrict__ bb1,
        const float* __restrict__ bb2, const float* __restrict__ bb3,
        float* __restrict__ node_max, float* __restrict__ first0) {
    __shared__ __align__(16) float xd[4][32];
    __shared__ __align__(16) float a0[64][32];
    __shared__ __align__(16) float a1[128][32];
    __shared__ __align__(16) float a2[256][32];
    __shared__ int midx[32];
    int t = threadIdx.x, tile = blockIdx.x, b = blockIdx.y;
    int j0 = tile * 32;
    if (t < 128) {
        int p = t & 31, c = t >> 5;
        int j = j0 + p, n = j & (N_ - 1), k = j >> 12;
        int m = knn[(b * N_ + n) * 3 + k];
        if (c < 3) xd[c][p] = x[(b * 3 + c) * N_ + n] - cm[(b * 3 + c) * M_ + m];
        else { xd[3][p] = 0.f; midx[p] = m; }
    }
    __syncthreads();
    int p4 = (t & 7) * 4, cg = t >> 3;
    // L1: 64 x 4
    for (int co0 = cg * 4; co0 < 64; co0 += 128) {
        float acc[4][4];
        #pragma unroll
        for (int i = 0; i < 4; i++) { float bv = bb0[co0 + i];
            #pragma unroll
            for (int j = 0; j < 4; j++) acc[i][j] = bv; }
        gemm_acc<32>(acc, wp + WP_FP0 + co0 * 4, 4, 4, &xd[0][0], p4);
        #pragma unroll
        for (int i = 0; i < 4; i++)
            #pragma unroll
            for (int j = 0; j < 4; j++)
                a0[co0 + i][p4 + j] = fmaxf(acc[i][j], 0.f);
    }
    __syncthreads();
    // L2: 128 x 64
    for (int co0 = cg * 4; co0 < 128; co0 += 128) {
        float acc[4][4];
        #pragma unroll
        for (int i = 0; i < 4; i++) { float bv = bb1[co0 + i];
            #pragma unroll
            for (int j = 0; j < 4; j++) acc[i][j] = bv; }
        gemm_acc<32>(acc, wp + WP_FP1 + co0 * 64, 64, 64, &a0[0][0], p4);
        #pragma unroll
        for (int i = 0; i < 4; i++)
            #pragma unroll
            for (int j = 0; j < 4; j++)
                a1[co0 + i][p4 + j] = fmaxf(acc[i][j], 0.f);
    }
    __syncthreads();
    // L3: 256 x 128
    for (int co0 = cg * 4; co0 < 256; co0 += 128) {
        float acc[4][4];
        #pragma unroll
        for (int i = 0; i < 4; i++) { float bv = bb2[co0 + i];
            #pragma unroll
            for (int j = 0; j < 4; j++) acc[i][j] = bv; }
        gemm_acc<32>(acc, wp + WP_FP2 + co0 * 128, 128, 128, &a1[0][0], p4);
        #pragma unroll
        for (int i = 0; i < 4; i++)
            #pragma unroll
            for (int j = 0; j < 4; j++)
                a2[co0 + i][p4 + j] = fmaxf(acc[i][j], 0.f);
    }
    __syncthreads();
    // L4: 384 x 260 = [a2 | xd], fused segment-max
    for (int co0 = cg * 4; co0 < 384; co0 += 128) {
        float acc[4][4];
        #pragma unroll
        for (int i = 0; i < 4; i++) { float bv = bb3[co0 + i];
            #pragma unroll
            for (int j = 0; j < 4; j++) acc[i][j] = bv; }
        gemm_acc<32>(acc, wp + WP_FP3 + co0 * 260,       260, 256, &a2[0][0], p4);
        gemm_acc<32>(acc, wp + WP_FP3 + co0 * 260 + 256, 260, 4,   &xd[0][0], p4);
        #pragma unroll
        for (int i = 0; i < 4; i++) {
            #pragma unroll
            for (int j = 0; j < 4; j++) {
                float v = fmaxf(acc[i][j], 0.f);
                int m = midx[p4 + j];
                atomicMax((int*)&node_max[((size_t)(b * M_ + m)) * 384 + co0 + i],
                          __float_as_int(v));
                if (tile == 0 && (p4 + j) == 0) first0[b * 384 + co0 + i] = v;
            }
        }
    }
}

__global__ void build_fin(const float* __restrict__ cm, const float* __restrict__ counts,
                          const float* __restrict__ nmax, const float* __restrict__ first0,
                          float* __restrict__ fin) {
    int tot = B_ * 387 * M_;
    int i = blockIdx.x * blockDim.x + threadIdx.x;
    int st = gridDim.x * blockDim.x;
    for (; i < tot; i += st) {
        int b = i / (387 * M_), r = i % (387 * M_);
        int ch = r / M_, m = r % M_;
        float v;
        if (ch < 3) v = cm[(b * 3 + ch) * M_ + m];
        else {
            v = (counts[b * M_ + m] > 0.f) ? nmax[((size_t)(b * M_ + m)) * 384 + (ch - 3)]
                                           : first0[b * 384 + (ch - 3)];
        }
        fin[(b * 388 + ch) * M_ + m] = v;
    }
}

// fused node-MLP: 387->512->512->768->(concat 1155)->1024, P=8 nodes/block
__global__ __launch_bounds__(256) void mlp2(
        const float* __restrict__ fin_g, const float* __restrict__ wp,
        const float* __restrict__ bb0, const float* __restrict__ bb1,
        const float* __restrict__ bb2, const float* __restrict__ bb3,
        float* __restrict__ out) {
    __shared__ __align__(16) float fin[388][8];
    __shared__ __align__(16) float bufA[768][8];
    __shared__ __align__(16) float bufB[768][8];
    int t = threadIdx.x, b = blockIdx.y;
    int m0 = blockIdx.x * 8;
    for (int e = t; e < 388 * 8; e += 256) {
        int ch = e >> 3, p = e & 7;
        (&fin[0][0])[e] = fin_g[(b * 388 + ch) * M_ + m0 + p];
    }
    __syncthreads();
    int p4 = (t & 1) * 4, cg = t >> 1;
    // L1: 512 x 388 (fin -> bufA)
    for (int co0 = cg * 4; co0 < 512; co0 += 512) {
        float acc[4][4];
        #pragma unroll
        for (int i = 0; i < 4; i++) { float bv = bb0[co0 + i];
            #pragma unroll
            for (int j = 0; j < 4; j++) acc[i][j] = bv; }
        gemm_acc<8>(acc, wp + WP_FN0 + co0 * 388, 388, 388, &fin[0][0], p4);
        #pragma unroll
        for (int i = 0; i < 4; i++)
            #pragma unroll
            for (int j = 0; j < 4; j++)
                bufA[co0 + i][p4 + j] = fmaxf(acc[i][j], 0.f);
    }
    __syncthreads();
    // L2: 512 x 512 (bufA -> bufB)
    for (int co0 = cg * 4; co0 < 512; co0 += 512) {
        float acc[4][4];
        #pragma unroll
        for (int i = 0; i < 4; i++) { float bv = bb1[co0 + i];
            #pragma unroll
            for (int j = 0; j < 4; j++) acc[i][j] = bv; }
        gemm_acc<8>(acc, wp + WP_FN1 + co0 * 512, 512, 512, &bufA[0][0], p4);
        #pragma unroll
        for (int i = 0; i < 4; i++)
            #pragma unroll
            for (int j = 0; j < 4; j++)
                bufB[co0 + i][p4 + j] = fmaxf(acc[i][j], 0.f);
    }
    __syncthreads();
    // L3: 768 x 512 (bufB -> bufA)
    for (int co0 = cg * 4; co0 < 768; co0 += 512) {
        float acc[4][4];
        #pragma unroll
        for (int i = 0; i < 4; i++) { float bv = bb2[co0 + i];
            #pragma unroll
            for (int j = 0; j < 4; j++) acc[i][j] = bv; }
        gemm_acc<8>(acc, wp + WP_FN2 + co0 * 512, 512, 512, &bufB[0][0], p4);
        #pragma unroll
        for (int i = 0; i < 4; i++)
            #pragma unroll
            for (int j = 0; j < 4; j++)
                bufA[co0 + i][p4 + j] = fmaxf(acc[i][j], 0.f);
    }
    __syncthreads();
    // L4: 1024 x 1156 = [bufA(768) | fin(388)], fused global max over nodes
    for (int co0 = cg * 4; co0 < 1024; co0 += 512) {
        float acc[4][4];
        #pragma unroll
        for (int i = 0; i < 4; i++) { float bv = bb3[co0 + i];
            #pragma unroll
            for (int j = 0; j < 4; j++) acc[i][j] = bv; }
        gemm_acc<8>(acc, wp + WP_FN3 + co0 * 1156,       1156, 768, &bufA[0][0], p4);
        gemm_acc<8>(acc, wp + WP_FN3 + co0 * 1156 + 768, 1156, 388, &fin[0][0],  p4);
        #pragma unroll
        for (int i = 0; i < 4; i++) {
            float mx = 0.f;
            #pragma unroll
            for (int j = 0; j < 4; j++) mx = fmaxf(mx, acc[i][j]);
            atomicMax((int*)&out[b * 1024 + co0 + i], __float_as_int(mx));
        }
    }
}

extern "C" void kernel_launch(void* const* d_in, const int* in_sizes, int n_in,
                              void* d_out, int out_size, void* d_ws, size_t ws_size,
                              hipStream_t stream) {
    (void)in_sizes; (void)n_in; (void)out_size; (void)ws_size;
    const float* x    = (const float*)d_in[0];
    const float* node = (const float*)d_in[2];
    const float* fpw[4] = {(const float*)d_in[4], (const float*)d_in[6],
                           (const float*)d_in[8], (const float*)d_in[10]};
    const float* fpb[4] = {(const float*)d_in[5], (const float*)d_in[7],
                           (const float*)d_in[9], (const float*)d_in[11]};
    const float* fnw[4] = {(const float*)d_in[12], (const float*)d_in[14],
                           (const float*)d_in[16], (const float*)d_in[18]};
    const float* fnb[4] = {(const float*)d_in[13], (const float*)d_in[15],
                           (const float*)d_in[17], (const float*)d_in[19]};
    float* ws  = (float*)d_ws;
    float* out = (float*)d_out;
    float* wp  = ws + OFF_WPAD;

    zero_f<<<2048, 256, 0, stream>>>(ws, ZERO_COUNT);
    zero_f<<<32, 256, 0, stream>>>(out, B_ * 1024);

    pad_w<<<8,   256, 0, stream>>>(fpw[0], wp + WP_FP0,   64,    3,    4);
    pad_w<<<32,  256, 0, stream>>>(fpw[1], wp + WP_FP1,  128,   64,   64);
    pad_w<<<128, 256, 0, stream>>>(fpw[2], wp + WP_FP2,  256,  128,  128);
    pad_w<<<256, 256, 0, stream>>>(fpw[3], wp + WP_FP3,  384,  259,  260);
    pad_w<<<512, 256, 0, stream>>>(fnw[0], wp + WP_FN0,  512,  387,  388);
    pad_w<<<512, 256, 0, stream>>>(fnw[1], wp + WP_FN1,  512,  512,  512);
    pad_w<<<768, 256, 0, stream>>>(fnw[2], wp + WP_FN2,  768,  512,  512);
    pad_w<<<2048,256, 0, stream>>>(fnw[3], wp + WP_FN3, 1024, 1155, 1156);

    knn_assign<<<dim3(N_ / 256, B_), 256, 0, stream>>>(
        x, node, (int*)(ws + OFF_KNN), ws + OFF_COUNTS, ws + OFF_SUMS);
    cmean<<<(B_ * M_ + 255) / 256, 256, 0, stream>>>(
        ws + OFF_COUNTS, ws + OFF_SUMS, ws + OFF_CM);
    mlp1<<<dim3(KNN_ * N_ / 32, B_), 256, 0, stream>>>(
        x, ws + OFF_CM, (int*)(ws + OFF_KNN), wp,
        fpb[0], fpb[1], fpb[2], fpb[3], ws + OFF_NODEMAX, ws + OFF_FIRST0);
    build_fin<<<1024, 256, 0, stream>>>(
        ws + OFF_CM, ws + OFF_COUNTS, ws + OFF_NODEMAX, ws + OFF_FIRST0, ws + OFF_FINALIN);
    mlp2<<<dim3(M_ / 8, B_), 256, 0, stream>>>(
        ws + OFF_FINALIN, wp, fnb[0], fnb[1], fnb[2], fnb[3], out);
}

// Round 2
// 952.820 us; speedup vs baseline: 1.1556x; 1.1556x over previous
//
#include <hip/hip_runtime.h>
#include <math.h>

#define B_   8
#define N_   4096
#define M_   256
#define KNN_ 3

// ---- workspace layout (float element offsets) ----
#define OFF_COUNTS   0          // [8][256] float
#define OFF_SUMS     2048       // [8][256][3] float
#define OFF_CM       8192       // [8][3][256] float
#define OFF_NODEMAX  14336      // [8][256][384] float (atomicMax as int)
#define OFF_FIRST0   800768     // [8][384]
#define OFF_FINALIN  803840     // [8][388][256] (row 387 stays zero)
#define OFF_CURSOR   1598464    // [8][256] int (scatter cursors)
#define ZERO_COUNT   1600512
#define OFF_OFFS     1600512    // [8][257] int (segment offsets)
#define OFF_KNN      1602568    // [8][4096][3] int
#define OFF_SORTED   1700872    // [8][12288] int (sorted stacked idx j)
#define OFF_MSORT    1799176    // [8][12288] int (segment id per sorted entry)
#define OFF_WPAD     1897480    // padded weights (16B aligned)
// padded-weight sub-offsets (relative to OFF_WPAD)
#define WP_FP0 0        // 64  x 4
#define WP_FP1 256      // 128 x 64
#define WP_FP2 8448     // 256 x 128
#define WP_FP3 41216    // 384 x 260
#define WP_FN0 141056   // 512 x 388
#define WP_FN1 339712   // 512 x 512
#define WP_FN2 601856   // 768 x 512
#define WP_FN3 995072   // 1024 x 1156
// total ws floats = 1897480 + 2178816 = 4,076,296 (~16.3 MB)

__global__ void zero_f(float* __restrict__ p, int n) {
    int i = blockIdx.x * blockDim.x + threadIdx.x;
    int st = gridDim.x * blockDim.x;
    for (; i < n; i += st) p[i] = 0.f;
}

__global__ void pad_w(const float* __restrict__ src, float* __restrict__ dst,
                      int cout, int cin, int cinp) {
    int i = blockIdx.x * blockDim.x + threadIdx.x;
    int st = gridDim.x * blockDim.x;
    int tot = cout * cinp;
    for (; i < tot; i += st) {
        int co = i / cinp, k = i - co * cinp;
        dst[i] = (k < cin) ? src[co * cin + k] : 0.f;
    }
}

// one thread per point: top-3 nearest nodes + atomic counts/sums
__global__ __launch_bounds__(256) void knn_assign(
        const float* __restrict__ x, const float* __restrict__ node,
        int* __restrict__ knn, float* __restrict__ counts, float* __restrict__ sums) {
    __shared__ float nd0[M_], nd1[M_], nd2[M_], nn2[M_];
    int b = blockIdx.y, t = threadIdx.x;
    {
        float c0 = node[(b * 3 + 0) * M_ + t];
        float c1 = node[(b * 3 + 1) * M_ + t];
        float c2 = node[(b * 3 + 2) * M_ + t];
        nd0[t] = c0; nd1[t] = c1; nd2[t] = c2;
        nn2[t] = c0 * c0 + c1 * c1 + c2 * c2;
    }
    __syncthreads();
    int n = blockIdx.x * 256 + t;
    float x0 = x[(b * 3 + 0) * N_ + n];
    float x1 = x[(b * 3 + 1) * N_ + n];
    float x2 = x[(b * 3 + 2) * N_ + n];
    float xx = x0 * x0 + x1 * x1 + x2 * x2;
    float d0 = 1e30f, d1 = 1e30f, d2b = 1e30f;
    int i0 = 0, i1 = 0, i2 = 0;
    for (int m = 0; m < M_; m++) {
        float cross = x0 * nd0[m] + x1 * nd1[m] + x2 * nd2[m];
        float d = xx + nn2[m] - 2.f * cross;
        if (d < d0)       { d2b = d1; i2 = i1; d1 = d0; i1 = i0; d0 = d; i0 = m; }
        else if (d < d1)  { d2b = d1; i2 = i1; d1 = d;  i1 = m; }
        else if (d < d2b) { d2b = d;  i2 = m; }
    }
    int base = (b * N_ + n) * 3;
    knn[base + 0] = i0; knn[base + 1] = i1; knn[base + 2] = i2;
    int mm[3] = {i0, i1, i2};
    #pragma unroll
    for (int k = 0; k < 3; k++) {
        int m = mm[k];
        atomicAdd(&counts[b * M_ + m], 1.f);
        atomicAdd(&sums[(b * M_ + m) * 3 + 0], x0);
        atomicAdd(&sums[(b * M_ + m) * 3 + 1], x1);
        atomicAdd(&sums[(b * M_ + m) * 3 + 2], x2);
    }
}

__global__ void cmean(const float* __restrict__ counts, const float* __restrict__ sums,
                      float* __restrict__ cm) {
    int i = blockIdx.x * 256 + threadIdx.x;
    if (i >= B_ * M_) return;
    int b = i >> 8, m = i & 255;
    float inv = 1.f / (counts[i] + 1e-5f);
    #pragma unroll
    for (int c = 0; c < 3; c++)
        cm[(b * 3 + c) * M_ + m] = sums[i * 3 + c] * inv;
}

// exclusive prefix sum of counts -> offs [8][257]
__global__ __launch_bounds__(256) void scan_offs(const float* __restrict__ counts,
                                                 int* __restrict__ offs) {
    __shared__ int tmp[256];
    int t = threadIdx.x;
    for (int b = 0; b < B_; b++) {
        int v = (int)counts[b * M_ + t];
        tmp[t] = v;
        __syncthreads();
        for (int off = 1; off < 256; off <<= 1) {
            int u = (t >= off) ? tmp[t - off] : 0;
            __syncthreads();
            tmp[t] += u;
            __syncthreads();
        }
        offs[b * 257 + t] = tmp[t] - v;
        if (t == 255) offs[b * 257 + 256] = tmp[255];
        __syncthreads();
    }
}

// counting-sort scatter: sorted[b][pos] = stacked idx j, msort[b][pos] = m
__global__ __launch_bounds__(256) void scatter(const int* __restrict__ knn,
        const int* __restrict__ offs, int* __restrict__ cursor,
        int* __restrict__ sorted, int* __restrict__ msort) {
    int g = blockIdx.x * 256 + threadIdx.x;
    int b = g / (KNN_ * N_), j = g % (KNN_ * N_);
    int n = j & (N_ - 1), k = j >> 12;
    int m = knn[(b * N_ + n) * 3 + k];
    int pos = atomicAdd(&cursor[b * M_ + m], 1);
    int dst = offs[b * 257 + m] + pos;
    sorted[b * (KNN_ * N_) + dst] = j;
    msort[b * (KNN_ * N_) + dst] = m;
}

// accumulate acc[4co][4p] += Wrow0[i*wstride + k] * in[k*P + p4 + j] over k<cink
template <int P>
__device__ __forceinline__ void gemm_acc(float acc[4][4],
        const float* __restrict__ Wrow0, int wstride, int cink,
        const float* __restrict__ in, int p4) {
    for (int kk = 0; kk < cink; kk += 4) {
        float av[4][4];
        #pragma unroll
        for (int k2 = 0; k2 < 4; k2++)
            *(float4*)av[k2] = *(const float4*)&in[(kk + k2) * P + p4];
        #pragma unroll
        for (int i = 0; i < 4; i++) {
            float wv[4];
            *(float4*)wv = *(const float4*)&Wrow0[i * wstride + kk];
            #pragma unroll
            for (int j = 0; j < 4; j++)
                acc[i][j] += wv[0] * av[0][j] + wv[1] * av[1][j]
                           + wv[2] * av[2][j] + wv[3] * av[3][j];
        }
    }
}

// fused point-MLP over SORTED entries: 3->64->128->256->(concat 259)->384,
// P=32 points/block, per-block LDS segment-max, one atomic per (segment,channel).
__global__ __launch_bounds__(256) void mlp1s(
        const float* __restrict__ x, const float* __restrict__ cm,
        const int* __restrict__ sorted, const int* __restrict__ msort,
        const float* __restrict__ wp,
        const float* __restrict__ bb0, const float* __restrict__ bb1,
        const float* __restrict__ bb2, const float* __restrict__ bb3,
        float* __restrict__ node_max, float* __restrict__ first0) {
    __shared__ __align__(16) float xd[4][32];
    __shared__ __align__(16) float a2s[256][32];
    __shared__ __align__(16) float lo[6144];   // a0[64][32] + a1[128][32]; L4: out[128][33]
    __shared__ int midx[32], segm[33], segstart[34];
    __shared__ int nseg, p0loc;
    int t = threadIdx.x, b = blockIdx.y;
    int e0 = blockIdx.x * 32;
    if (t == 0) p0loc = -1;
    __syncthreads();
    if (t < 128) {
        int p = t & 31, c = t >> 5;
        int j = sorted[b * (KNN_ * N_) + e0 + p];
        int m = msort[b * (KNN_ * N_) + e0 + p];
        int n = j & (N_ - 1);
        if (c < 3) xd[c][p] = x[(b * 3 + c) * N_ + n] - cm[(b * 3 + c) * M_ + m];
        else { xd[3][p] = 0.f; midx[p] = m; if (j == 0) p0loc = p; }
    }
    __syncthreads();
    if (t == 0) {
        int ns = 0;
        for (int p = 0; p < 32; p++) {
            if (p == 0 || midx[p] != midx[p - 1]) { segstart[ns] = p; segm[ns] = midx[p]; ns++; }
        }
        segstart[ns] = 32; nseg = ns;
    }
    int p4 = (t & 7) * 4, cg = t >> 3;
    float* a0 = lo;           // [64][32]
    float* a1 = lo + 2048;    // [128][32]
    // L1: 64 x 4
    for (int co0 = cg * 4; co0 < 64; co0 += 128) {
        float acc[4][4];
        #pragma unroll
        for (int i = 0; i < 4; i++) { float bv = bb0[co0 + i];
            #pragma unroll
            for (int j = 0; j < 4; j++) acc[i][j] = bv; }
        gemm_acc<32>(acc, wp + WP_FP0 + co0 * 4, 4, 4, &xd[0][0], p4);
        #pragma unroll
        for (int i = 0; i < 4; i++)
            #pragma unroll
            for (int j = 0; j < 4; j++)
                a0[(co0 + i) * 32 + p4 + j] = fmaxf(acc[i][j], 0.f);
    }
    __syncthreads();
    // L2: 128 x 64
    {
        int co0 = cg * 4;
        float acc[4][4];
        #pragma unroll
        for (int i = 0; i < 4; i++) { float bv = bb1[co0 + i];
            #pragma unroll
            for (int j = 0; j < 4; j++) acc[i][j] = bv; }
        gemm_acc<32>(acc, wp + WP_FP1 + co0 * 64, 64, 64, a0, p4);
        __syncthreads();   // a0 reads done before a1 writes (a1 disjoint, but keep order safe)
        #pragma unroll
        for (int i = 0; i < 4; i++)
            #pragma unroll
            for (int j = 0; j < 4; j++)
                a1[(co0 + i) * 32 + p4 + j] = fmaxf(acc[i][j], 0.f);
    }
    __syncthreads();
    // L3: 256 x 128
    for (int co0 = cg * 4; co0 < 256; co0 += 128) {
        float acc[4][4];
        #pragma unroll
        for (int i = 0; i < 4; i++) { float bv = bb2[co0 + i];
            #pragma unroll
            for (int j = 0; j < 4; j++) acc[i][j] = bv; }
        gemm_acc<32>(acc, wp + WP_FP2 + co0 * 128, 128, 128, a1, p4);
        #pragma unroll
        for (int i = 0; i < 4; i++)
            #pragma unroll
            for (int j = 0; j < 4; j++)
                a2s[co0 + i][p4 + j] = fmaxf(acc[i][j], 0.f);
    }
    __syncthreads();
    // L4: 384 x 260 = [a2 | xd], 3 passes of 128 channels; LDS segment-max
    for (int pass = 0; pass < 3; pass++) {
        int co = pass * 128 + cg * 4;
        float acc[4][4];
        #pragma unroll
        for (int i = 0; i < 4; i++) { float bv = bb3[co + i];
            #pragma unroll
            for (int j = 0; j < 4; j++) acc[i][j] = bv; }
        gemm_acc<32>(acc, wp + WP_FP3 + co * 260,       260, 256, &a2s[0][0], p4);
        gemm_acc<32>(acc, wp + WP_FP3 + co * 260 + 256, 260, 4,   &xd[0][0],  p4);
        #pragma unroll
        for (int i = 0; i < 4; i++)
            #pragma unroll
            for (int j = 0; j < 4; j++)
                lo[(cg * 4 + i) * 33 + p4 + j] = fmaxf(acc[i][j], 0.f);
        __syncthreads();
        int c = t & 127, half = t >> 7;
        int cog = pass * 128 + c;
        if (half == 0 && p0loc >= 0)
            first0[b * 384 + cog] = lo[c * 33 + p0loc];
        for (int s = half; s < nseg; s += 2) {
            float mx = 0.f;
            for (int p = segstart[s]; p < segstart[s + 1]; p++)
                mx = fmaxf(mx, lo[c * 33 + p]);
            atomicMax((int*)&node_max[(size_t)(b * M_ + segm[s]) * 384 + cog],
                      __float_as_int(mx));
        }
        __syncthreads();
    }
}

__global__ void build_fin(const float* __restrict__ cm, const float* __restrict__ counts,
                          const float* __restrict__ nmax, const float* __restrict__ first0,
                          float* __restrict__ fin) {
    int tot = B_ * 387 * M_;
    int i = blockIdx.x * blockDim.x + threadIdx.x;
    int st = gridDim.x * blockDim.x;
    for (; i < tot; i += st) {
        int b = i / (387 * M_), r = i % (387 * M_);
        int ch = r / M_, m = r % M_;
        float v;
        if (ch < 3) v = cm[(b * 3 + ch) * M_ + m];
        else {
            v = (counts[b * M_ + m] > 0.f) ? nmax[((size_t)(b * M_ + m)) * 384 + (ch - 3)]
                                           : first0[b * 384 + (ch - 3)];
        }
        fin[(b * 388 + ch) * M_ + m] = v;
    }
}

// fused node-MLP: 387->512->512->768->(concat 1155)->1024, P=8 nodes/block
__global__ __launch_bounds__(256) void mlp2(
        const float* __restrict__ fin_g, const float* __restrict__ wp,
        const float* __restrict__ bb0, const float* __restrict__ bb1,
        const float* __restrict__ bb2, const float* __restrict__ bb3,
        float* __restrict__ out) {
    __shared__ __align__(16) float fin[388][8];
    __shared__ __align__(16) float bufA[768][8];
    __shared__ __align__(16) float bufB[768][8];
    int t = threadIdx.x, b = blockIdx.y;
    int m0 = blockIdx.x * 8;
    for (int e = t; e < 388 * 8; e += 256) {
        int ch = e >> 3, p = e & 7;
        (&fin[0][0])[e] = fin_g[(b * 388 + ch) * M_ + m0 + p];
    }
    __syncthreads();
    int p4 = (t & 1) * 4, cg = t >> 1;
    // L1: 512 x 388 (fin -> bufA)
    {
        int co0 = cg * 4;
        float acc[4][4];
        #pragma unroll
        for (int i = 0; i < 4; i++) { float bv = bb0[co0 + i];
            #pragma unroll
            for (int j = 0; j < 4; j++) acc[i][j] = bv; }
        gemm_acc<8>(acc, wp + WP_FN0 + co0 * 388, 388, 388, &fin[0][0], p4);
        #pragma unroll
        for (int i = 0; i < 4; i++)
            #pragma unroll
            for (int j = 0; j < 4; j++)
                bufA[co0 + i][p4 + j] = fmaxf(acc[i][j], 0.f);
    }
    __syncthreads();
    // L2: 512 x 512 (bufA -> bufB)
    {
        int co0 = cg * 4;
        float acc[4][4];
        #pragma unroll
        for (int i = 0; i < 4; i++) { float bv = bb1[co0 + i];
            #pragma unroll
            for (int j = 0; j < 4; j++) acc[i][j] = bv; }
        gemm_acc<8>(acc, wp + WP_FN1 + co0 * 512, 512, 512, &bufA[0][0], p4);
        #pragma unroll
        for (int i = 0; i < 4; i++)
            #pragma unroll
            for (int j = 0; j < 4; j++)
                bufB[co0 + i][p4 + j] = fmaxf(acc[i][j], 0.f);
    }
    __syncthreads();
    // L3: 768 x 512 (bufB -> bufA)
    for (int co0 = cg * 4; co0 < 768; co0 += 512) {
        float acc[4][4];
        #pragma unroll
        for (int i = 0; i < 4; i++) { float bv = bb2[co0 + i];
            #pragma unroll
            for (int j = 0; j < 4; j++) acc[i][j] = bv; }
        gemm_acc<8>(acc, wp + WP_FN2 + co0 * 512, 512, 512, &bufB[0][0], p4);
        #pragma unroll
        for (int i = 0; i < 4; i++)
            #pragma unroll
            for (int j = 0; j < 4; j++)
                bufA[co0 + i][p4 + j] = fmaxf(acc[i][j], 0.f);
    }
    __syncthreads();
    // L4: 1024 x 1156 = [bufA(768) | fin(388)], fused global max over nodes
    for (int co0 = cg * 4; co0 < 1024; co0 += 512) {
        float acc[4][4];
        #pragma unroll
        for (int i = 0; i < 4; i++) { float bv = bb3[co0 + i];
            #pragma unroll
            for (int j = 0; j < 4; j++) acc[i][j] = bv; }
        gemm_acc<8>(acc, wp + WP_FN3 + co0 * 1156,       1156, 768, &bufA[0][0], p4);
        gemm_acc<8>(acc, wp + WP_FN3 + co0 * 1156 + 768, 1156, 388, &fin[0][0],  p4);
        #pragma unroll
        for (int i = 0; i < 4; i++) {
            float mx = 0.f;
            #pragma unroll
            for (int j = 0; j < 4; j++) mx = fmaxf(mx, acc[i][j]);
            atomicMax((int*)&out[b * 1024 + co0 + i], __float_as_int(mx));
        }
    }
}

extern "C" void kernel_launch(void* const* d_in, const int* in_sizes, int n_in,
                              void* d_out, int out_size, void* d_ws, size_t ws_size,
                              hipStream_t stream) {
    (void)in_sizes; (void)n_in; (void)out_size; (void)ws_size;
    const float* x    = (const float*)d_in[0];
    const float* node = (const float*)d_in[2];
    const float* fpw[4] = {(const float*)d_in[4], (const float*)d_in[6],
                           (const float*)d_in[8], (const float*)d_in[10]};
    const float* fpb[4] = {(const float*)d_in[5], (const float*)d_in[7],
                           (const float*)d_in[9], (const float*)d_in[11]};
    const float* fnw[4] = {(const float*)d_in[12], (const float*)d_in[14],
                           (const float*)d_in[16], (const float*)d_in[18]};
    const float* fnb[4] = {(const float*)d_in[13], (const float*)d_in[15],
                           (const float*)d_in[17], (const float*)d_in[19]};
    float* ws  = (float*)d_ws;
    float* out = (float*)d_out;
    float* wp  = ws + OFF_WPAD;

    zero_f<<<2048, 256, 0, stream>>>(ws, ZERO_COUNT);
    zero_f<<<32, 256, 0, stream>>>(out, B_ * 1024);

    pad_w<<<8,   256, 0, stream>>>(fpw[0], wp + WP_FP0,   64,    3,    4);
    pad_w<<<32,  256, 0, stream>>>(fpw[1], wp + WP_FP1,  128,   64,   64);
    pad_w<<<128, 256, 0, stream>>>(fpw[2], wp + WP_FP2,  256,  128,  128);
    pad_w<<<256, 256, 0, stream>>>(fpw[3], wp + WP_FP3,  384,  259,  260);
    pad_w<<<512, 256, 0, stream>>>(fnw[0], wp + WP_FN0,  512,  387,  388);
    pad_w<<<512, 256, 0, stream>>>(fnw[1], wp + WP_FN1,  512,  512,  512);
    pad_w<<<768, 256, 0, stream>>>(fnw[2], wp + WP_FN2,  768,  512,  512);
    pad_w<<<2048,256, 0, stream>>>(fnw[3], wp + WP_FN3, 1024, 1155, 1156);

    knn_assign<<<dim3(N_ / 256, B_), 256, 0, stream>>>(
        x, node, (int*)(ws + OFF_KNN), ws + OFF_COUNTS, ws + OFF_SUMS);
    cmean<<<(B_ * M_ + 255) / 256, 256, 0, stream>>>(
        ws + OFF_COUNTS, ws + OFF_SUMS, ws + OFF_CM);
    scan_offs<<<1, 256, 0, stream>>>(ws + OFF_COUNTS, (int*)(ws + OFF_OFFS));
    scatter<<<B_ * KNN_ * N_ / 256, 256, 0, stream>>>(
        (int*)(ws + OFF_KNN), (int*)(ws + OFF_OFFS), (int*)(ws + OFF_CURSOR),
        (int*)(ws + OFF_SORTED), (int*)(ws + OFF_MSORT));
    mlp1s<<<dim3(KNN_ * N_ / 32, B_), 256, 0, stream>>>(
        x, ws + OFF_CM, (int*)(ws + OFF_SORTED), (int*)(ws + OFF_MSORT), wp,
        fpb[0], fpb[1], fpb[2], fpb[3], ws + OFF_NODEMAX, ws + OFF_FIRST0);
    build_fin<<<1024, 256, 0, stream>>>(
        ws + OFF_CM, ws + OFF_COUNTS, ws + OFF_NODEMAX, ws + OFF_FIRST0, ws + OFF_FINALIN);
    mlp2<<<dim3(M_ / 8, B_), 256, 0, stream>>>(
        ws + OFF_FINALIN, wp, fnb[0], fnb[1], fnb[2], fnb[3], out);
}

// Round 3
// 455.150 us; speedup vs baseline: 2.4191x; 2.0934x over previous
//
#include <hip/hip_runtime.h>
#include <math.h>

#define B_   8
#define N_   4096
#define M_   256
#define KNN_ 3

// ---- workspace layout (float element offsets) ----
#define OFF_COUNTS   0          // [8][256] float
#define OFF_SUMS     2048       // [8][256][3] float
#define OFF_CM       8192       // [8][3][256] float
#define OFF_NODEMAX  14336      // [8][256][384] float (atomicMax as int)
#define OFF_FIRST0   800768     // [8][384]
#define OFF_FINALIN  803840     // [8][388][256] (row 387 stays zero)
#define OFF_CURSOR   1598464    // [8][256] int
#define ZERO_COUNT   1600512
#define OFF_OFFS     1600512    // [8][257] int
#define OFF_KNN      1602568    // [8][4096][3] int
#define OFF_SORTED   1700872    // [8][12288] int
#define OFF_MSORT    1799176    // [8][12288] int
#define OFF_WBF      1897480    // bf16 weights region (ushort*), 16B aligned
// bf16 padded weight offsets (USHORT units, relative to wb base)
#define O_W0 0         // 64   x 32
#define O_W1 2048      // 128  x 64
#define O_W2 10240     // 256  x 128
#define O_W3 43008     // 384  x 288
#define O_V0 153600    // 512  x 416
#define O_V1 366592    // 512  x 512
#define O_V2 628736    // 768  x 512
#define O_V3 1021952   // 1024 x 1184
// end: 2234368 ushorts = 1117184 floats; ws total ~12.1 MB

typedef short  bf16x8 __attribute__((ext_vector_type(8)));
typedef float  f32x4  __attribute__((ext_vector_type(4)));

__device__ __forceinline__ unsigned short f2b(float f) {
    unsigned u = __float_as_uint(f);
    return (unsigned short)((u + 0x7FFFu + ((u >> 16) & 1u)) >> 16);
}

__global__ void zero_f(float* __restrict__ p, int n) {
    int i = blockIdx.x * blockDim.x + threadIdx.x;
    int st = gridDim.x * blockDim.x;
    for (; i < n; i += st) p[i] = 0.f;
}

__global__ void pad_w_bf16(const float* __restrict__ src, unsigned short* __restrict__ dst,
                           int cout, int cin, int cinp) {
    int i = blockIdx.x * blockDim.x + threadIdx.x;
    int st = gridDim.x * blockDim.x;
    int tot = cout * cinp;
    for (; i < tot; i += st) {
        int co = i / cinp, k = i - co * cinp;
        dst[i] = (k < cin) ? f2b(src[co * cin + k]) : (unsigned short)0;
    }
}

// one thread per point: top-3 nearest nodes + atomic counts/sums
__global__ __launch_bounds__(256) void knn_assign(
        const float* __restrict__ x, const float* __restrict__ node,
        int* __restrict__ knn, float* __restrict__ counts, float* __restrict__ sums) {
    __shared__ float nd0[M_], nd1[M_], nd2[M_], nn2[M_];
    int b = blockIdx.y, t = threadIdx.x;
    {
        float c0 = node[(b * 3 + 0) * M_ + t];
        float c1 = node[(b * 3 + 1) * M_ + t];
        float c2 = node[(b * 3 + 2) * M_ + t];
        nd0[t] = c0; nd1[t] = c1; nd2[t] = c2;
        nn2[t] = c0 * c0 + c1 * c1 + c2 * c2;
    }
    __syncthreads();
    int n = blockIdx.x * 256 + t;
    float x0 = x[(b * 3 + 0) * N_ + n];
    float x1 = x[(b * 3 + 1) * N_ + n];
    float x2 = x[(b * 3 + 2) * N_ + n];
    float xx = x0 * x0 + x1 * x1 + x2 * x2;
    float d0 = 1e30f, d1 = 1e30f, d2b = 1e30f;
    int i0 = 0, i1 = 0, i2 = 0;
    for (int m = 0; m < M_; m++) {
        float cross = x0 * nd0[m] + x1 * nd1[m] + x2 * nd2[m];
        float d = xx + nn2[m] - 2.f * cross;
        if (d < d0)       { d2b = d1; i2 = i1; d1 = d0; i1 = i0; d0 = d; i0 = m; }
        else if (d < d1)  { d2b = d1; i2 = i1; d1 = d;  i1 = m; }
        else if (d < d2b) { d2b = d;  i2 = m; }
    }
    int base = (b * N_ + n) * 3;
    knn[base + 0] = i0; knn[base + 1] = i1; knn[base + 2] = i2;
    int mm[3] = {i0, i1, i2};
    #pragma unroll
    for (int k = 0; k < 3; k++) {
        int m = mm[k];
        atomicAdd(&counts[b * M_ + m], 1.f);
        atomicAdd(&sums[(b * M_ + m) * 3 + 0], x0);
        atomicAdd(&sums[(b * M_ + m) * 3 + 1], x1);
        atomicAdd(&sums[(b * M_ + m) * 3 + 2], x2);
    }
}

__global__ void cmean(const float* __restrict__ counts, const float* __restrict__ sums,
                      float* __restrict__ cm) {
    int i = blockIdx.x * 256 + threadIdx.x;
    if (i >= B_ * M_) return;
    int b = i >> 8, m = i & 255;
    float inv = 1.f / (counts[i] + 1e-5f);
    #pragma unroll
    for (int c = 0; c < 3; c++)
        cm[(b * 3 + c) * M_ + m] = sums[i * 3 + c] * inv;
}

__global__ __launch_bounds__(256) void scan_offs(const float* __restrict__ counts,
                                                 int* __restrict__ offs) {
    __shared__ int tmp[256];
    int t = threadIdx.x;
    for (int b = 0; b < B_; b++) {
        int v = (int)counts[b * M_ + t];
        tmp[t] = v;
        __syncthreads();
        for (int off = 1; off < 256; off <<= 1) {
            int u = (t >= off) ? tmp[t - off] : 0;
            __syncthreads();
            tmp[t] += u;
            __syncthreads();
        }
        offs[b * 257 + t] = tmp[t] - v;
        if (t == 255) offs[b * 257 + 256] = tmp[255];
        __syncthreads();
    }
}

__global__ __launch_bounds__(256) void scatter(const int* __restrict__ knn,
        const int* __restrict__ offs, int* __restrict__ cursor,
        int* __restrict__ sorted, int* __restrict__ msort) {
    int g = blockIdx.x * 256 + threadIdx.x;
    int b = g / (KNN_ * N_), j = g % (KNN_ * N_);
    int n = j & (N_ - 1), k = j >> 12;
    int m = knn[(b * N_ + n) * 3 + k];
    int pos = atomicAdd(&cursor[b * M_ + m], 1);
    int dst = offs[b * 257 + m] + pos;
    sorted[b * (KNN_ * N_) + dst] = j;
    msort[b * (KNN_ * N_) + dst] = m;
}

// generic 16x16x32 bf16 MFMA layer: W [cout][KS*32] bf16 (global),
// actin LDS [P][INS] bf16, actout LDS [P][OUTS] bf16, P = PT*16.
template<int KS, int INS, int OUTS, int PT>
__device__ __forceinline__ void layer16(const unsigned short* __restrict__ Wg,
        const float* __restrict__ bias, const unsigned short* actin,
        unsigned short* actout, int cout, int wave, int lane) {
    int r = lane & 15, g = lane >> 4;
    int nt = (cout >> 4) * PT;
    for (int tl = wave; tl < nt; tl += 4) {
        int co0 = (tl / PT) << 4, p0 = (tl % PT) << 4;
        f32x4 acc = {0.f, 0.f, 0.f, 0.f};
        const unsigned short* wrow = Wg + (co0 + r) * (KS * 32) + g * 8;
        const unsigned short* arow = actin + (p0 + r) * INS + g * 8;
        for (int ks = 0; ks < KS; ks++) {
            bf16x8 av = *(const bf16x8*)(wrow + ks * 32);
            bf16x8 bv = *(const bf16x8*)(arow + ks * 32);
            acc = __builtin_amdgcn_mfma_f32_16x16x32_bf16(av, bv, acc, 0, 0, 0);
        }
        f32x4 bv4 = *(const f32x4*)(bias + co0 + g * 4);
        float v0 = fmaxf(acc[0] + bv4[0], 0.f);
        float v1 = fmaxf(acc[1] + bv4[1], 0.f);
        float v2 = fmaxf(acc[2] + bv4[2], 0.f);
        float v3 = fmaxf(acc[3] + bv4[3], 0.f);
        uint2 w;
        w.x = (unsigned)f2b(v0) | ((unsigned)f2b(v1) << 16);
        w.y = (unsigned)f2b(v2) | ((unsigned)f2b(v3) << 16);
        *(uint2*)(actout + (p0 + r) * OUTS + co0 + g * 4) = w;
    }
}

// MFMA point-MLP over sorted entries, 64 points/block.
// LDS rows padded +8 bf16 (odd 16B-granule stride).
__global__ __launch_bounds__(256) void mlp1m(
        const float* __restrict__ x, const float* __restrict__ cm,
        const int* __restrict__ sorted, const int* __restrict__ msort,
        const unsigned short* __restrict__ wb,
        const float* __restrict__ bb0, const float* __restrict__ bb1,
        const float* __restrict__ bb2, const float* __restrict__ bb3,
        float* __restrict__ node_max, float* __restrict__ first0) {
    __shared__ __align__(16) char smem[69632];
    unsigned short* inb = (unsigned short*)smem;             // [64][40]
    unsigned short* a0  = (unsigned short*)(smem + 5120);    // [64][72]
    unsigned short* a1  = (unsigned short*)(smem + 14336);   // [64][136]
    unsigned short* cat = (unsigned short*)(smem + 31744);   // [64][296] (cols 256..258 = xd)
    float* stg          = (float*)smem;                      // [96][65] f32, aliases inb/a0/a1 (L4)
    __shared__ int midx[64], segm[65], segstart[66];
    __shared__ int nseg, p0loc;
    int t = threadIdx.x, b = blockIdx.y, lane = t & 63, wave = t >> 6;
    int e0 = blockIdx.x * 64;
    if (t == 0) p0loc = -1;
    __syncthreads();
    if (t < 64) {
        int p = t;
        int j = sorted[b * 12288 + e0 + p];
        int m = msort[b * 12288 + e0 + p];
        int n = j & (N_ - 1);
        midx[p] = m;
        if (j == 0) p0loc = p;
        float xd0 = x[(b * 3 + 0) * N_ + n] - cm[(b * 3 + 0) * M_ + m];
        float xd1 = x[(b * 3 + 1) * N_ + n] - cm[(b * 3 + 1) * M_ + m];
        float xd2 = x[(b * 3 + 2) * N_ + n] - cm[(b * 3 + 2) * M_ + m];
        unsigned short u0 = f2b(xd0), u1 = f2b(xd1), u2 = f2b(xd2);
        unsigned short* ri = inb + p * 40;
        ri[0] = u0; ri[1] = u1; ri[2] = u2;
        for (int k = 3; k < 32; k++) ri[k] = 0;
        unsigned short* rc = cat + p * 296;
        rc[256] = u0; rc[257] = u1; rc[258] = u2;
        for (int k = 259; k < 288; k++) rc[k] = 0;
    }
    __syncthreads();
    if (t == 0) {
        int ns = 0;
        for (int p = 0; p < 64; p++)
            if (p == 0 || midx[p] != midx[p - 1]) { segstart[ns] = p; segm[ns] = midx[p]; ns++; }
        segstart[ns] = 64; nseg = ns;
    }
    __syncthreads();
    layer16<1, 40, 72, 4>(wb + O_W0, bb0, inb, a0, 64, wave, lane);
    __syncthreads();
    layer16<2, 72, 136, 4>(wb + O_W1, bb1, a0, a1, 128, wave, lane);
    __syncthreads();
    layer16<4, 136, 296, 4>(wb + O_W2, bb2, a1, cat, 256, wave, lane);
    __syncthreads();
    // L4: 384 x 288 in 4 passes of 96 couts; stage f32 + in-LDS segment max
    int r = lane & 15, g = lane >> 4;
    for (int pass = 0; pass < 4; pass++) {
        for (int tl = wave; tl < 24; tl += 4) {
            int ct = tl >> 2, pt = tl & 3;
            int co0 = pass * 96 + ct * 16, p0 = pt * 16;
            f32x4 acc = {0.f, 0.f, 0.f, 0.f};
            const unsigned short* wrow = wb + O_W3 + (co0 + r) * 288 + g * 8;
            const unsigned short* arow = cat + (p0 + r) * 296 + g * 8;
            for (int ks = 0; ks < 9; ks++) {
                bf16x8 av = *(const bf16x8*)(wrow + ks * 32);
                bf16x8 bv = *(const bf16x8*)(arow + ks * 32);
                acc = __builtin_amdgcn_mfma_f32_16x16x32_bf16(av, bv, acc, 0, 0, 0);
            }
            f32x4 bv4 = *(const f32x4*)(bb3 + co0 + g * 4);
            #pragma unroll
            for (int i = 0; i < 4; i++)
                stg[(ct * 16 + g * 4 + i) * 65 + p0 + r] = fmaxf(acc[i] + bv4[i], 0.f);
        }
        __syncthreads();
        if (p0loc >= 0 && t < 96) first0[b * 384 + pass * 96 + t] = stg[t * 65 + p0loc];
        if (t < 192) {
            int c = t % 96, half = t / 96;
            for (int s = half; s < nseg; s += 2) {
                float mx = 0.f;
                for (int p = segstart[s]; p < segstart[s + 1]; p++)
                    mx = fmaxf(mx, stg[c * 65 + p]);
                atomicMax((int*)&node_max[(size_t)(b * M_ + segm[s]) * 384 + pass * 96 + c],
                          __float_as_int(mx));
            }
        }
        __syncthreads();
    }
}

__global__ void build_fin(const float* __restrict__ cm, const float* __restrict__ counts,
                          const float* __restrict__ nmax, const float* __restrict__ first0,
                          float* __restrict__ fin) {
    int tot = B_ * 387 * M_;
    int i = blockIdx.x * blockDim.x + threadIdx.x;
    int st = gridDim.x * blockDim.x;
    for (; i < tot; i += st) {
        int b = i / (387 * M_), r = i % (387 * M_);
        int ch = r / M_, m = r % M_;
        float v;
        if (ch < 3) v = cm[(b * 3 + ch) * M_ + m];
        else {
            v = (counts[b * M_ + m] > 0.f) ? nmax[((size_t)(b * M_ + m)) * 384 + (ch - 3)]
                                           : first0[b * 384 + (ch - 3)];
        }
        fin[(b * 388 + ch) * M_ + m] = v;
    }
}

// MFMA node-MLP, 16 nodes/block
__global__ __launch_bounds__(256) void mlp2m(
        const float* __restrict__ fin_g, const unsigned short* __restrict__ wb,
        const float* __restrict__ q0, const float* __restrict__ q1,
        const float* __restrict__ q2, const float* __restrict__ q3,
        float* __restrict__ out) {
    __shared__ __align__(16) char smem[71424];
    unsigned short* fin = (unsigned short*)smem;             // [16][424] (aliases h1)
    unsigned short* h1  = (unsigned short*)smem;             // [16][520]
    unsigned short* h0  = (unsigned short*)(smem + 16640);   // [16][520]
    unsigned short* cat = (unsigned short*)(smem + 33280);   // [16][1192]
    int t = threadIdx.x, b = blockIdx.y, lane = t & 63, wave = t >> 6;
    int m0 = blockIdx.x * 16;
    for (int e = t; e < 16 * 416; e += 256) {
        int ch = e >> 4, p = e & 15;
        float v = (ch < 388) ? fin_g[(b * 388 + ch) * M_ + m0 + p] : 0.f;
        unsigned short u = f2b(v);
        fin[p * 424 + ch] = u;
        cat[p * 1192 + 768 + ch] = u;
    }
    __syncthreads();
    layer16<13, 424, 520, 1>(wb + O_V0, q0, fin, h0, 512, wave, lane);
    __syncthreads();
    layer16<16, 520, 520, 1>(wb + O_V1, q1, h0, h1, 512, wave, lane);
    __syncthreads();
    layer16<16, 520, 1192, 1>(wb + O_V2, q2, h1, cat, 768, wave, lane);
    __syncthreads();
    // L4: 1024 x 1184, in-wave max over the 16 nodes + one atomic per (co group)
    int r = lane & 15, g = lane >> 4;
    for (int tl = wave; tl < 64; tl += 4) {
        int co0 = tl * 16;
        f32x4 acc = {0.f, 0.f, 0.f, 0.f};
        const unsigned short* wrow = wb + O_V3 + (co0 + r) * 1184 + g * 8;
        const unsigned short* arow = cat + r * 1192 + g * 8;
        for (int ks = 0; ks < 37; ks++) {
            bf16x8 av = *(const bf16x8*)(wrow + ks * 32);
            bf16x8 bv = *(const bf16x8*)(arow + ks * 32);
            acc = __builtin_amdgcn_mfma_f32_16x16x32_bf16(av, bv, acc, 0, 0, 0);
        }
        f32x4 bv4 = *(const f32x4*)(q3 + co0 + g * 4);
        #pragma unroll
        for (int i = 0; i < 4; i++) {
            float v = fmaxf(acc[i] + bv4[i], 0.f);
            v = fmaxf(v, __shfl_xor(v, 1));
            v = fmaxf(v, __shfl_xor(v, 2));
            v = fmaxf(v, __shfl_xor(v, 4));
            v = fmaxf(v, __shfl_xor(v, 8));
            if (r == 0)
                atomicMax((int*)&out[b * 1024 + co0 + g * 4 + i], __float_as_int(v));
        }
    }
}

extern "C" void kernel_launch(void* const* d_in, const int* in_sizes, int n_in,
                              void* d_out, int out_size, void* d_ws, size_t ws_size,
                              hipStream_t stream) {
    (void)in_sizes; (void)n_in; (void)out_size; (void)ws_size;
    const float* x    = (const float*)d_in[0];
    const float* node = (const float*)d_in[2];
    const float* fpw[4] = {(const float*)d_in[4], (const float*)d_in[6],
                           (const float*)d_in[8], (const float*)d_in[10]};
    const float* fpb[4] = {(const float*)d_in[5], (const float*)d_in[7],
                           (const float*)d_in[9], (const float*)d_in[11]};
    const float* fnw[4] = {(const float*)d_in[12], (const float*)d_in[14],
                           (const float*)d_in[16], (const float*)d_in[18]};
    const float* fnb[4] = {(const float*)d_in[13], (const float*)d_in[15],
                           (const float*)d_in[17], (const float*)d_in[19]};
    float* ws  = (float*)d_ws;
    float* out = (float*)d_out;
    unsigned short* wb = (unsigned short*)(ws + OFF_WBF);

    zero_f<<<2048, 256, 0, stream>>>(ws, ZERO_COUNT);
    zero_f<<<32, 256, 0, stream>>>(out, B_ * 1024);

    pad_w_bf16<<<8,    256, 0, stream>>>(fpw[0], wb + O_W0,   64,    3,   32);
    pad_w_bf16<<<32,   256, 0, stream>>>(fpw[1], wb + O_W1,  128,   64,   64);
    pad_w_bf16<<<128,  256, 0, stream>>>(fpw[2], wb + O_W2,  256,  128,  128);
    pad_w_bf16<<<432,  256, 0, stream>>>(fpw[3], wb + O_W3,  384,  259,  288);
    pad_w_bf16<<<832,  256, 0, stream>>>(fnw[0], wb + O_V0,  512,  387,  416);
    pad_w_bf16<<<1024, 256, 0, stream>>>(fnw[1], wb + O_V1,  512,  512,  512);
    pad_w_bf16<<<1536, 256, 0, stream>>>(fnw[2], wb + O_V2,  768,  512,  512);
    pad_w_bf16<<<2048, 256, 0, stream>>>(fnw[3], wb + O_V3, 1024, 1155, 1184);

    knn_assign<<<dim3(N_ / 256, B_), 256, 0, stream>>>(
        x, node, (int*)(ws + OFF_KNN), ws + OFF_COUNTS, ws + OFF_SUMS);
    cmean<<<(B_ * M_ + 255) / 256, 256, 0, stream>>>(
        ws + OFF_COUNTS, ws + OFF_SUMS, ws + OFF_CM);
    scan_offs<<<1, 256, 0, stream>>>(ws + OFF_COUNTS, (int*)(ws + OFF_OFFS));
    scatter<<<B_ * KNN_ * N_ / 256, 256, 0, stream>>>(
        (int*)(ws + OFF_KNN), (int*)(ws + OFF_OFFS), (int*)(ws + OFF_CURSOR),
        (int*)(ws + OFF_SORTED), (int*)(ws + OFF_MSORT));
    mlp1m<<<dim3(KNN_ * N_ / 64, B_), 256, 0, stream>>>(
        x, ws + OFF_CM, (int*)(ws + OFF_SORTED), (int*)(ws + OFF_MSORT), wb,
        fpb[0], fpb[1], fpb[2], fpb[3], ws + OFF_NODEMAX, ws + OFF_FIRST0);
    build_fin<<<1024, 256, 0, stream>>>(
        ws + OFF_CM, ws + OFF_COUNTS, ws + OFF_NODEMAX, ws + OFF_FIRST0, ws + OFF_FINALIN);
    mlp2m<<<dim3(M_ / 16, B_), 256, 0, stream>>>(
        ws + OFF_FINALIN, wb, fnb[0], fnb[1], fnb[2], fnb[3], out);
}

// Round 4
// 371.034 us; speedup vs baseline: 2.9675x; 1.2267x over previous
//
#include <hip/hip_runtime.h>
#include <math.h>

#define B_   8
#define N_   4096
#define M_   256
#define KNN_ 3

// ---- workspace layout (float element offsets) ----
#define OFF_COUNTS   0          // [8][256] f32
#define OFF_SUMS     2048       // [8][256][3] f32
#define OFF_CM       8192       // [8][3][256] f32
#define OFF_NODEMAX  14336      // [8][256][384] f32 (atomicMax as int) ; H0 aliases (phase2)
#define OFF_H0       14336      // ushort [2048][512] (written by nlayer L1, after nodemax consumed)
#define OFF_FIRST0   800768     // [8][384] f32
#define OFF_CURSOR   803840     // [8][256] int
#define OFF_OFFS     805888     // [8][257] int
#define ZERO_COUNT   805888
#define OFF_KNN      807944     // [8][4096][3] int ; CAT aliases (phase2)
#define OFF_CAT      807944     // ushort [2048][1184] (written after mlp1m done with knn/sorted)
#define OFF_SORTED   906248     // [8][12288] int
#define OFF_MSORT    1004552    // [8][12288] int
#define OFF_FIN2     2020360    // ushort [2048][416] ; H1 aliases (fin2 dead after nlayer L1)
#define OFF_H1       2020360    // ushort [2048][512]
#define OFF_WBF      2544648    // bf16 weights (ushort), ends 3,661,832 f ≈ 14.65 MB
// bf16 padded weight offsets (USHORT units, relative to wb base)
#define O_W0 0         // 64   x 32
#define O_W1 2048      // 128  x 64
#define O_W2 10240     // 256  x 128
#define O_W3 43008     // 384  x 288
#define O_V0 153600    // 512  x 416
#define O_V1 366592    // 512  x 512
#define O_V2 628736    // 768  x 512
#define O_V3 1021952   // 1024 x 1184

typedef short  bf16x8 __attribute__((ext_vector_type(8)));
typedef float  f32x4  __attribute__((ext_vector_type(4)));

__device__ __forceinline__ unsigned short f2b(float f) {
    unsigned u = __float_as_uint(f);
    return (unsigned short)((u + 0x7FFFu + ((u >> 16) & 1u)) >> 16);
}
__device__ __forceinline__ float b2f(unsigned short u) {
    return __uint_as_float(((unsigned)u) << 16);
}

__global__ void zero_f(float* __restrict__ p, int n) {
    int i = blockIdx.x * blockDim.x + threadIdx.x;
    int st = gridDim.x * blockDim.x;
    for (; i < n; i += st) p[i] = 0.f;
}

__global__ void pad_w_bf16(const float* __restrict__ src, unsigned short* __restrict__ dst,
                           int cout, int cin, int cinp) {
    int i = blockIdx.x * blockDim.x + threadIdx.x;
    int st = gridDim.x * blockDim.x;
    int tot = cout * cinp;
    for (; i < tot; i += st) {
        int co = i / cinp, k = i - co * cinp;
        dst[i] = (k < cin) ? f2b(src[co * cin + k]) : (unsigned short)0;
    }
}

__global__ __launch_bounds__(256) void knn_assign(
        const float* __restrict__ x, const float* __restrict__ node,
        int* __restrict__ knn, float* __restrict__ counts, float* __restrict__ sums) {
    __shared__ float nd0[M_], nd1[M_], nd2[M_], nn2[M_];
    int b = blockIdx.y, t = threadIdx.x;
    {
        float c0 = node[(b * 3 + 0) * M_ + t];
        float c1 = node[(b * 3 + 1) * M_ + t];
        float c2 = node[(b * 3 + 2) * M_ + t];
        nd0[t] = c0; nd1[t] = c1; nd2[t] = c2;
        nn2[t] = c0 * c0 + c1 * c1 + c2 * c2;
    }
    __syncthreads();
    int n = blockIdx.x * 256 + t;
    float x0 = x[(b * 3 + 0) * N_ + n];
    float x1 = x[(b * 3 + 1) * N_ + n];
    float x2 = x[(b * 3 + 2) * N_ + n];
    float xx = x0 * x0 + x1 * x1 + x2 * x2;
    float d0 = 1e30f, d1 = 1e30f, d2b = 1e30f;
    int i0 = 0, i1 = 0, i2 = 0;
    for (int m = 0; m < M_; m++) {
        float cross = x0 * nd0[m] + x1 * nd1[m] + x2 * nd2[m];
        float d = xx + nn2[m] - 2.f * cross;
        if (d < d0)       { d2b = d1; i2 = i1; d1 = d0; i1 = i0; d0 = d; i0 = m; }
        else if (d < d1)  { d2b = d1; i2 = i1; d1 = d;  i1 = m; }
        else if (d < d2b) { d2b = d;  i2 = m; }
    }
    int base = (b * N_ + n) * 3;
    knn[base + 0] = i0; knn[base + 1] = i1; knn[base + 2] = i2;
    int mm[3] = {i0, i1, i2};
    #pragma unroll
    for (int k = 0; k < 3; k++) {
        int m = mm[k];
        atomicAdd(&counts[b * M_ + m], 1.f);
        atomicAdd(&sums[(b * M_ + m) * 3 + 0], x0);
        atomicAdd(&sums[(b * M_ + m) * 3 + 1], x1);
        atomicAdd(&sums[(b * M_ + m) * 3 + 2], x2);
    }
}

__global__ void cmean(const float* __restrict__ counts, const float* __restrict__ sums,
                      float* __restrict__ cm) {
    int i = blockIdx.x * 256 + threadIdx.x;
    if (i >= B_ * M_) return;
    int b = i >> 8, m = i & 255;
    float inv = 1.f / (counts[i] + 1e-5f);
    #pragma unroll
    for (int c = 0; c < 3; c++)
        cm[(b * 3 + c) * M_ + m] = sums[i * 3 + c] * inv;
}

__global__ __launch_bounds__(256) void scan_offs(const float* __restrict__ counts,
                                                 int* __restrict__ offs) {
    __shared__ int tmp[256];
    int t = threadIdx.x, b = blockIdx.x;
    int v = (int)counts[b * M_ + t];
    tmp[t] = v;
    __syncthreads();
    for (int off = 1; off < 256; off <<= 1) {
        int u = (t >= off) ? tmp[t - off] : 0;
        __syncthreads();
        tmp[t] += u;
        __syncthreads();
    }
    offs[b * 257 + t] = tmp[t] - v;
    if (t == 255) offs[b * 257 + 256] = tmp[255];
}

__global__ __launch_bounds__(256) void scatter(const int* __restrict__ knn,
        const int* __restrict__ offs, int* __restrict__ cursor,
        int* __restrict__ sorted, int* __restrict__ msort) {
    int g = blockIdx.x * 256 + threadIdx.x;
    int b = g / (KNN_ * N_), j = g % (KNN_ * N_);
    int n = j & (N_ - 1), k = j >> 12;
    int m = knn[(b * N_ + n) * 3 + k];
    int pos = atomicAdd(&cursor[b * M_ + m], 1);
    int dst = offs[b * 257 + m] + pos;
    sorted[b * (KNN_ * N_) + dst] = j;
    msort[b * (KNN_ * N_) + dst] = m;
}

// wave owns p-tile `wave`; B-frags held in regs; co-tiles in pairs (2 indep chains)
template<int KS, int INS, int OUTS, int NCT>
__device__ __forceinline__ void layerW(const unsigned short* __restrict__ Wg,
        const float* __restrict__ bias, const unsigned short* actin,
        unsigned short* actout, int wave, int lane) {
    int r = lane & 15, g = lane >> 4, p0 = wave * 16;
    bf16x8 bfr[KS];
    const unsigned short* arow = actin + (p0 + r) * INS + g * 8;
    #pragma unroll
    for (int ks = 0; ks < KS; ks++) bfr[ks] = *(const bf16x8*)(arow + ks * 32);
    #pragma unroll
    for (int ct = 0; ct < NCT; ct += 2) {
        const unsigned short* w0 = Wg + (ct * 16 + r) * (KS * 32) + g * 8;
        const unsigned short* w1 = w0 + 16 * KS * 32;
        bf16x8 wa[KS], wc[KS];
        #pragma unroll
        for (int ks = 0; ks < KS; ks++) {
            wa[ks] = *(const bf16x8*)(w0 + ks * 32);
            wc[ks] = *(const bf16x8*)(w1 + ks * 32);
        }
        f32x4 aA = {0.f,0.f,0.f,0.f}, aB = {0.f,0.f,0.f,0.f};
        #pragma unroll
        for (int ks = 0; ks < KS; ks++) {
            aA = __builtin_amdgcn_mfma_f32_16x16x32_bf16(wa[ks], bfr[ks], aA, 0, 0, 0);
            aB = __builtin_amdgcn_mfma_f32_16x16x32_bf16(wc[ks], bfr[ks], aB, 0, 0, 0);
        }
        f32x4 b0 = *(const f32x4*)(bias + ct * 16 + g * 4);
        f32x4 b1 = *(const f32x4*)(bias + ct * 16 + 16 + g * 4);
        uint2 s0, s1;
        s0.x = (unsigned)f2b(fmaxf(aA[0] + b0[0], 0.f)) | ((unsigned)f2b(fmaxf(aA[1] + b0[1], 0.f)) << 16);
        s0.y = (unsigned)f2b(fmaxf(aA[2] + b0[2], 0.f)) | ((unsigned)f2b(fmaxf(aA[3] + b0[3], 0.f)) << 16);
        s1.x = (unsigned)f2b(fmaxf(aB[0] + b1[0], 0.f)) | ((unsigned)f2b(fmaxf(aB[1] + b1[1], 0.f)) << 16);
        s1.y = (unsigned)f2b(fmaxf(aB[2] + b1[2], 0.f)) | ((unsigned)f2b(fmaxf(aB[3] + b1[3], 0.f)) << 16);
        *(uint2*)(actout + (p0 + r) * OUTS + ct * 16 + g * 4) = s0;
        *(uint2*)(actout + (p0 + r) * OUTS + ct * 16 + 16 + g * 4) = s1;
    }
}

// MFMA point-MLP over sorted entries, 64 points/block, 2-arena LDS (56 KB)
__global__ __launch_bounds__(256) void mlp1m(
        const float* __restrict__ x, const float* __restrict__ cm,
        const int* __restrict__ sorted, const int* __restrict__ msort,
        const unsigned short* __restrict__ wb,
        const float* __restrict__ bb0, const float* __restrict__ bb1,
        const float* __restrict__ bb2, const float* __restrict__ bb3,
        float* __restrict__ node_max, float* __restrict__ first0) {
    __shared__ __align__(16) char smem[55296];
    // arena A (0..17408): inb [64][40] -> a1 [64][136] -> stg u16 [96][66]
    // arena B (17408..55296): a0 [64][72] -> cat [64][296]
    unsigned short* inb = (unsigned short*)smem;
    unsigned short* a1  = (unsigned short*)smem;
    unsigned short* stg = (unsigned short*)smem;
    unsigned short* a0  = (unsigned short*)(smem + 17408);
    unsigned short* cat = (unsigned short*)(smem + 17408);
    __shared__ int midx[64], segm[65], segstart[66];
    __shared__ int nseg, p0loc;
    int t = threadIdx.x, b = blockIdx.y, lane = t & 63, wave = t >> 6;
    int e0 = blockIdx.x * 64;
    unsigned short u0 = 0, u1 = 0, u2 = 0;
    if (t == 0) p0loc = -1;
    __syncthreads();
    if (t < 64) {
        int p = t;
        int j = sorted[b * 12288 + e0 + p];
        int m = msort[b * 12288 + e0 + p];
        int n = j & (N_ - 1);
        midx[p] = m;
        if (j == 0) p0loc = p;
        float xd0 = x[(b * 3 + 0) * N_ + n] - cm[(b * 3 + 0) * M_ + m];
        float xd1 = x[(b * 3 + 1) * N_ + n] - cm[(b * 3 + 1) * M_ + m];
        float xd2 = x[(b * 3 + 2) * N_ + n] - cm[(b * 3 + 2) * M_ + m];
        u0 = f2b(xd0); u1 = f2b(xd1); u2 = f2b(xd2);
        unsigned short* ri = inb + p * 40;
        ri[0] = u0; ri[1] = u1; ri[2] = u2;
        for (int k = 3; k < 32; k++) ri[k] = 0;
    }
    __syncthreads();
    if (t == 0) {
        int ns = 0;
        for (int p = 0; p < 64; p++)
            if (p == 0 || midx[p] != midx[p - 1]) { segstart[ns] = p; segm[ns] = midx[p]; ns++; }
        segstart[ns] = 64; nseg = ns;
    }
    __syncthreads();
    layerW<1, 40, 72, 4>(wb + O_W0, bb0, inb, a0, wave, lane);       // a1 overwrites inb next
    __syncthreads();
    layerW<2, 72, 136, 8>(wb + O_W1, bb1, a0, a1, wave, lane);       // cat overwrites a0 next
    __syncthreads();
    if (t < 64) {   // xd tail + pad into cat (arena B free of a0 now)
        unsigned short* rc = cat + t * 296;
        rc[256] = u0; rc[257] = u1; rc[258] = u2;
        for (int k = 259; k < 288; k++) rc[k] = 0;
    }
    layerW<4, 136, 296, 16>(wb + O_W2, bb2, a1, cat, wave, lane);    // writes cat cols 0..255
    __syncthreads();
    // L4: 384 x 288, B-frags (cat) in regs; 4 passes of 96 couts; bf16 staging + seg-max
    int r = lane & 15, g = lane >> 4, p0 = wave * 16;
    bf16x8 bfr[9];
    {
        const unsigned short* arow = cat + (p0 + r) * 296 + g * 8;
        #pragma unroll
        for (int ks = 0; ks < 9; ks++) bfr[ks] = *(const bf16x8*)(arow + ks * 32);
    }
    for (int pass = 0; pass < 4; pass++) {
        #pragma unroll
        for (int ctp = 0; ctp < 6; ctp += 2) {
            int coA = pass * 96 + ctp * 16;
            const unsigned short* w0 = wb + O_W3 + (coA + r) * 288 + g * 8;
            const unsigned short* w1 = w0 + 16 * 288;
            bf16x8 wa[9], wc[9];
            #pragma unroll
            for (int ks = 0; ks < 9; ks++) {
                wa[ks] = *(const bf16x8*)(w0 + ks * 32);
                wc[ks] = *(const bf16x8*)(w1 + ks * 32);
            }
            f32x4 aA = {0.f,0.f,0.f,0.f}, aB = {0.f,0.f,0.f,0.f};
            #pragma unroll
            for (int ks = 0; ks < 9; ks++) {
                aA = __builtin_amdgcn_mfma_f32_16x16x32_bf16(wa[ks], bfr[ks], aA, 0, 0, 0);
                aB = __builtin_amdgcn_mfma_f32_16x16x32_bf16(wc[ks], bfr[ks], aB, 0, 0, 0);
            }
            f32x4 b0 = *(const f32x4*)(bb3 + coA + g * 4);
            f32x4 b1 = *(const f32x4*)(bb3 + coA + 16 + g * 4);
            #pragma unroll
            for (int i = 0; i < 4; i++) {
                stg[(ctp * 16 + g * 4 + i) * 66 + p0 + r]      = f2b(fmaxf(aA[i] + b0[i], 0.f));
                stg[(ctp * 16 + 16 + g * 4 + i) * 66 + p0 + r] = f2b(fmaxf(aB[i] + b1[i], 0.f));
            }
        }
        __syncthreads();
        if (p0loc >= 0 && t < 96)
            first0[b * 384 + pass * 96 + t] = b2f(stg[t * 66 + p0loc]);
        if (t < 192) {
            int c = t % 96, half = t / 96;
            for (int s = half; s < nseg; s += 2) {
                float mx = 0.f;
                for (int p = segstart[s]; p < segstart[s + 1]; p++)
                    mx = fmaxf(mx, b2f(stg[c * 66 + p]));
                atomicMax((int*)&node_max[(size_t)(b * M_ + segm[s]) * 384 + pass * 96 + c],
                          __float_as_int(mx));
            }
        }
        __syncthreads();
    }
}

// masked node features -> bf16 fin2 [2048][416] and cat tail [2048][1184] cols 768..1183
__global__ void build_fin2(const float* __restrict__ cm, const float* __restrict__ counts,
                           const float* __restrict__ nmax, const float* __restrict__ first0,
                           unsigned short* __restrict__ fin2, unsigned short* __restrict__ cat) {
    int tot = 2048 * 416;
    int i = blockIdx.x * blockDim.x + threadIdx.x;
    int st = gridDim.x * blockDim.x;
    for (; i < tot; i += st) {
        int n = i / 416, ch = i - n * 416;
        int b = n >> 8, m = n & 255;
        float v = 0.f;
        if (ch < 3) v = cm[(b * 3 + ch) * M_ + m];
        else if (ch < 387)
            v = (counts[n] > 0.f) ? nmax[(size_t)n * 384 + (ch - 3)]
                                  : first0[b * 384 + (ch - 3)];
        unsigned short u = f2b(v);
        fin2[n * 416 + ch] = u;
        cat[(size_t)n * 1184 + 768 + ch] = u;
    }
}

// node-MLP layer: one wave = one 16x16 output tile; acts in global bf16 (stride = KS*32)
template<int KS, int CTN>
__global__ __launch_bounds__(256) void nlayer(const unsigned short* __restrict__ W,
        const float* __restrict__ bias, const unsigned short* __restrict__ actin,
        unsigned short* __restrict__ actout, int outs) {
    int wave = threadIdx.x >> 6, lane = threadIdx.x & 63;
    int id = blockIdx.x * 4 + wave;
    int nt = id / CTN, ct = id - nt * CTN;
    int r = lane & 15, g = lane >> 4;
    const unsigned short* wrow = W + (ct * 16 + r) * (KS * 32) + g * 8;
    const unsigned short* arow = actin + (nt * 16 + r) * (KS * 32) + g * 8;
    f32x4 acc = {0.f, 0.f, 0.f, 0.f};
    #pragma unroll
    for (int ks = 0; ks < KS; ks++)
        acc = __builtin_amdgcn_mfma_f32_16x16x32_bf16(
            *(const bf16x8*)(wrow + ks * 32), *(const bf16x8*)(arow + ks * 32), acc, 0, 0, 0);
    f32x4 b4 = *(const f32x4*)(bias + ct * 16 + g * 4);
    uint2 s;
    s.x = (unsigned)f2b(fmaxf(acc[0] + b4[0], 0.f)) | ((unsigned)f2b(fmaxf(acc[1] + b4[1], 0.f)) << 16);
    s.y = (unsigned)f2b(fmaxf(acc[2] + b4[2], 0.f)) | ((unsigned)f2b(fmaxf(acc[3] + b4[3], 0.f)) << 16);
    *(uint2*)(actout + (size_t)(nt * 16 + r) * outs + ct * 16 + g * 4) = s;
}

// last node layer + global max over nodes
template<int KS, int CTN>
__global__ __launch_bounds__(256) void nlayer_max(const unsigned short* __restrict__ W,
        const float* __restrict__ bias, const unsigned short* __restrict__ actin,
        float* __restrict__ out) {
    int wave = threadIdx.x >> 6, lane = threadIdx.x & 63;
    int id = blockIdx.x * 4 + wave;
    int nt = id / CTN, ct = id - nt * CTN;
    int r = lane & 15, g = lane >> 4;
    const unsigned short* wrow = W + (ct * 16 + r) * (KS * 32) + g * 8;
    const unsigned short* arow = actin + (size_t)(nt * 16 + r) * (KS * 32) + g * 8;
    f32x4 acc = {0.f, 0.f, 0.f, 0.f};
    #pragma unroll
    for (int ks = 0; ks < KS; ks++)
        acc = __builtin_amdgcn_mfma_f32_16x16x32_bf16(
            *(const bf16x8*)(wrow + ks * 32), *(const bf16x8*)(arow + ks * 32), acc, 0, 0, 0);
    f32x4 b4 = *(const f32x4*)(bias + ct * 16 + g * 4);
    int b = nt >> 4;
    #pragma unroll
    for (int i = 0; i < 4; i++) {
        float v = fmaxf(acc[i] + b4[i], 0.f);
        v = fmaxf(v, __shfl_xor(v, 1));
        v = fmaxf(v, __shfl_xor(v, 2));
        v = fmaxf(v, __shfl_xor(v, 4));
        v = fmaxf(v, __shfl_xor(v, 8));
        if (r == 0)
            atomicMax((int*)&out[b * 1024 + ct * 16 + g * 4 + i], __float_as_int(v));
    }
}

extern "C" void kernel_launch(void* const* d_in, const int* in_sizes, int n_in,
                              void* d_out, int out_size, void* d_ws, size_t ws_size,
                              hipStream_t stream) {
    (void)in_sizes; (void)n_in; (void)out_size; (void)ws_size;
    const float* x    = (const float*)d_in[0];
    const float* node = (const float*)d_in[2];
    const float* fpw[4] = {(const float*)d_in[4], (const float*)d_in[6],
                           (const float*)d_in[8], (const float*)d_in[10]};
    const float* fpb[4] = {(const float*)d_in[5], (const float*)d_in[7],
                           (const float*)d_in[9], (const float*)d_in[11]};
    const float* fnw[4] = {(const float*)d_in[12], (const float*)d_in[14],
                           (const float*)d_in[16], (const float*)d_in[18]};
    const float* fnb[4] = {(const float*)d_in[13], (const float*)d_in[15],
                           (const float*)d_in[17], (const float*)d_in[19]};
    float* ws  = (float*)d_ws;
    float* out = (float*)d_out;
    unsigned short* wb   = (unsigned short*)(ws + OFF_WBF);
    unsigned short* fin2 = (unsigned short*)(ws + OFF_FIN2);
    unsigned short* h0   = (unsigned short*)(ws + OFF_H0);
    unsigned short* h1   = (unsigned short*)(ws + OFF_H1);
    unsigned short* catb = (unsigned short*)(ws + OFF_CAT);

    zero_f<<<2048, 256, 0, stream>>>(ws, ZERO_COUNT);
    zero_f<<<32, 256, 0, stream>>>(out, B_ * 1024);

    pad_w_bf16<<<8,    256, 0, stream>>>(fpw[0], wb + O_W0,   64,    3,   32);
    pad_w_bf16<<<32,   256, 0, stream>>>(fpw[1], wb + O_W1,  128,   64,   64);
    pad_w_bf16<<<128,  256, 0, stream>>>(fpw[2], wb + O_W2,  256,  128,  128);
    pad_w_bf16<<<432,  256, 0, stream>>>(fpw[3], wb + O_W3,  384,  259,  288);
    pad_w_bf16<<<832,  256, 0, stream>>>(fnw[0], wb + O_V0,  512,  387,  416);
    pad_w_bf16<<<1024, 256, 0, stream>>>(fnw[1], wb + O_V1,  512,  512,  512);
    pad_w_bf16<<<1536, 256, 0, stream>>>(fnw[2], wb + O_V2,  768,  512,  512);
    pad_w_bf16<<<2048, 256, 0, stream>>>(fnw[3], wb + O_V3, 1024, 1155, 1184);

    knn_assign<<<dim3(N_ / 256, B_), 256, 0, stream>>>(
        x, node, (int*)(ws + OFF_KNN), ws + OFF_COUNTS, ws + OFF_SUMS);
    cmean<<<(B_ * M_ + 255) / 256, 256, 0, stream>>>(
        ws + OFF_COUNTS, ws + OFF_SUMS, ws + OFF_CM);
    scan_offs<<<B_, 256, 0, stream>>>(ws + OFF_COUNTS, (int*)(ws + OFF_OFFS));
    scatter<<<B_ * KNN_ * N_ / 256, 256, 0, stream>>>(
        (int*)(ws + OFF_KNN), (int*)(ws + OFF_OFFS), (int*)(ws + OFF_CURSOR),
        (int*)(ws + OFF_SORTED), (int*)(ws + OFF_MSORT));
    mlp1m<<<dim3(KNN_ * N_ / 64, B_), 256, 0, stream>>>(
        x, ws + OFF_CM, (int*)(ws + OFF_SORTED), (int*)(ws + OFF_MSORT), wb,
        fpb[0], fpb[1], fpb[2], fpb[3], ws + OFF_NODEMAX, ws + OFF_FIRST0);
    build_fin2<<<3328, 256, 0, stream>>>(
        ws + OFF_CM, ws + OFF_COUNTS, ws + OFF_NODEMAX, ws + OFF_FIRST0, fin2, catb);
    nlayer<13, 32><<<1024, 256, 0, stream>>>(wb + O_V0, fnb[0], fin2, h0, 512);
    nlayer<16, 32><<<1024, 256, 0, stream>>>(wb + O_V1, fnb[1], h0, h1, 512);
    nlayer<16, 48><<<1536, 256, 0, stream>>>(wb + O_V2, fnb[2], h1, catb, 1184);
    nlayer_max<37, 64><<<2048, 256, 0, stream>>>(wb + O_V3, fnb[3], catb, out);
}

// Round 5
// 287.402 us; speedup vs baseline: 3.8311x; 1.2910x over previous
//
#include <hip/hip_runtime.h>
#include <math.h>

#define B_   8
#define N_   4096
#define M_   256
#define KNN_ 3

// ---- workspace layout (float element offsets) ----
#define OFF_COUNTS   0          // [8][256] f32
#define OFF_SUMS     2048       // [8][256][3] f32
#define OFF_CM       8192       // [8][3][256] f32
#define OFF_NODEMAX  14336      // [8][256][384] f32 ; H0 aliases (phase2)
#define OFF_H0       14336      // ushort [2048][512]
#define OFF_FIRST0   800768     // [8][384] f32
#define OFF_CURSOR   803840     // [8][256] int
#define OFF_OFFS     805888     // [8][257] int
#define ZERO_COUNT   805888
#define OFF_KNN      807944     // [8][4096][3] int ; CAT aliases (phase2)
#define OFF_CAT      807944     // ushort [2048][1184]
#define OFF_SORTED   906248     // [8][12288] int
#define OFF_MSORT    1004552    // [8][12288] int
#define OFF_FIN2     2020360    // ushort [2048][416] ; H1 aliases
#define OFF_H1       2020360    // ushort [2048][512]
#define OFF_WBF      2544648    // bf16 weights (ushort)
// bf16 padded weight offsets (USHORT units, relative to wb base; contiguous)
#define O_W0 0         // 64   x 32
#define O_W1 2048      // 128  x 64
#define O_W2 10240     // 256  x 128
#define O_W3 43008     // 384  x 288
#define O_V0 153600    // 512  x 416
#define O_V1 366592    // 512  x 512
#define O_V2 628736    // 768  x 512
#define O_V3 1021952   // 1024 x 1184
#define W_TOTAL 2234368

typedef short  bf16x8 __attribute__((ext_vector_type(8)));
typedef float  f32x4  __attribute__((ext_vector_type(4)));

__device__ __forceinline__ unsigned short f2b(float f) {
    unsigned u = __float_as_uint(f);
    return (unsigned short)((u + 0x7FFFu + ((u >> 16) & 1u)) >> 16);
}
__device__ __forceinline__ float b2f(unsigned short u) {
    return __uint_as_float(((unsigned)u) << 16);
}

__global__ void zero_f(float* __restrict__ p, int n) {
    int i = blockIdx.x * blockDim.x + threadIdx.x;
    int st = gridDim.x * blockDim.x;
    for (; i < n; i += st) p[i] = 0.f;
}

// all 8 weight pads in one launch (regions contiguous in dst)
__global__ void pad_all(const float* s0, const float* s1, const float* s2, const float* s3,
                        const float* s4, const float* s5, const float* s6, const float* s7,
                        unsigned short* __restrict__ dst) {
    int i = blockIdx.x * blockDim.x + threadIdx.x;
    int st = gridDim.x * blockDim.x;
    for (; i < W_TOTAL; i += st) {
        const float* src; int base, cin, cinp;
        if      (i < O_W1) { src = s0; base = O_W0; cin = 3;    cinp = 32; }
        else if (i < O_W2) { src = s1; base = O_W1; cin = 64;   cinp = 64; }
        else if (i < O_W3) { src = s2; base = O_W2; cin = 128;  cinp = 128; }
        else if (i < O_V0) { src = s3; base = O_W3; cin = 259;  cinp = 288; }
        else if (i < O_V1) { src = s4; base = O_V0; cin = 387;  cinp = 416; }
        else if (i < O_V2) { src = s5; base = O_V1; cin = 512;  cinp = 512; }
        else if (i < O_V3) { src = s6; base = O_V2; cin = 512;  cinp = 512; }
        else               { src = s7; base = O_V3; cin = 1155; cinp = 1184; }
        int loc = i - base;
        int co = loc / cinp, k = loc - co * cinp;
        dst[i] = (k < cin) ? f2b(src[co * cin + k]) : (unsigned short)0;
    }
}

__global__ __launch_bounds__(256) void knn_assign(
        const float* __restrict__ x, const float* __restrict__ node,
        int* __restrict__ knn, float* __restrict__ counts, float* __restrict__ sums) {
    __shared__ float nd0[M_], nd1[M_], nd2[M_], nn2[M_];
    int b = blockIdx.y, t = threadIdx.x;
    {
        float c0 = node[(b * 3 + 0) * M_ + t];
        float c1 = node[(b * 3 + 1) * M_ + t];
        float c2 = node[(b * 3 + 2) * M_ + t];
        nd0[t] = c0; nd1[t] = c1; nd2[t] = c2;
        nn2[t] = c0 * c0 + c1 * c1 + c2 * c2;
    }
    __syncthreads();
    int n = blockIdx.x * 256 + t;
    float x0 = x[(b * 3 + 0) * N_ + n];
    float x1 = x[(b * 3 + 1) * N_ + n];
    float x2 = x[(b * 3 + 2) * N_ + n];
    float xx = x0 * x0 + x1 * x1 + x2 * x2;
    float d0 = 1e30f, d1 = 1e30f, d2b = 1e30f;
    int i0 = 0, i1 = 0, i2 = 0;
    for (int m = 0; m < M_; m++) {
        float cross = x0 * nd0[m] + x1 * nd1[m] + x2 * nd2[m];
        float d = xx + nn2[m] - 2.f * cross;
        if (d < d0)       { d2b = d1; i2 = i1; d1 = d0; i1 = i0; d0 = d; i0 = m; }
        else if (d < d1)  { d2b = d1; i2 = i1; d1 = d;  i1 = m; }
        else if (d < d2b) { d2b = d;  i2 = m; }
    }
    int base = (b * N_ + n) * 3;
    knn[base + 0] = i0; knn[base + 1] = i1; knn[base + 2] = i2;
    int mm[3] = {i0, i1, i2};
    #pragma unroll
    for (int k = 0; k < 3; k++) {
        int m = mm[k];
        atomicAdd(&counts[b * M_ + m], 1.f);
        atomicAdd(&sums[(b * M_ + m) * 3 + 0], x0);
        atomicAdd(&sums[(b * M_ + m) * 3 + 1], x1);
        atomicAdd(&sums[(b * M_ + m) * 3 + 2], x2);
    }
}

__global__ void cmean(const float* __restrict__ counts, const float* __restrict__ sums,
                      float* __restrict__ cm) {
    int i = blockIdx.x * 256 + threadIdx.x;
    if (i >= B_ * M_) return;
    int b = i >> 8, m = i & 255;
    float inv = 1.f / (counts[i] + 1e-5f);
    #pragma unroll
    for (int c = 0; c < 3; c++)
        cm[(b * 3 + c) * M_ + m] = sums[i * 3 + c] * inv;
}

__global__ __launch_bounds__(256) void scan_offs(const float* __restrict__ counts,
                                                 int* __restrict__ offs) {
    __shared__ int tmp[256];
    int t = threadIdx.x, b = blockIdx.x;
    int v = (int)counts[b * M_ + t];
    tmp[t] = v;
    __syncthreads();
    for (int off = 1; off < 256; off <<= 1) {
        int u = (t >= off) ? tmp[t - off] : 0;
        __syncthreads();
        tmp[t] += u;
        __syncthreads();
    }
    offs[b * 257 + t] = tmp[t] - v;
    if (t == 255) offs[b * 257 + 256] = tmp[255];
}

__global__ __launch_bounds__(256) void scatter(const int* __restrict__ knn,
        const int* __restrict__ offs, int* __restrict__ cursor,
        int* __restrict__ sorted, int* __restrict__ msort) {
    int g = blockIdx.x * 256 + threadIdx.x;
    int b = g / (KNN_ * N_), j = g % (KNN_ * N_);
    int n = j & (N_ - 1), k = j >> 12;
    int m = knn[(b * N_ + n) * 3 + k];
    int pos = atomicAdd(&cursor[b * M_ + m], 1);
    int dst = offs[b * 257 + m] + pos;
    sorted[b * (KNN_ * N_) + dst] = j;
    msort[b * (KNN_ * N_) + dst] = m;
}

// B-stationary layer: wave holds B-frags for ALL 4 p-tiles in regs,
// owns CTW co-tiles, streams W. 4 independent MFMA chains (one per p-tile).
template<int KS, int INS, int OUTS, int CTW>
__device__ __forceinline__ void layerB(const unsigned short* __restrict__ Wg,
        const float* __restrict__ bias, const unsigned short* actin,
        unsigned short* actout, int wave, int lane) {
    int r = lane & 15, g = lane >> 4;
    bf16x8 bfr[4][KS];
    #pragma unroll
    for (int pt = 0; pt < 4; pt++) {
        const unsigned short* arow = actin + (pt * 16 + r) * INS + g * 8;
        #pragma unroll
        for (int ks = 0; ks < KS; ks++)
            bfr[pt][ks] = *(const bf16x8*)(arow + ks * 32);
    }
    #pragma unroll
    for (int c = 0; c < CTW; c++) {
        int ct = wave * CTW + c;
        const unsigned short* wrow = Wg + (ct * 16 + r) * (KS * 32) + g * 8;
        f32x4 acc[4];
        #pragma unroll
        for (int pt = 0; pt < 4; pt++) acc[pt] = (f32x4){0.f, 0.f, 0.f, 0.f};
        #pragma unroll
        for (int ks = 0; ks < KS; ks++) {
            bf16x8 wv = *(const bf16x8*)(wrow + ks * 32);
            #pragma unroll
            for (int pt = 0; pt < 4; pt++)
                acc[pt] = __builtin_amdgcn_mfma_f32_16x16x32_bf16(wv, bfr[pt][ks], acc[pt], 0, 0, 0);
        }
        f32x4 b4 = *(const f32x4*)(bias + ct * 16 + g * 4);
        #pragma unroll
        for (int pt = 0; pt < 4; pt++) {
            uint2 s;
            s.x = (unsigned)f2b(fmaxf(acc[pt][0] + b4[0], 0.f)) |
                  ((unsigned)f2b(fmaxf(acc[pt][1] + b4[1], 0.f)) << 16);
            s.y = (unsigned)f2b(fmaxf(acc[pt][2] + b4[2], 0.f)) |
                  ((unsigned)f2b(fmaxf(acc[pt][3] + b4[3], 0.f)) << 16);
            *(uint2*)(actout + (pt * 16 + r) * OUTS + ct * 16 + g * 4) = s;
        }
    }
}

// MFMA point-MLP over sorted entries, 64 points/block, weights streamed once per block
__global__ __launch_bounds__(256, 2) void mlp1m(
        const float* __restrict__ x, const float* __restrict__ cm,
        const int* __restrict__ sorted, const int* __restrict__ msort,
        const unsigned short* __restrict__ wb,
        const float* __restrict__ bb0, const float* __restrict__ bb1,
        const float* __restrict__ bb2, const float* __restrict__ bb3,
        float* __restrict__ node_max, float* __restrict__ first0) {
    __shared__ __align__(16) char smem[55296];
    // arena A (0..17408): inb [64][40] -> a1 [64][136] -> stg u16 [64][66]
    // arena B (17408..55296): a0 [64][72] -> cat [64][296]
    unsigned short* inb = (unsigned short*)smem;
    unsigned short* a1  = (unsigned short*)smem;
    unsigned short* stg = (unsigned short*)smem;
    unsigned short* a0  = (unsigned short*)(smem + 17408);
    unsigned short* cat = (unsigned short*)(smem + 17408);
    __shared__ int midx[64], segm[65], segstart[66];
    __shared__ int nseg, p0loc;
    int t = threadIdx.x, b = blockIdx.y, lane = t & 63, wave = t >> 6;
    int e0 = blockIdx.x * 64;
    unsigned short u0 = 0, u1 = 0, u2 = 0;
    if (t == 0) p0loc = -1;
    __syncthreads();
    if (t < 64) {
        int p = t;
        int j = sorted[b * 12288 + e0 + p];
        int m = msort[b * 12288 + e0 + p];
        int n = j & (N_ - 1);
        midx[p] = m;
        if (j == 0) p0loc = p;
        float xd0 = x[(b * 3 + 0) * N_ + n] - cm[(b * 3 + 0) * M_ + m];
        float xd1 = x[(b * 3 + 1) * N_ + n] - cm[(b * 3 + 1) * M_ + m];
        float xd2 = x[(b * 3 + 2) * N_ + n] - cm[(b * 3 + 2) * M_ + m];
        u0 = f2b(xd0); u1 = f2b(xd1); u2 = f2b(xd2);
        unsigned short* ri = inb + p * 40;
        ri[0] = u0; ri[1] = u1; ri[2] = u2;
        for (int k = 3; k < 32; k++) ri[k] = 0;
    }
    __syncthreads();
    if (t == 0) {
        int ns = 0;
        for (int p = 0; p < 64; p++)
            if (p == 0 || midx[p] != midx[p - 1]) { segstart[ns] = p; segm[ns] = midx[p]; ns++; }
        segstart[ns] = 64; nseg = ns;
    }
    __syncthreads();
    layerB<1, 40, 72, 1>(wb + O_W0, bb0, inb, a0, wave, lane);     // inb -> a0
    __syncthreads();
    layerB<2, 72, 136, 2>(wb + O_W1, bb1, a0, a1, wave, lane);     // a0 -> a1 (over inb)
    __syncthreads();
    if (t < 64) {   // xd tail + pad into cat (arena B free of a0 now)
        unsigned short* rc = cat + t * 296;
        rc[256] = u0; rc[257] = u1; rc[258] = u2;
        for (int k = 259; k < 288; k++) rc[k] = 0;
    }
    layerB<4, 136, 296, 4>(wb + O_W2, bb2, a1, cat, wave, lane);   // a1 -> cat (over a0)
    __syncthreads();
    // L4: 384 x 288; B-frags (all 4 p-tiles, KS=9) persistent in regs;
    // 6 passes of 64 couts (1 ct/wave), bf16 staging (over a1) + in-LDS segment max
    int r = lane & 15, g = lane >> 4;
    bf16x8 bfr[4][9];
    #pragma unroll
    for (int pt = 0; pt < 4; pt++) {
        const unsigned short* arow = cat + (pt * 16 + r) * 296 + g * 8;
        #pragma unroll
        for (int ks = 0; ks < 9; ks++)
            bfr[pt][ks] = *(const bf16x8*)(arow + ks * 32);
    }
    for (int pass = 0; pass < 6; pass++) {
        int ct = pass * 4 + wave;
        const unsigned short* wrow = wb + O_W3 + (ct * 16 + r) * 288 + g * 8;
        f32x4 acc[4];
        #pragma unroll
        for (int pt = 0; pt < 4; pt++) acc[pt] = (f32x4){0.f, 0.f, 0.f, 0.f};
        #pragma unroll
        for (int ks = 0; ks < 9; ks++) {
            bf16x8 wv = *(const bf16x8*)(wrow + ks * 32);
            #pragma unroll
            for (int pt = 0; pt < 4; pt++)
                acc[pt] = __builtin_amdgcn_mfma_f32_16x16x32_bf16(wv, bfr[pt][ks], acc[pt], 0, 0, 0);
        }
        f32x4 b4 = *(const f32x4*)(bb3 + ct * 16 + g * 4);
        #pragma unroll
        for (int pt = 0; pt < 4; pt++)
            #pragma unroll
            for (int i = 0; i < 4; i++)
                stg[(wave * 16 + g * 4 + i) * 66 + pt * 16 + r] = f2b(fmaxf(acc[pt][i] + b4[i], 0.f));
        __syncthreads();
        if (p0loc >= 0 && t < 64)
            first0[b * 384 + pass * 64 + t] = b2f(stg[t * 66 + p0loc]);
        {
            int c = t & 63, q = t >> 6;
            for (int s = q; s < nseg; s += 4) {
                float mx = 0.f;
                for (int p = segstart[s]; p < segstart[s + 1]; p++)
                    mx = fmaxf(mx, b2f(stg[c * 66 + p]));
                atomicMax((int*)&node_max[(size_t)(b * M_ + segm[s]) * 384 + pass * 64 + c],
                          __float_as_int(mx));
            }
        }
        __syncthreads();
    }
}

// masked node features -> bf16 fin2 [2048][416] and cat tail [2048][1184] cols 768..1183
__global__ void build_fin2(const float* __restrict__ cm, const float* __restrict__ counts,
                           const float* __restrict__ nmax, const float* __restrict__ first0,
                           unsigned short* __restrict__ fin2, unsigned short* __restrict__ cat) {
    int tot = 2048 * 416;
    int i = blockIdx.x * blockDim.x + threadIdx.x;
    int st = gridDim.x * blockDim.x;
    for (; i < tot; i += st) {
        int n = i / 416, ch = i - n * 416;
        int b = n >> 8, m = n & 255;
        float v = 0.f;
        if (ch < 3) v = cm[(b * 3 + ch) * M_ + m];
        else if (ch < 387)
            v = (counts[n] > 0.f) ? nmax[(size_t)n * 384 + (ch - 3)]
                                  : first0[b * 384 + (ch - 3)];
        unsigned short u = f2b(v);
        fin2[n * 416 + ch] = u;
        cat[(size_t)n * 1184 + 768 + ch] = u;
    }
}

// node-MLP layer: one wave = 2 co-tiles sharing one act-frag set (2 indep chains)
template<int KS, int CTP>   // CTP = co-tile pairs per node row
__global__ __launch_bounds__(256) void nlayer2(const unsigned short* __restrict__ W,
        const float* __restrict__ bias, const unsigned short* __restrict__ actin,
        unsigned short* __restrict__ actout, int outs) {
    int wave = threadIdx.x >> 6, lane = threadIdx.x & 63;
    int id = blockIdx.x * 4 + wave;
    int nt = id / CTP, cp = id - nt * CTP;
    int r = lane & 15, g = lane >> 4;
    const unsigned short* arow = actin + (size_t)(nt * 16 + r) * (KS * 32) + g * 8;
    bf16x8 afr[KS];
    #pragma unroll
    for (int ks = 0; ks < KS; ks++) afr[ks] = *(const bf16x8*)(arow + ks * 32);
    const unsigned short* w0 = W + (cp * 32 + r) * (KS * 32) + g * 8;
    const unsigned short* w1 = w0 + 16 * KS * 32;
    f32x4 aA = {0.f,0.f,0.f,0.f}, aB = {0.f,0.f,0.f,0.f};
    #pragma unroll
    for (int ks = 0; ks < KS; ks++) {
        aA = __builtin_amdgcn_mfma_f32_16x16x32_bf16(*(const bf16x8*)(w0 + ks * 32), afr[ks], aA, 0, 0, 0);
        aB = __builtin_amdgcn_mfma_f32_16x16x32_bf16(*(const bf16x8*)(w1 + ks * 32), afr[ks], aB, 0, 0, 0);
    }
    f32x4 b0 = *(const f32x4*)(bias + cp * 32 + g * 4);
    f32x4 b1 = *(const f32x4*)(bias + cp * 32 + 16 + g * 4);
    uint2 s0, s1;
    s0.x = (unsigned)f2b(fmaxf(aA[0] + b0[0], 0.f)) | ((unsigned)f2b(fmaxf(aA[1] + b0[1], 0.f)) << 16);
    s0.y = (unsigned)f2b(fmaxf(aA[2] + b0[2], 0.f)) | ((unsigned)f2b(fmaxf(aA[3] + b0[3], 0.f)) << 16);
    s1.x = (unsigned)f2b(fmaxf(aB[0] + b1[0], 0.f)) | ((unsigned)f2b(fmaxf(aB[1] + b1[1], 0.f)) << 16);
    s1.y = (unsigned)f2b(fmaxf(aB[2] + b1[2], 0.f)) | ((unsigned)f2b(fmaxf(aB[3] + b1[3], 0.f)) << 16);
    *(uint2*)(actout + (size_t)(nt * 16 + r) * outs + cp * 32 + g * 4) = s0;
    *(uint2*)(actout + (size_t)(nt * 16 + r) * outs + cp * 32 + 16 + g * 4) = s1;
}

// last node layer (2 co-tiles/wave) + global max over nodes
template<int KS, int CTP>
__global__ __launch_bounds__(256) void nlayer_max2(const unsigned short* __restrict__ W,
        const float* __restrict__ bias, const unsigned short* __restrict__ actin,
        float* __restrict__ out) {
    int wave = threadIdx.x >> 6, lane = threadIdx.x & 63;
    int id = blockIdx.x * 4 + wave;
    int nt = id / CTP, cp = id - nt * CTP;
    int r = lane & 15, g = lane >> 4;
    const unsigned short* arow = actin + (size_t)(nt * 16 + r) * (KS * 32) + g * 8;
    bf16x8 afr[KS];
    #pragma unroll
    for (int ks = 0; ks < KS; ks++) afr[ks] = *(const bf16x8*)(arow + ks * 32);
    const unsigned short* w0 = W + (cp * 32 + r) * (KS * 32) + g * 8;
    const unsigned short* w1 = w0 + 16 * KS * 32;
    f32x4 aA = {0.f,0.f,0.f,0.f}, aB = {0.f,0.f,0.f,0.f};
    #pragma unroll
    for (int ks = 0; ks < KS; ks++) {
        aA = __builtin_amdgcn_mfma_f32_16x16x32_bf16(*(const bf16x8*)(w0 + ks * 32), afr[ks], aA, 0, 0, 0);
        aB = __builtin_amdgcn_mfma_f32_16x16x32_bf16(*(const bf16x8*)(w1 + ks * 32), afr[ks], aB, 0, 0, 0);
    }
    f32x4 b0 = *(const f32x4*)(bias + cp * 32 + g * 4);
    f32x4 b1 = *(const f32x4*)(bias + cp * 32 + 16 + g * 4);
    int b = nt >> 4;
    #pragma unroll
    for (int i = 0; i < 4; i++) {
        float v = fmaxf(aA[i] + b0[i], 0.f);
        v = fmaxf(v, __shfl_xor(v, 1));
        v = fmaxf(v, __shfl_xor(v, 2));
        v = fmaxf(v, __shfl_xor(v, 4));
        v = fmaxf(v, __shfl_xor(v, 8));
        if (r == 0)
            atomicMax((int*)&out[b * 1024 + cp * 32 + g * 4 + i], __float_as_int(v));
        float w = fmaxf(aB[i] + b1[i], 0.f);
        w = fmaxf(w, __shfl_xor(w, 1));
        w = fmaxf(w, __shfl_xor(w, 2));
        w = fmaxf(w, __shfl_xor(w, 4));
        w = fmaxf(w, __shfl_xor(w, 8));
        if (r == 0)
            atomicMax((int*)&out[b * 1024 + cp * 32 + 16 + g * 4 + i], __float_as_int(w));
    }
}

extern "C" void kernel_launch(void* const* d_in, const int* in_sizes, int n_in,
                              void* d_out, int out_size, void* d_ws, size_t ws_size,
                              hipStream_t stream) {
    (void)in_sizes; (void)n_in; (void)out_size; (void)ws_size;
    const float* x    = (const float*)d_in[0];
    const float* node = (const float*)d_in[2];
    const float* fpw[4] = {(const float*)d_in[4], (const float*)d_in[6],
                           (const float*)d_in[8], (const float*)d_in[10]};
    const float* fpb[4] = {(const float*)d_in[5], (const float*)d_in[7],
                           (const float*)d_in[9], (const float*)d_in[11]};
    const float* fnw[4] = {(const float*)d_in[12], (const float*)d_in[14],
                           (const float*)d_in[16], (const float*)d_in[18]};
    const float* fnb[4] = {(const float*)d_in[13], (const float*)d_in[15],
                           (const float*)d_in[17], (const float*)d_in[19]};
    float* ws  = (float*)d_ws;
    float* out = (float*)d_out;
    unsigned short* wb   = (unsigned short*)(ws + OFF_WBF);
    unsigned short* fin2 = (unsigned short*)(ws + OFF_FIN2);
    unsigned short* h0   = (unsigned short*)(ws + OFF_H0);
    unsigned short* h1   = (unsigned short*)(ws + OFF_H1);
    unsigned short* catb = (unsigned short*)(ws + OFF_CAT);

    zero_f<<<2048, 256, 0, stream>>>(ws, ZERO_COUNT);
    zero_f<<<32, 256, 0, stream>>>(out, B_ * 1024);
    pad_all<<<2048, 256, 0, stream>>>(fpw[0], fpw[1], fpw[2], fpw[3],
                                      fnw[0], fnw[1], fnw[2], fnw[3], wb);

    knn_assign<<<dim3(N_ / 256, B_), 256, 0, stream>>>(
        x, node, (int*)(ws + OFF_KNN), ws + OFF_COUNTS, ws + OFF_SUMS);
    cmean<<<(B_ * M_ + 255) / 256, 256, 0, stream>>>(
        ws + OFF_COUNTS, ws + OFF_SUMS, ws + OFF_CM);
    scan_offs<<<B_, 256, 0, stream>>>(ws + OFF_COUNTS, (int*)(ws + OFF_OFFS));
    scatter<<<B_ * KNN_ * N_ / 256, 256, 0, stream>>>(
        (int*)(ws + OFF_KNN), (int*)(ws + OFF_OFFS), (int*)(ws + OFF_CURSOR),
        (int*)(ws + OFF_SORTED), (int*)(ws + OFF_MSORT));
    mlp1m<<<dim3(KNN_ * N_ / 64, B_), 256, 0, stream>>>(
        x, ws + OFF_CM, (int*)(ws + OFF_SORTED), (int*)(ws + OFF_MSORT), wb,
        fpb[0], fpb[1], fpb[2], fpb[3], ws + OFF_NODEMAX, ws + OFF_FIRST0);
    build_fin2<<<3328, 256, 0, stream>>>(
        ws + OFF_CM, ws + OFF_COUNTS, ws + OFF_NODEMAX, ws + OFF_FIRST0, fin2, catb);
    nlayer2<13, 16><<<512,  256, 0, stream>>>(wb + O_V0, fnb[0], fin2, h0, 512);
    nlayer2<16, 16><<<512,  256, 0, stream>>>(wb + O_V1, fnb[1], h0, h1, 512);
    nlayer2<16, 24><<<768,  256, 0, stream>>>(wb + O_V2, fnb[2], h1, catb, 1184);
    nlayer_max2<37, 32><<<1024, 256, 0, stream>>>(wb + O_V3, fnb[3], catb, out);
}

// Round 6
// 249.405 us; speedup vs baseline: 4.4148x; 1.1523x over previous
//
#include <hip/hip_runtime.h>
#include <math.h>

#define B_   8
#define N_   4096
#define M_   256
#define KNN_ 3

// ---- workspace layout (float element offsets) ----
#define OFF_COUNTS   0          // [8][256] f32
#define OFF_SUMS     2048       // [8][256][3] f32
#define OFF_CM       8192       // [8][3][256] f32
#define OFF_NODEMAX  14336      // [8][256][384] f32 ; H0 aliases (phase2)
#define OFF_H0       14336      // ushort [2048][512]
#define OFF_FIRST0   800768     // [8][384] f32
#define OFF_CURSOR   803840     // [8][256] int
#define OFF_OFFS     805888     // [8][257] int
#define ZERO_COUNT   805888
#define OFF_KNN      807944     // [8][4096][3] int ; CAT aliases (phase2)
#define OFF_CAT      807944     // ushort [2048][1184]
#define OFF_SORTED   906248     // [8][12288] int
#define OFF_MSORT    1004552    // [8][12288] int
#define OFF_FIN2     2020360    // ushort [2048][416] ; H1 aliases
#define OFF_H1       2020360    // ushort [2048][512]
#define OFF_WBF      2544648    // bf16 weights (ushort)
// bf16 padded weight offsets (USHORT units, relative to wb base; contiguous)
#define O_W0 0         // 64   x 32
#define O_W1 2048      // 128  x 64
#define O_W2 10240     // 256  x 128
#define O_W3 43008     // 384  x 288
#define O_V0 153600    // 512  x 416
#define O_V1 366592    // 512  x 512
#define O_V2 628736    // 768  x 512
#define O_V3 1021952   // 1024 x 1184
#define W_TOTAL 2234368

typedef short  bf16x8 __attribute__((ext_vector_type(8)));
typedef float  f32x4  __attribute__((ext_vector_type(4)));

__device__ __forceinline__ unsigned short f2b(float f) {
    unsigned u = __float_as_uint(f);
    return (unsigned short)((u + 0x7FFFu + ((u >> 16) & 1u)) >> 16);
}
__device__ __forceinline__ float b2f(unsigned short u) {
    return __uint_as_float(((unsigned)u) << 16);
}

// zero ws control region + out, and pad/convert all 8 weight matrices (one launch)
__global__ void setup(const float* s0, const float* s1, const float* s2, const float* s3,
                      const float* s4, const float* s5, const float* s6, const float* s7,
                      unsigned short* __restrict__ dst, float* __restrict__ wsz,
                      float* __restrict__ out) {
    int i = blockIdx.x * blockDim.x + threadIdx.x;
    int st = gridDim.x * blockDim.x;
    for (int j = i; j < ZERO_COUNT; j += st) wsz[j] = 0.f;
    for (int j = i; j < B_ * 1024; j += st) out[j] = 0.f;
    for (; i < W_TOTAL; i += st) {
        const float* src; int base, cin, cinp;
        if      (i < O_W1) { src = s0; base = O_W0; cin = 3;    cinp = 32; }
        else if (i < O_W2) { src = s1; base = O_W1; cin = 64;   cinp = 64; }
        else if (i < O_W3) { src = s2; base = O_W2; cin = 128;  cinp = 128; }
        else if (i < O_V0) { src = s3; base = O_W3; cin = 259;  cinp = 288; }
        else if (i < O_V1) { src = s4; base = O_V0; cin = 387;  cinp = 416; }
        else if (i < O_V2) { src = s5; base = O_V1; cin = 512;  cinp = 512; }
        else if (i < O_V3) { src = s6; base = O_V2; cin = 512;  cinp = 512; }
        else               { src = s7; base = O_V3; cin = 1155; cinp = 1184; }
        int loc = i - base;
        int co = loc / cinp, k = loc - co * cinp;
        dst[i] = (k < cin) ? f2b(src[co * cin + k]) : (unsigned short)0;
    }
}

__global__ __launch_bounds__(256) void knn_assign(
        const float* __restrict__ x, const float* __restrict__ node,
        int* __restrict__ knn, float* __restrict__ counts, float* __restrict__ sums) {
    __shared__ float nd0[M_], nd1[M_], nd2[M_], nn2[M_];
    int b = blockIdx.y, t = threadIdx.x;
    {
        float c0 = node[(b * 3 + 0) * M_ + t];
        float c1 = node[(b * 3 + 1) * M_ + t];
        float c2 = node[(b * 3 + 2) * M_ + t];
        nd0[t] = c0; nd1[t] = c1; nd2[t] = c2;
        nn2[t] = c0 * c0 + c1 * c1 + c2 * c2;
    }
    __syncthreads();
    int n = blockIdx.x * 256 + t;
    float x0 = x[(b * 3 + 0) * N_ + n];
    float x1 = x[(b * 3 + 1) * N_ + n];
    float x2 = x[(b * 3 + 2) * N_ + n];
    float xx = x0 * x0 + x1 * x1 + x2 * x2;
    float d0 = 1e30f, d1 = 1e30f, d2b = 1e30f;
    int i0 = 0, i1 = 0, i2 = 0;
    for (int m = 0; m < M_; m++) {
        float cross = x0 * nd0[m] + x1 * nd1[m] + x2 * nd2[m];
        float d = xx + nn2[m] - 2.f * cross;
        if (d < d0)       { d2b = d1; i2 = i1; d1 = d0; i1 = i0; d0 = d; i0 = m; }
        else if (d < d1)  { d2b = d1; i2 = i1; d1 = d;  i1 = m; }
        else if (d < d2b) { d2b = d;  i2 = m; }
    }
    int base = (b * N_ + n) * 3;
    knn[base + 0] = i0; knn[base + 1] = i1; knn[base + 2] = i2;
    int mm[3] = {i0, i1, i2};
    #pragma unroll
    for (int k = 0; k < 3; k++) {
        int m = mm[k];
        atomicAdd(&counts[b * M_ + m], 1.f);
        atomicAdd(&sums[(b * M_ + m) * 3 + 0], x0);
        atomicAdd(&sums[(b * M_ + m) * 3 + 1], x1);
        atomicAdd(&sums[(b * M_ + m) * 3 + 2], x2);
    }
}

// cluster means + exclusive scan of counts, one block per batch
__global__ __launch_bounds__(256) void cmean_scan(const float* __restrict__ counts,
        const float* __restrict__ sums, float* __restrict__ cm, int* __restrict__ offs) {
    __shared__ int tmp[256];
    int t = threadIdx.x, b = blockIdx.x;
    float cnt = counts[b * M_ + t];
    float inv = 1.f / (cnt + 1e-5f);
    #pragma unroll
    for (int c = 0; c < 3; c++)
        cm[(b * 3 + c) * M_ + t] = sums[(b * M_ + t) * 3 + c] * inv;
    int v = (int)cnt;
    tmp[t] = v;
    __syncthreads();
    for (int off = 1; off < 256; off <<= 1) {
        int u = (t >= off) ? tmp[t - off] : 0;
        __syncthreads();
        tmp[t] += u;
        __syncthreads();
    }
    offs[b * 257 + t] = tmp[t] - v;
    if (t == 255) offs[b * 257 + 256] = tmp[255];
}

__global__ __launch_bounds__(256) void scatter(const int* __restrict__ knn,
        const int* __restrict__ offs, int* __restrict__ cursor,
        int* __restrict__ sorted, int* __restrict__ msort) {
    int g = blockIdx.x * 256 + threadIdx.x;
    int b = g / (KNN_ * N_), j = g % (KNN_ * N_);
    int n = j & (N_ - 1), k = j >> 12;
    int m = knn[(b * N_ + n) * 3 + k];
    int pos = atomicAdd(&cursor[b * M_ + m], 1);
    int dst = offs[b * 257 + m] + pos;
    sorted[b * (KNN_ * N_) + dst] = j;
    msort[b * (KNN_ * N_) + dst] = m;
}

// B-stationary layer: wave holds B-frags for ALL 4 p-tiles in regs,
// owns CTW co-tiles, streams W. 4 independent MFMA chains (one per p-tile).
template<int KS, int INS, int OUTS, int CTW>
__device__ __forceinline__ void layerB(const unsigned short* __restrict__ Wg,
        const float* __restrict__ bias, const unsigned short* actin,
        unsigned short* actout, int wave, int lane) {
    int r = lane & 15, g = lane >> 4;
    bf16x8 bfr[4][KS];
    #pragma unroll
    for (int pt = 0; pt < 4; pt++) {
        const unsigned short* arow = actin + (pt * 16 + r) * INS + g * 8;
        #pragma unroll
        for (int ks = 0; ks < KS; ks++)
            bfr[pt][ks] = *(const bf16x8*)(arow + ks * 32);
    }
    #pragma unroll
    for (int c = 0; c < CTW; c++) {
        int ct = wave * CTW + c;
        const unsigned short* wrow = Wg + (ct * 16 + r) * (KS * 32) + g * 8;
        f32x4 acc[4];
        #pragma unroll
        for (int pt = 0; pt < 4; pt++) acc[pt] = (f32x4){0.f, 0.f, 0.f, 0.f};
        #pragma unroll
        for (int ks = 0; ks < KS; ks++) {
            bf16x8 wv = *(const bf16x8*)(wrow + ks * 32);
            #pragma unroll
            for (int pt = 0; pt < 4; pt++)
                acc[pt] = __builtin_amdgcn_mfma_f32_16x16x32_bf16(wv, bfr[pt][ks], acc[pt], 0, 0, 0);
        }
        f32x4 b4 = *(const f32x4*)(bias + ct * 16 + g * 4);
        #pragma unroll
        for (int pt = 0; pt < 4; pt++) {
            uint2 s;
            s.x = (unsigned)f2b(fmaxf(acc[pt][0] + b4[0], 0.f)) |
                  ((unsigned)f2b(fmaxf(acc[pt][1] + b4[1], 0.f)) << 16);
            s.y = (unsigned)f2b(fmaxf(acc[pt][2] + b4[2], 0.f)) |
                  ((unsigned)f2b(fmaxf(acc[pt][3] + b4[3], 0.f)) << 16);
            *(uint2*)(actout + (pt * 16 + r) * OUTS + ct * 16 + g * 4) = s;
        }
    }
}

// MFMA point-MLP over sorted entries, 64 points/block.
// L4 is barrier-free: seg-max fully in-register via D-fragment layout
// (col = lane&15 = point, row = g*4+i = channel); masking with 0 is exact (ReLU>=0).
__global__ __launch_bounds__(256, 2) void mlp1m(
        const float* __restrict__ x, const float* __restrict__ cm,
        const int* __restrict__ sorted, const int* __restrict__ msort,
        const unsigned short* __restrict__ wb,
        const float* __restrict__ bb0, const float* __restrict__ bb1,
        const float* __restrict__ bb2, const float* __restrict__ bb3,
        float* __restrict__ node_max, float* __restrict__ first0) {
    __shared__ __align__(16) char smem[55296];
    // arena A (0..17408): inb [64][40] -> a1 [64][136]
    // arena B (17408..55296): a0 [64][72] -> cat [64][296]
    unsigned short* inb = (unsigned short*)smem;
    unsigned short* a1  = (unsigned short*)smem;
    unsigned short* a0  = (unsigned short*)(smem + 17408);
    unsigned short* cat = (unsigned short*)(smem + 17408);
    __shared__ int midx[64], segm[65], segstart[66];
    __shared__ int nseg, p0loc;
    int t = threadIdx.x, b = blockIdx.y, lane = t & 63, wave = t >> 6;
    int e0 = blockIdx.x * 64;
    unsigned short u0 = 0, u1 = 0, u2 = 0;
    if (t == 0) p0loc = -1;
    __syncthreads();
    if (t < 64) {
        int p = t;
        int j = sorted[b * 12288 + e0 + p];
        int m = msort[b * 12288 + e0 + p];
        int n = j & (N_ - 1);
        midx[p] = m;
        if (j == 0) p0loc = p;
        float xd0 = x[(b * 3 + 0) * N_ + n] - cm[(b * 3 + 0) * M_ + m];
        float xd1 = x[(b * 3 + 1) * N_ + n] - cm[(b * 3 + 1) * M_ + m];
        float xd2 = x[(b * 3 + 2) * N_ + n] - cm[(b * 3 + 2) * M_ + m];
        u0 = f2b(xd0); u1 = f2b(xd1); u2 = f2b(xd2);
        unsigned short* ri = inb + p * 40;
        ri[0] = u0; ri[1] = u1; ri[2] = u2;
        for (int k = 3; k < 32; k++) ri[k] = 0;
    }
    __syncthreads();
    if (t == 0) {
        int ns = 0;
        for (int p = 0; p < 64; p++)
            if (p == 0 || midx[p] != midx[p - 1]) { segstart[ns] = p; segm[ns] = midx[p]; ns++; }
        segstart[ns] = 64; nseg = ns;
    }
    __syncthreads();
    layerB<1, 40, 72, 1>(wb + O_W0, bb0, inb, a0, wave, lane);     // inb -> a0
    __syncthreads();
    layerB<2, 72, 136, 2>(wb + O_W1, bb1, a0, a1, wave, lane);     // a0 -> a1 (over inb)
    __syncthreads();
    if (t < 64) {   // xd tail + pad into cat (arena B free of a0 now)
        unsigned short* rc = cat + t * 296;
        rc[256] = u0; rc[257] = u1; rc[258] = u2;
        for (int k = 259; k < 288; k++) rc[k] = 0;
    }
    layerB<4, 136, 296, 4>(wb + O_W2, bb2, a1, cat, wave, lane);   // a1 -> cat (over a0)
    __syncthreads();
    // ---- L4: 384 x 288, barrier-free, per-wave independent 6 co-tiles ----
    int r = lane & 15, g = lane >> 4;
    bf16x8 bfr[4][9];
    #pragma unroll
    for (int pt = 0; pt < 4; pt++) {
        const unsigned short* arow = cat + (pt * 16 + r) * 296 + g * 8;
        #pragma unroll
        for (int ks = 0; ks < 9; ks++)
            bfr[pt][ks] = *(const bf16x8*)(arow + ks * 32);
    }
    int ns = nseg, p0l = p0loc;
    for (int c = 0; c < 6; c++) {
        int ct = wave * 6 + c;
        const unsigned short* wrow = wb + O_W3 + (ct * 16 + r) * 288 + g * 8;
        f32x4 acc[4];
        #pragma unroll
        for (int pt = 0; pt < 4; pt++) acc[pt] = (f32x4){0.f, 0.f, 0.f, 0.f};
        #pragma unroll
        for (int ks = 0; ks < 9; ks++) {
            bf16x8 wv = *(const bf16x8*)(wrow + ks * 32);
            #pragma unroll
            for (int pt = 0; pt < 4; pt++)
                acc[pt] = __builtin_amdgcn_mfma_f32_16x16x32_bf16(wv, bfr[pt][ks], acc[pt], 0, 0, 0);
        }
        f32x4 b4 = *(const f32x4*)(bb3 + ct * 16 + g * 4);
        float v[4][4];
        #pragma unroll
        for (int pt = 0; pt < 4; pt++)
            #pragma unroll
            for (int i = 0; i < 4; i++)
                v[pt][i] = fmaxf(acc[pt][i] + b4[i], 0.f);
        if (p0l >= 0) {   // first-point channel values (one block per batch)
            #pragma unroll
            for (int pt = 0; pt < 4; pt++)
                if (p0l == pt * 16 + r) {
                    #pragma unroll
                    for (int i = 0; i < 4; i++)
                        first0[b * 384 + ct * 16 + g * 4 + i] = v[pt][i];
                }
        }
        for (int s = 0; s < ns; s++) {
            int s0 = segstart[s], s1 = segstart[s + 1];
            float mx0 = 0.f, mx1 = 0.f, mx2 = 0.f, mx3 = 0.f;
            #pragma unroll
            for (int pt = 0; pt < 4; pt++) {
                int p = pt * 16 + r;
                bool in = (p >= s0) && (p < s1);
                mx0 = fmaxf(mx0, in ? v[pt][0] : 0.f);
                mx1 = fmaxf(mx1, in ? v[pt][1] : 0.f);
                mx2 = fmaxf(mx2, in ? v[pt][2] : 0.f);
                mx3 = fmaxf(mx3, in ? v[pt][3] : 0.f);
            }
            #pragma unroll
            for (int sh = 1; sh < 16; sh <<= 1) {
                mx0 = fmaxf(mx0, __shfl_xor(mx0, sh));
                mx1 = fmaxf(mx1, __shfl_xor(mx1, sh));
                mx2 = fmaxf(mx2, __shfl_xor(mx2, sh));
                mx3 = fmaxf(mx3, __shfl_xor(mx3, sh));
            }
            if (r == 0) {
                float* dst = &node_max[(size_t)(b * M_ + segm[s]) * 384 + ct * 16 + g * 4];
                atomicMax((int*)(dst + 0), __float_as_int(mx0));
                atomicMax((int*)(dst + 1), __float_as_int(mx1));
                atomicMax((int*)(dst + 2), __float_as_int(mx2));
                atomicMax((int*)(dst + 3), __float_as_int(mx3));
            }
        }
    }
}

// masked node features -> bf16 fin2 [2048][416] and cat tail [2048][1184] cols 768..1183
__global__ void build_fin2(const float* __restrict__ cm, const float* __restrict__ counts,
                           const float* __restrict__ nmax, const float* __restrict__ first0,
                           unsigned short* __restrict__ fin2, unsigned short* __restrict__ cat) {
    int tot = 2048 * 416;
    int i = blockIdx.x * blockDim.x + threadIdx.x;
    int st = gridDim.x * blockDim.x;
    for (; i < tot; i += st) {
        int n = i / 416, ch = i - n * 416;
        int b = n >> 8, m = n & 255;
        float v = 0.f;
        if (ch < 3) v = cm[(b * 3 + ch) * M_ + m];
        else if (ch < 387)
            v = (counts[n] > 0.f) ? nmax[(size_t)n * 384 + (ch - 3)]
                                  : first0[b * 384 + (ch - 3)];
        unsigned short u = f2b(v);
        fin2[n * 416 + ch] = u;
        cat[(size_t)n * 1184 + 768 + ch] = u;
    }
}

// node-MLP layer: one wave = 4 co-tiles sharing one act-frag set (4 indep chains)
template<int KS, int CTQ>   // CTQ = co-quads per node row
__global__ __launch_bounds__(256, 2) void nlayer4(const unsigned short* __restrict__ W,
        const float* __restrict__ bias, const unsigned short* __restrict__ actin,
        unsigned short* __restrict__ actout, int outs) {
    int wave = threadIdx.x >> 6, lane = threadIdx.x & 63;
    int id = blockIdx.x * 4 + wave;
    int nt = id / CTQ, cq = id - nt * CTQ;
    int r = lane & 15, g = lane >> 4;
    const unsigned short* arow = actin + (size_t)(nt * 16 + r) * (KS * 32) + g * 8;
    bf16x8 afr[KS];
    #pragma unroll
    for (int ks = 0; ks < KS; ks++) afr[ks] = *(const bf16x8*)(arow + ks * 32);
    const unsigned short* w0 = W + (cq * 64 + r) * (KS * 32) + g * 8;
    f32x4 acc[4];
    #pragma unroll
    for (int c = 0; c < 4; c++) acc[c] = (f32x4){0.f, 0.f, 0.f, 0.f};
    #pragma unroll
    for (int ks = 0; ks < KS; ks++) {
        #pragma unroll
        for (int c = 0; c < 4; c++) {
            bf16x8 wv = *(const bf16x8*)(w0 + c * 16 * KS * 32 + ks * 32);
            acc[c] = __builtin_amdgcn_mfma_f32_16x16x32_bf16(wv, afr[ks], acc[c], 0, 0, 0);
        }
    }
    #pragma unroll
    for (int c = 0; c < 4; c++) {
        f32x4 b4 = *(const f32x4*)(bias + cq * 64 + c * 16 + g * 4);
        uint2 s;
        s.x = (unsigned)f2b(fmaxf(acc[c][0] + b4[0], 0.f)) |
              ((unsigned)f2b(fmaxf(acc[c][1] + b4[1], 0.f)) << 16);
        s.y = (unsigned)f2b(fmaxf(acc[c][2] + b4[2], 0.f)) |
              ((unsigned)f2b(fmaxf(acc[c][3] + b4[3], 0.f)) << 16);
        *(uint2*)(actout + (size_t)(nt * 16 + r) * outs + cq * 64 + c * 16 + g * 4) = s;
    }
}

// last node layer (4 co-tiles/wave) + global max over nodes
template<int KS, int CTQ>
__global__ __launch_bounds__(256, 2) void nlayer_max4(const unsigned short* __restrict__ W,
        const float* __restrict__ bias, const unsigned short* __restrict__ actin,
        float* __restrict__ out) {
    int wave = threadIdx.x >> 6, lane = threadIdx.x & 63;
    int id = blockIdx.x * 4 + wave;
    int nt = id / CTQ, cq = id - nt * CTQ;
    int r = lane & 15, g = lane >> 4;
    const unsigned short* arow = actin + (size_t)(nt * 16 + r) * (KS * 32) + g * 8;
    bf16x8 afr[KS];
    #pragma unroll
    for (int ks = 0; ks < KS; ks++) afr[ks] = *(const bf16x8*)(arow + ks * 32);
    const unsigned short* w0 = W + (cq * 64 + r) * (KS * 32) + g * 8;
    f32x4 acc[4];
    #pragma unroll
    for (int c = 0; c < 4; c++) acc[c] = (f32x4){0.f, 0.f, 0.f, 0.f};
    #pragma unroll
    for (int ks = 0; ks < KS; ks++) {
        #pragma unroll
        for (int c = 0; c < 4; c++) {
            bf16x8 wv = *(const bf16x8*)(w0 + c * 16 * KS * 32 + ks * 32);
            acc[c] = __builtin_amdgcn_mfma_f32_16x16x32_bf16(wv, afr[ks], acc[c], 0, 0, 0);
        }
    }
    int b = nt >> 4;
    #pragma unroll
    for (int c = 0; c < 4; c++) {
        f32x4 b4 = *(const f32x4*)(bias + cq * 64 + c * 16 + g * 4);
        #pragma unroll
        for (int i = 0; i < 4; i++) {
            float v = fmaxf(acc[c][i] + b4[i], 0.f);
            v = fmaxf(v, __shfl_xor(v, 1));
            v = fmaxf(v, __shfl_xor(v, 2));
            v = fmaxf(v, __shfl_xor(v, 4));
            v = fmaxf(v, __shfl_xor(v, 8));
            if (r == 0)
                atomicMax((int*)&out[b * 1024 + cq * 64 + c * 16 + g * 4 + i],
                          __float_as_int(v));
        }
    }
}

extern "C" void kernel_launch(void* const* d_in, const int* in_sizes, int n_in,
                              void* d_out, int out_size, void* d_ws, size_t ws_size,
                              hipStream_t stream) {
    (void)in_sizes; (void)n_in; (void)out_size; (void)ws_size;
    const float* x    = (const float*)d_in[0];
    const float* node = (const float*)d_in[2];
    const float* fpw[4] = {(const float*)d_in[4], (const float*)d_in[6],
                           (const float*)d_in[8], (const float*)d_in[10]};
    const float* fpb[4] = {(const float*)d_in[5], (const float*)d_in[7],
                           (const float*)d_in[9], (const float*)d_in[11]};
    const float* fnw[4] = {(const float*)d_in[12], (const float*)d_in[14],
                           (const float*)d_in[16], (const float*)d_in[18]};
    const float* fnb[4] = {(const float*)d_in[13], (const float*)d_in[15],
                           (const float*)d_in[17], (const float*)d_in[19]};
    float* ws  = (float*)d_ws;
    float* out = (float*)d_out;
    unsigned short* wb   = (unsigned short*)(ws + OFF_WBF);
    unsigned short* fin2 = (unsigned short*)(ws + OFF_FIN2);
    unsigned short* h0   = (unsigned short*)(ws + OFF_H0);
    unsigned short* h1   = (unsigned short*)(ws + OFF_H1);
    unsigned short* catb = (unsigned short*)(ws + OFF_CAT);

    setup<<<2048, 256, 0, stream>>>(fpw[0], fpw[1], fpw[2], fpw[3],
                                    fnw[0], fnw[1], fnw[2], fnw[3], wb, ws, out);
    knn_assign<<<dim3(N_ / 256, B_), 256, 0, stream>>>(
        x, node, (int*)(ws + OFF_KNN), ws + OFF_COUNTS, ws + OFF_SUMS);
    cmean_scan<<<B_, 256, 0, stream>>>(
        ws + OFF_COUNTS, ws + OFF_SUMS, ws + OFF_CM, (int*)(ws + OFF_OFFS));
    scatter<<<B_ * KNN_ * N_ / 256, 256, 0, stream>>>(
        (int*)(ws + OFF_KNN), (int*)(ws + OFF_OFFS), (int*)(ws + OFF_CURSOR),
        (int*)(ws + OFF_SORTED), (int*)(ws + OFF_MSORT));
    mlp1m<<<dim3(KNN_ * N_ / 64, B_), 256, 0, stream>>>(
        x, ws + OFF_CM, (int*)(ws + OFF_SORTED), (int*)(ws + OFF_MSORT), wb,
        fpb[0], fpb[1], fpb[2], fpb[3], ws + OFF_NODEMAX, ws + OFF_FIRST0);
    build_fin2<<<3328, 256, 0, stream>>>(
        ws + OFF_CM, ws + OFF_COUNTS, ws + OFF_NODEMAX, ws + OFF_FIRST0, fin2, catb);
    nlayer4<13, 8><<<256,  256, 0, stream>>>(wb + O_V0, fnb[0], fin2, h0, 512);
    nlayer4<16, 8><<<256,  256, 0, stream>>>(wb + O_V1, fnb[1], h0, h1, 512);
    nlayer4<16, 12><<<384, 256, 0, stream>>>(wb + O_V2, fnb[2], h1, catb, 1184);
    nlayer_max4<37, 16><<<512, 256, 0, stream>>>(wb + O_V3, fnb[3], catb, out);
}

// Round 7
// 232.394 us; speedup vs baseline: 4.7379x; 1.0732x over previous
//
#include <hip/hip_runtime.h>
#include <math.h>

#define B_   8
#define N_   4096
#define M_   256
#define KNN_ 3

// ---- workspace layout (float element offsets) ----
#define OFF_COUNTS   0          // [8][256] f32
#define OFF_SUMS     2048       // [8][256][3] f32
#define OFF_CM       8192       // [8][3][256] f32
#define OFF_NODEMAX  14336      // [8][256][384] f32 ; H0 aliases (phase2)
#define OFF_H0       14336      // ushort [2048][512]
#define OFF_FIRST0   800768     // [8][384] f32
#define OFF_CURSOR   803840     // [8][256] int
#define ZERO_COUNT   805888     // memset range (floats)
#define OFF_OFFS     805888     // [8][257] int
#define OFF_KNN      807944     // [8][4096][3] int ; CAT aliases (phase2)
#define OFF_CAT      807944     // ushort [2048][1184]
#define OFF_SORTED   906248     // [8][12288] int
#define OFF_MSORT    1004552    // [8][12288] int
#define OFF_FIN2     2020360    // ushort [2048][416] ; H1 aliases
#define OFF_H1       2020360    // ushort [2048][512]
#define OFF_WBF      2544648    // bf16 weights (ushort)
#define OFF_W3X      3661832    // f32x4 [384] (W3 cols 256..258)
// bf16 padded weight offsets (USHORT units, relative to wb base; contiguous)
#define O_W0 0         // 64   x 32
#define O_W1 2048      // 128  x 64
#define O_W2 10240     // 256  x 128
#define O_W3 43008     // 384  x 288
#define O_V0 153600    // 512  x 416
#define O_V1 366592    // 512  x 512
#define O_V2 628736    // 768  x 512
#define O_V3 1021952   // 1024 x 1184
#define W_TOTAL 2234368

typedef short  bf16x8 __attribute__((ext_vector_type(8)));
typedef float  f32x4  __attribute__((ext_vector_type(4)));

__device__ __forceinline__ unsigned short f2b(float f) {
    unsigned u = __float_as_uint(f);
    return (unsigned short)((u + 0x7FFFu + ((u >> 16) & 1u)) >> 16);
}
// HW packed bf16 convert (RNE), 2 f32 -> 1 dword
__device__ __forceinline__ unsigned cvt2(float lo, float hi) {
    unsigned r;
    asm("v_cvt_pk_bf16_f32 %0, %1, %2" : "=v"(r) : "v"(lo), "v"(hi));
    return r;
}

// fused: blocks 0..127 = KNN assign; blocks 128+ = weight pad/convert + w3x
__global__ __launch_bounds__(256) void knn_setup(
        const float* __restrict__ x, const float* __restrict__ node,
        int* __restrict__ knn, float* __restrict__ counts, float* __restrict__ sums,
        const float* s0, const float* s1, const float* s2, const float* s3,
        const float* s4, const float* s5, const float* s6, const float* s7,
        unsigned short* __restrict__ dst, float* __restrict__ w3x) {
    __shared__ float nd0[M_], nd1[M_], nd2[M_], nn2[M_];
    int t = threadIdx.x;
    if (blockIdx.x < 128) {
        int b = blockIdx.x >> 4, xblk = blockIdx.x & 15;
        {
            float c0 = node[(b * 3 + 0) * M_ + t];
            float c1 = node[(b * 3 + 1) * M_ + t];
            float c2 = node[(b * 3 + 2) * M_ + t];
            nd0[t] = c0; nd1[t] = c1; nd2[t] = c2;
            nn2[t] = c0 * c0 + c1 * c1 + c2 * c2;
        }
        __syncthreads();
        int n = xblk * 256 + t;
        float x0 = x[(b * 3 + 0) * N_ + n];
        float x1 = x[(b * 3 + 1) * N_ + n];
        float x2 = x[(b * 3 + 2) * N_ + n];
        float xx = x0 * x0 + x1 * x1 + x2 * x2;
        float d0 = 1e30f, d1 = 1e30f, d2b = 1e30f;
        int i0 = 0, i1 = 0, i2 = 0;
        for (int m = 0; m < M_; m++) {
            float cross = x0 * nd0[m] + x1 * nd1[m] + x2 * nd2[m];
            float d = xx + nn2[m] - 2.f * cross;
            bool c0 = d < d0, c1 = d < d1, c2 = d < d2b;
            d2b = c1 ? d1 : (c2 ? d : d2b);
            i2  = c1 ? i1 : (c2 ? m : i2);
            d1  = c0 ? d0 : (c1 ? d : d1);
            i1  = c0 ? i0 : (c1 ? m : i1);
            d0  = c0 ? d  : d0;
            i0  = c0 ? m  : i0;
        }
        int base = (b * N_ + n) * 3;
        knn[base + 0] = i0; knn[base + 1] = i1; knn[base + 2] = i2;
        int mm[3] = {i0, i1, i2};
        #pragma unroll
        for (int k = 0; k < 3; k++) {
            int m = mm[k];
            atomicAdd(&counts[b * M_ + m], 1.f);
            atomicAdd(&sums[(b * M_ + m) * 3 + 0], x0);
            atomicAdd(&sums[(b * M_ + m) * 3 + 1], x1);
            atomicAdd(&sums[(b * M_ + m) * 3 + 2], x2);
        }
    } else {
        int i = (blockIdx.x - 128) * 256 + t;
        int st = (gridDim.x - 128) * 256;
        for (int j = i; j < 1536; j += st) {
            int ch = j >> 2, c = j & 3;
            w3x[j] = (c < 3) ? s3[ch * 259 + 256 + c] : 0.f;
        }
        for (; i < W_TOTAL; i += st) {
            const float* src; int base, cin, cinp;
            if      (i < O_W1) { src = s0; base = O_W0; cin = 3;    cinp = 32; }
            else if (i < O_W2) { src = s1; base = O_W1; cin = 64;   cinp = 64; }
            else if (i < O_W3) { src = s2; base = O_W2; cin = 128;  cinp = 128; }
            else if (i < O_V0) { src = s3; base = O_W3; cin = 259;  cinp = 288; }
            else if (i < O_V1) { src = s4; base = O_V0; cin = 387;  cinp = 416; }
            else if (i < O_V2) { src = s5; base = O_V1; cin = 512;  cinp = 512; }
            else if (i < O_V3) { src = s6; base = O_V2; cin = 512;  cinp = 512; }
            else               { src = s7; base = O_V3; cin = 1155; cinp = 1184; }
            int loc = i - base;
            int co = loc / cinp, k = loc - co * cinp;
            dst[i] = (k < cin) ? f2b(src[co * cin + k]) : (unsigned short)0;
        }
    }
}

// cluster means + exclusive scan of counts, one block per batch
__global__ __launch_bounds__(256) void cmean_scan(const float* __restrict__ counts,
        const float* __restrict__ sums, float* __restrict__ cm, int* __restrict__ offs) {
    __shared__ int tmp[256];
    int t = threadIdx.x, b = blockIdx.x;
    float cnt = counts[b * M_ + t];
    float inv = 1.f / (cnt + 1e-5f);
    #pragma unroll
    for (int c = 0; c < 3; c++)
        cm[(b * 3 + c) * M_ + t] = sums[(b * M_ + t) * 3 + c] * inv;
    int v = (int)cnt;
    tmp[t] = v;
    __syncthreads();
    for (int off = 1; off < 256; off <<= 1) {
        int u = (t >= off) ? tmp[t - off] : 0;
        __syncthreads();
        tmp[t] += u;
        __syncthreads();
    }
    offs[b * 257 + t] = tmp[t] - v;
    if (t == 255) offs[b * 257 + 256] = tmp[255];
}

__global__ __launch_bounds__(256) void scatter(const int* __restrict__ knn,
        const int* __restrict__ offs, int* __restrict__ cursor,
        int* __restrict__ sorted, int* __restrict__ msort) {
    int g = blockIdx.x * 256 + threadIdx.x;
    int b = g / (KNN_ * N_), j = g % (KNN_ * N_);
    int n = j & (N_ - 1), k = j >> 12;
    int m = knn[(b * N_ + n) * 3 + k];
    int pos = atomicAdd(&cursor[b * M_ + m], 1);
    int dst = offs[b * 257 + m] + pos;
    sorted[b * (KNN_ * N_) + dst] = j;
    msort[b * (KNN_ * N_) + dst] = m;
}

// B-stationary layer: wave holds B-frags for ALL 4 p-tiles in regs,
// owns CTW co-tiles, streams W. 4 independent MFMA chains.
template<int KS, int INS, int OUTS, int CTW>
__device__ __forceinline__ void layerB(const unsigned short* __restrict__ Wg,
        const float* __restrict__ bias, const unsigned short* actin,
        unsigned short* actout, int wave, int lane) {
    int r = lane & 15, g = lane >> 4;
    bf16x8 bfr[4][KS];
    #pragma unroll
    for (int pt = 0; pt < 4; pt++) {
        const unsigned short* arow = actin + (pt * 16 + r) * INS + g * 8;
        #pragma unroll
        for (int ks = 0; ks < KS; ks++)
            bfr[pt][ks] = *(const bf16x8*)(arow + ks * 32);
    }
    #pragma unroll
    for (int c = 0; c < CTW; c++) {
        int ct = wave * CTW + c;
        const unsigned short* wrow = Wg + (ct * 16 + r) * (KS * 32) + g * 8;
        f32x4 acc[4];
        #pragma unroll
        for (int pt = 0; pt < 4; pt++) acc[pt] = (f32x4){0.f, 0.f, 0.f, 0.f};
        #pragma unroll
        for (int ks = 0; ks < KS; ks++) {
            bf16x8 wv = *(const bf16x8*)(wrow + ks * 32);
            #pragma unroll
            for (int pt = 0; pt < 4; pt++)
                acc[pt] = __builtin_amdgcn_mfma_f32_16x16x32_bf16(wv, bfr[pt][ks], acc[pt], 0, 0, 0);
        }
        f32x4 b4 = *(const f32x4*)(bias + ct * 16 + g * 4);
        #pragma unroll
        for (int pt = 0; pt < 4; pt++) {
            uint2 s;
            s.x = cvt2(fmaxf(acc[pt][0] + b4[0], 0.f), fmaxf(acc[pt][1] + b4[1], 0.f));
            s.y = cvt2(fmaxf(acc[pt][2] + b4[2], 0.f), fmaxf(acc[pt][3] + b4[3], 0.f));
            *(uint2*)(actout + (pt * 16 + r) * OUTS + ct * 16 + g * 4) = s;
        }
    }
}

// MFMA point-MLP over sorted entries, 64 points/block, ~52.5 KB LDS (3 blocks/CU).
// L4 ks=8 tile (xd, 3 of 32 K nonzero) replaced by VALU from xdf + w3x.
__global__ __launch_bounds__(256, 3) void mlp1m(
        const float* __restrict__ x, const float* __restrict__ cm,
        const int* __restrict__ sorted, const int* __restrict__ msort,
        const unsigned short* __restrict__ wb, const float4* __restrict__ w3x,
        const float* __restrict__ bb0, const float* __restrict__ bb1,
        const float* __restrict__ bb2, const float* __restrict__ bb3,
        float* __restrict__ node_max, float* __restrict__ first0) {
    __shared__ __align__(16) char smem[50688];
    // arena A (0..16896): inb [64][40] -> a1 [64][132]
    // arena B (16896..50688): a0 [64][72] -> cat [64][264]
    unsigned short* inb = (unsigned short*)smem;
    unsigned short* a1  = (unsigned short*)smem;
    unsigned short* a0  = (unsigned short*)(smem + 16896);
    unsigned short* cat = (unsigned short*)(smem + 16896);
    __shared__ float4 xdf[64];
    __shared__ int midx[64], segm[65], segstart[66];
    __shared__ int nseg, p0loc;
    int t = threadIdx.x, b = blockIdx.y, lane = t & 63, wave = t >> 6;
    int e0 = blockIdx.x * 64;
    for (int e = t; e < 1280; e += 256) ((unsigned*)inb)[e] = 0u;   // zero inb [64][40]
    __syncthreads();
    if (t < 64) {   // wave 0: per-point init + ballot segment scan
        int p = t;
        if (p == 0) p0loc = -1;
        int j = sorted[b * 12288 + e0 + p];
        int m = msort[b * 12288 + e0 + p];
        int n = j & (N_ - 1);
        midx[p] = m;
        float xd0 = x[(b * 3 + 0) * N_ + n] - cm[(b * 3 + 0) * M_ + m];
        float xd1 = x[(b * 3 + 1) * N_ + n] - cm[(b * 3 + 1) * M_ + m];
        float xd2 = x[(b * 3 + 2) * N_ + n] - cm[(b * 3 + 2) * M_ + m];
        xdf[p] = make_float4(xd0, xd1, xd2, 0.f);
        inb[p * 40 + 0] = f2b(xd0);
        inb[p * 40 + 1] = f2b(xd1);
        inb[p * 40 + 2] = f2b(xd2);
        int prev = __shfl_up(m, 1);
        bool flag = (p == 0) || (m != prev);
        unsigned long long mk = __ballot(flag);
        int sid = __popcll(mk & ((1ull << p) - 1ull));
        if (flag) { segstart[sid] = p; segm[sid] = m; }
        if (p == 63) { int ns2 = __popcll(mk); nseg = ns2; segstart[ns2] = 64; }
        if (j == 0) p0loc = p;
    }
    __syncthreads();
    layerB<1, 40, 72, 1>(wb + O_W0, bb0, inb, a0, wave, lane);     // inb -> a0
    __syncthreads();
    layerB<2, 72, 132, 2>(wb + O_W1, bb1, a0, a1, wave, lane);     // a0 -> a1 (over inb)
    __syncthreads();
    layerB<4, 132, 264, 4>(wb + O_W2, bb2, a1, cat, wave, lane);   // a1 -> cat (over a0)
    __syncthreads();
    // ---- L4: 384 x 256(+xd), barrier-free, per-wave 6 co-tiles ----
    int r = lane & 15, g = lane >> 4;
    bf16x8 bfr[4][8];
    #pragma unroll
    for (int pt = 0; pt < 4; pt++) {
        const unsigned short* arow = cat + (pt * 16 + r) * 264 + g * 8;
        #pragma unroll
        for (int ks = 0; ks < 8; ks++)
            bfr[pt][ks] = *(const bf16x8*)(arow + ks * 32);
    }
    int ns = nseg, p0l = p0loc;
    #pragma unroll
    for (int c = 0; c < 6; c++) {
        int ct = wave * 6 + c;
        const unsigned short* wrow = wb + O_W3 + (ct * 16 + r) * 288 + g * 8;
        f32x4 acc[4];
        #pragma unroll
        for (int pt = 0; pt < 4; pt++) acc[pt] = (f32x4){0.f, 0.f, 0.f, 0.f};
        #pragma unroll
        for (int ks = 0; ks < 8; ks++) {
            bf16x8 wv = *(const bf16x8*)(wrow + ks * 32);
            #pragma unroll
            for (int pt = 0; pt < 4; pt++)
                acc[pt] = __builtin_amdgcn_mfma_f32_16x16x32_bf16(wv, bfr[pt][ks], acc[pt], 0, 0, 0);
        }
        f32x4 b4 = *(const f32x4*)(bb3 + ct * 16 + g * 4);
        float v[4][4];
        #pragma unroll
        for (int i = 0; i < 4; i++) {
            float4 wx = w3x[ct * 16 + g * 4 + i];
            #pragma unroll
            for (int pt = 0; pt < 4; pt++) {
                float4 xv = xdf[pt * 16 + r];
                float s = acc[pt][i] + b4[i] + wx.x * xv.x + wx.y * xv.y + wx.z * xv.z;
                v[pt][i] = fmaxf(s, 0.f);
            }
        }
        if (p0l >= 0) {
            #pragma unroll
            for (int pt = 0; pt < 4; pt++)
                if (p0l == pt * 16 + r) {
                    #pragma unroll
                    for (int i = 0; i < 4; i++)
                        first0[b * 384 + ct * 16 + g * 4 + i] = v[pt][i];
                }
        }
        for (int s = 0; s < ns; s++) {
            int s0 = segstart[s], s1 = segstart[s + 1];
            float mx0 = 0.f, mx1 = 0.f, mx2 = 0.f, mx3 = 0.f;
            #pragma unroll
            for (int pt = 0; pt < 4; pt++) {
                int p = pt * 16 + r;
                bool in = (p >= s0) && (p < s1);
                mx0 = fmaxf(mx0, in ? v[pt][0] : 0.f);
                mx1 = fmaxf(mx1, in ? v[pt][1] : 0.f);
                mx2 = fmaxf(mx2, in ? v[pt][2] : 0.f);
                mx3 = fmaxf(mx3, in ? v[pt][3] : 0.f);
            }
            #pragma unroll
            for (int sh = 1; sh < 16; sh <<= 1) {
                mx0 = fmaxf(mx0, __shfl_xor(mx0, sh));
                mx1 = fmaxf(mx1, __shfl_xor(mx1, sh));
                mx2 = fmaxf(mx2, __shfl_xor(mx2, sh));
                mx3 = fmaxf(mx3, __shfl_xor(mx3, sh));
            }
            if (r == 0) {
                float* dst = &node_max[(size_t)(b * M_ + segm[s]) * 384 + ct * 16 + g * 4];
                atomicMax((int*)(dst + 0), __float_as_int(mx0));
                atomicMax((int*)(dst + 1), __float_as_int(mx1));
                atomicMax((int*)(dst + 2), __float_as_int(mx2));
                atomicMax((int*)(dst + 3), __float_as_int(mx3));
            }
        }
    }
}

// masked node features -> bf16 fin2 [2048][416] and cat tail cols 768..1183
__global__ void build_fin2(const float* __restrict__ cm, const float* __restrict__ counts,
                           const float* __restrict__ nmax, const float* __restrict__ first0,
                           unsigned short* __restrict__ fin2, unsigned short* __restrict__ cat) {
    int tot = 2048 * 416;
    int i = blockIdx.x * blockDim.x + threadIdx.x;
    int st = gridDim.x * blockDim.x;
    for (; i < tot; i += st) {
        int n = i / 416, ch = i - n * 416;
        int b = n >> 8, m = n & 255;
        float v = 0.f;
        if (ch < 3) v = cm[(b * 3 + ch) * M_ + m];
        else if (ch < 387)
            v = (counts[n] > 0.f) ? nmax[(size_t)n * 384 + (ch - 3)]
                                  : first0[b * 384 + (ch - 3)];
        unsigned short u = f2b(v);
        fin2[n * 416 + ch] = u;
        cat[(size_t)n * 1184 + 768 + ch] = u;
    }
}

// node-MLP layer: one wave = 4 co-tiles sharing one act-frag set (4 indep chains)
template<int KS, int CTQ>
__global__ __launch_bounds__(256, 2) void nlayer4(const unsigned short* __restrict__ W,
        const float* __restrict__ bias, const unsigned short* __restrict__ actin,
        unsigned short* __restrict__ actout, int outs) {
    int wave = threadIdx.x >> 6, lane = threadIdx.x & 63;
    int id = blockIdx.x * 4 + wave;
    int nt = id / CTQ, cq = id - nt * CTQ;
    int r = lane & 15, g = lane >> 4;
    const unsigned short* arow = actin + (size_t)(nt * 16 + r) * (KS * 32) + g * 8;
    bf16x8 afr[KS];
    #pragma unroll
    for (int ks = 0; ks < KS; ks++) afr[ks] = *(const bf16x8*)(arow + ks * 32);
    const unsigned short* w0 = W + (cq * 64 + r) * (KS * 32) + g * 8;
    f32x4 acc[4];
    #pragma unroll
    for (int c = 0; c < 4; c++) acc[c] = (f32x4){0.f, 0.f, 0.f, 0.f};
    #pragma unroll
    for (int ks = 0; ks < KS; ks++) {
        #pragma unroll
        for (int c = 0; c < 4; c++) {
            bf16x8 wv = *(const bf16x8*)(w0 + c * 16 * KS * 32 + ks * 32);
            acc[c] = __builtin_amdgcn_mfma_f32_16x16x32_bf16(wv, afr[ks], acc[c], 0, 0, 0);
        }
    }
    #pragma unroll
    for (int c = 0; c < 4; c++) {
        f32x4 b4 = *(const f32x4*)(bias + cq * 64 + c * 16 + g * 4);
        uint2 s;
        s.x = cvt2(fmaxf(acc[c][0] + b4[0], 0.f), fmaxf(acc[c][1] + b4[1], 0.f));
        s.y = cvt2(fmaxf(acc[c][2] + b4[2], 0.f), fmaxf(acc[c][3] + b4[3], 0.f));
        *(uint2*)(actout + (size_t)(nt * 16 + r) * outs + cq * 64 + c * 16 + g * 4) = s;
    }
}

// last node layer (4 co-tiles/wave) + global max over nodes
template<int KS, int CTQ>
__global__ __launch_bounds__(256, 2) void nlayer_max4(const unsigned short* __restrict__ W,
        const float* __restrict__ bias, const unsigned short* __restrict__ actin,
        float* __restrict__ out) {
    int wave = threadIdx.x >> 6, lane = threadIdx.x & 63;
    int id = blockIdx.x * 4 + wave;
    int nt = id / CTQ, cq = id - nt * CTQ;
    int r = lane & 15, g = lane >> 4;
    const unsigned short* arow = actin + (size_t)(nt * 16 + r) * (KS * 32) + g * 8;
    bf16x8 afr[KS];
    #pragma unroll
    for (int ks = 0; ks < KS; ks++) afr[ks] = *(const bf16x8*)(arow + ks * 32);
    const unsigned short* w0 = W + (cq * 64 + r) * (KS * 32) + g * 8;
    f32x4 acc[4];
    #pragma unroll
    for (int c = 0; c < 4; c++) acc[c] = (f32x4){0.f, 0.f, 0.f, 0.f};
    #pragma unroll
    for (int ks = 0; ks < KS; ks++) {
        #pragma unroll
        for (int c = 0; c < 4; c++) {
            bf16x8 wv = *(const bf16x8*)(w0 + c * 16 * KS * 32 + ks * 32);
            acc[c] = __builtin_amdgcn_mfma_f32_16x16x32_bf16(wv, afr[ks], acc[c], 0, 0, 0);
        }
    }
    int b = nt >> 4;
    #pragma unroll
    for (int c = 0; c < 4; c++) {
        f32x4 b4 = *(const f32x4*)(bias + cq * 64 + c * 16 + g * 4);
        #pragma unroll
        for (int i = 0; i < 4; i++) {
            float v = fmaxf(acc[c][i] + b4[i], 0.f);
            v = fmaxf(v, __shfl_xor(v, 1));
            v = fmaxf(v, __shfl_xor(v, 2));
            v = fmaxf(v, __shfl_xor(v, 4));
            v = fmaxf(v, __shfl_xor(v, 8));
            if (r == 0)
                atomicMax((int*)&out[b * 1024 + cq * 64 + c * 16 + g * 4 + i],
                          __float_as_int(v));
        }
    }
}

extern "C" void kernel_launch(void* const* d_in, const int* in_sizes, int n_in,
                              void* d_out, int out_size, void* d_ws, size_t ws_size,
                              hipStream_t stream) {
    (void)in_sizes; (void)n_in; (void)out_size; (void)ws_size;
    const float* x    = (const float*)d_in[0];
    const float* node = (const float*)d_in[2];
    const float* fpw[4] = {(const float*)d_in[4], (const float*)d_in[6],
                           (const float*)d_in[8], (const float*)d_in[10]};
    const float* fpb[4] = {(const float*)d_in[5], (const float*)d_in[7],
                           (const float*)d_in[9], (const float*)d_in[11]};
    const float* fnw[4] = {(const float*)d_in[12], (const float*)d_in[14],
                           (const float*)d_in[16], (const float*)d_in[18]};
    const float* fnb[4] = {(const float*)d_in[13], (const float*)d_in[15],
                           (const float*)d_in[17], (const float*)d_in[19]};
    float* ws  = (float*)d_ws;
    float* out = (float*)d_out;
    unsigned short* wb   = (unsigned short*)(ws + OFF_WBF);
    unsigned short* fin2 = (unsigned short*)(ws + OFF_FIN2);
    unsigned short* h0   = (unsigned short*)(ws + OFF_H0);
    unsigned short* h1   = (unsigned short*)(ws + OFF_H1);
    unsigned short* catb = (unsigned short*)(ws + OFF_CAT);

    hipMemsetAsync(ws, 0, (size_t)ZERO_COUNT * 4, stream);
    hipMemsetAsync(out, 0, (size_t)B_ * 1024 * 4, stream);

    knn_setup<<<128 + 2048, 256, 0, stream>>>(
        x, node, (int*)(ws + OFF_KNN), ws + OFF_COUNTS, ws + OFF_SUMS,
        fpw[0], fpw[1], fpw[2], fpw[3], fnw[0], fnw[1], fnw[2], fnw[3],
        wb, ws + OFF_W3X);
    cmean_scan<<<B_, 256, 0, stream>>>(
        ws + OFF_COUNTS, ws + OFF_SUMS, ws + OFF_CM, (int*)(ws + OFF_OFFS));
    scatter<<<B_ * KNN_ * N_ / 256, 256, 0, stream>>>(
        (int*)(ws + OFF_KNN), (int*)(ws + OFF_OFFS), (int*)(ws + OFF_CURSOR),
        (int*)(ws + OFF_SORTED), (int*)(ws + OFF_MSORT));
    mlp1m<<<dim3(KNN_ * N_ / 64, B_), 256, 0, stream>>>(
        x, ws + OFF_CM, (int*)(ws + OFF_SORTED), (int*)(ws + OFF_MSORT), wb,
        (const float4*)(ws + OFF_W3X),
        fpb[0], fpb[1], fpb[2], fpb[3], ws + OFF_NODEMAX, ws + OFF_FIRST0);
    build_fin2<<<3328, 256, 0, stream>>>(
        ws + OFF_CM, ws + OFF_COUNTS, ws + OFF_NODEMAX, ws + OFF_FIRST0, fin2, catb);
    nlayer4<13, 8><<<256,  256, 0, stream>>>(wb + O_V0, fnb[0], fin2, h0, 512);
    nlayer4<16, 8><<<256,  256, 0, stream>>>(wb + O_V1, fnb[1], h0, h1, 512);
    nlayer4<16, 12><<<384, 256, 0, stream>>>(wb + O_V2, fnb[2], h1, catb, 1184);
    nlayer_max4<37, 16><<<512, 256, 0, stream>>>(wb + O_V3, fnb[3], catb, out);
}

// Round 8
// 194.518 us; speedup vs baseline: 5.6604x; 1.1947x over previous
//
#include <hip/hip_runtime.h>
#include <math.h>

#define B_   8
#define N_   4096
#define M_   256
#define KNN_ 3

// ---- workspace layout (float element offsets) ----
#define OFF_COUNTS   0          // [8][256] f32
#define OFF_SUMS     2048       // [8][256][3] f32
#define OFF_CM       8192       // [8][3][256] f32
#define OFF_NODEMAX  14336      // [8][256][384] f32 ; H0 aliases (phase2)
#define OFF_H0       14336      // ushort [2048][512]
#define OFF_FIRST0   800768     // [8][384] f32
#define OFF_CURSOR   803840     // [8][256] int
#define ZERO_COUNT   805888     // memset range (floats)
#define OFF_OFFS     805888     // [8][257] int
#define OFF_KNN      807944     // [8][4096][3] int ; CAT aliases (phase2)
#define OFF_CAT      807944     // ushort [2048][1184]
#define OFF_SORTED   906248     // [8][12288] int
#define OFF_MSORT    1004552    // [8][12288] int
#define OFF_FIN2     2020360    // ushort [2048][416] ; H1 aliases
#define OFF_H1       2020360    // ushort [2048][512]
#define OFF_WBF      2544648    // bf16 weights (ushort)
#define OFF_W3X      3661832    // f32x4 [384] (W3 cols 256..258)
// bf16 padded weight offsets (USHORT units, relative to wb base; contiguous)
#define O_W0 0         // 64   x 32
#define O_W1 2048      // 128  x 64
#define O_W2 10240     // 256  x 128
#define O_W3 43008     // 384  x 288
#define O_V0 153600    // 512  x 416
#define O_V1 366592    // 512  x 512
#define O_V2 628736    // 768  x 512
#define O_V3 1021952   // 1024 x 1184
#define W_TOTAL 2234368

typedef short  bf16x8 __attribute__((ext_vector_type(8)));
typedef float  f32x4  __attribute__((ext_vector_type(4)));
typedef float  f32x16 __attribute__((ext_vector_type(16)));

__device__ __forceinline__ unsigned short f2b(float f) {
    unsigned u = __float_as_uint(f);
    return (unsigned short)((u + 0x7FFFu + ((u >> 16) & 1u)) >> 16);
}
// HW packed bf16 convert (RNE), 2 f32 -> 1 dword
__device__ __forceinline__ unsigned cvt2(float lo, float hi) {
    unsigned r;
    asm("v_cvt_pk_bf16_f32 %0, %1, %2" : "=v"(r) : "v"(lo), "v"(hi));
    return r;
}
__device__ __forceinline__ f32x16 zero16() {
    f32x16 z;
    #pragma unroll
    for (int i = 0; i < 16; i++) z[i] = 0.f;
    return z;
}

// fused: blocks 0..127 = KNN assign; blocks 128+ = weight pad/convert + w3x
__global__ __launch_bounds__(256) void knn_setup(
        const float* __restrict__ x, const float* __restrict__ node,
        int* __restrict__ knn, float* __restrict__ counts, float* __restrict__ sums,
        const float* s0, const float* s1, const float* s2, const float* s3,
        const float* s4, const float* s5, const float* s6, const float* s7,
        unsigned short* __restrict__ dst, float* __restrict__ w3x) {
    __shared__ float nd0[M_], nd1[M_], nd2[M_], nn2[M_];
    int t = threadIdx.x;
    if (blockIdx.x < 128) {
        int b = blockIdx.x >> 4, xblk = blockIdx.x & 15;
        {
            float c0 = node[(b * 3 + 0) * M_ + t];
            float c1 = node[(b * 3 + 1) * M_ + t];
            float c2 = node[(b * 3 + 2) * M_ + t];
            nd0[t] = c0; nd1[t] = c1; nd2[t] = c2;
            nn2[t] = c0 * c0 + c1 * c1 + c2 * c2;
        }
        __syncthreads();
        int n = xblk * 256 + t;
        float x0 = x[(b * 3 + 0) * N_ + n];
        float x1 = x[(b * 3 + 1) * N_ + n];
        float x2 = x[(b * 3 + 2) * N_ + n];
        float xx = x0 * x0 + x1 * x1 + x2 * x2;
        float d0 = 1e30f, d1 = 1e30f, d2b = 1e30f;
        int i0 = 0, i1 = 0, i2 = 0;
        for (int m = 0; m < M_; m++) {
            float cross = x0 * nd0[m] + x1 * nd1[m] + x2 * nd2[m];
            float d = xx + nn2[m] - 2.f * cross;
            bool c0 = d < d0, c1 = d < d1, c2 = d < d2b;
            d2b = c1 ? d1 : (c2 ? d : d2b);
            i2  = c1 ? i1 : (c2 ? m : i2);
            d1  = c0 ? d0 : (c1 ? d : d1);
            i1  = c0 ? i0 : (c1 ? m : i1);
            d0  = c0 ? d  : d0;
            i0  = c0 ? m  : i0;
        }
        int base = (b * N_ + n) * 3;
        knn[base + 0] = i0; knn[base + 1] = i1; knn[base + 2] = i2;
        int mm[3] = {i0, i1, i2};
        #pragma unroll
        for (int k = 0; k < 3; k++) {
            int m = mm[k];
            atomicAdd(&counts[b * M_ + m], 1.f);
            atomicAdd(&sums[(b * M_ + m) * 3 + 0], x0);
            atomicAdd(&sums[(b * M_ + m) * 3 + 1], x1);
            atomicAdd(&sums[(b * M_ + m) * 3 + 2], x2);
        }
    } else {
        int i = (blockIdx.x - 128) * 256 + t;
        int st = (gridDim.x - 128) * 256;
        for (int j = i; j < 1536; j += st) {
            int ch = j >> 2, c = j & 3;
            w3x[j] = (c < 3) ? s3[ch * 259 + 256 + c] : 0.f;
        }
        for (; i < W_TOTAL; i += st) {
            const float* src; int base, cin, cinp;
            if      (i < O_W1) { src = s0; base = O_W0; cin = 3;    cinp = 32; }
            else if (i < O_W2) { src = s1; base = O_W1; cin = 64;   cinp = 64; }
            else if (i < O_W3) { src = s2; base = O_W2; cin = 128;  cinp = 128; }
            else if (i < O_V0) { src = s3; base = O_W3; cin = 259;  cinp = 288; }
            else if (i < O_V1) { src = s4; base = O_V0; cin = 387;  cinp = 416; }
            else if (i < O_V2) { src = s5; base = O_V1; cin = 512;  cinp = 512; }
            else if (i < O_V3) { src = s6; base = O_V2; cin = 512;  cinp = 512; }
            else               { src = s7; base = O_V3; cin = 1155; cinp = 1184; }
            int loc = i - base;
            int co = loc / cinp, k = loc - co * cinp;
            dst[i] = (k < cin) ? f2b(src[co * cin + k]) : (unsigned short)0;
        }
    }
}

// cluster means + exclusive scan of counts, one block per batch
__global__ __launch_bounds__(256) void cmean_scan(const float* __restrict__ counts,
        const float* __restrict__ sums, float* __restrict__ cm, int* __restrict__ offs) {
    __shared__ int tmp[256];
    int t = threadIdx.x, b = blockIdx.x;
    float cnt = counts[b * M_ + t];
    float inv = 1.f / (cnt + 1e-5f);
    #pragma unroll
    for (int c = 0; c < 3; c++)
        cm[(b * 3 + c) * M_ + t] = sums[(b * M_ + t) * 3 + c] * inv;
    int v = (int)cnt;
    tmp[t] = v;
    __syncthreads();
    for (int off = 1; off < 256; off <<= 1) {
        int u = (t >= off) ? tmp[t - off] : 0;
        __syncthreads();
        tmp[t] += u;
        __syncthreads();
    }
    offs[b * 257 + t] = tmp[t] - v;
    if (t == 255) offs[b * 257 + 256] = tmp[255];
}

__global__ __launch_bounds__(256) void scatter(const int* __restrict__ knn,
        const int* __restrict__ offs, int* __restrict__ cursor,
        int* __restrict__ sorted, int* __restrict__ msort) {
    int g = blockIdx.x * 256 + threadIdx.x;
    int b = g / (KNN_ * N_), j = g % (KNN_ * N_);
    int n = j & (N_ - 1), k = j >> 12;
    int m = knn[(b * N_ + n) * 3 + k];
    int pos = atomicAdd(&cursor[b * M_ + m], 1);
    int dst = offs[b * 257 + m] + pos;
    sorted[b * (KNN_ * N_) + dst] = j;
    msort[b * (KNN_ * N_) + dst] = m;
}

// B-stationary layer: wave holds B-frags for ALL 4 p-tiles in regs,
// owns CTW co-tiles, streams W. 4 independent MFMA chains.
template<int KS, int INS, int OUTS, int CTW>
__device__ __forceinline__ void layerB(const unsigned short* __restrict__ Wg,
        const float* __restrict__ bias, const unsigned short* actin,
        unsigned short* actout, int wave, int lane) {
    int r = lane & 15, g = lane >> 4;
    bf16x8 bfr[4][KS];
    #pragma unroll
    for (int pt = 0; pt < 4; pt++) {
        const unsigned short* arow = actin + (pt * 16 + r) * INS + g * 8;
        #pragma unroll
        for (int ks = 0; ks < KS; ks++)
            bfr[pt][ks] = *(const bf16x8*)(arow + ks * 32);
    }
    #pragma unroll
    for (int c = 0; c < CTW; c++) {
        int ct = wave * CTW + c;
        const unsigned short* wrow = Wg + (ct * 16 + r) * (KS * 32) + g * 8;
        f32x4 acc[4];
        #pragma unroll
        for (int pt = 0; pt < 4; pt++) acc[pt] = (f32x4){0.f, 0.f, 0.f, 0.f};
        #pragma unroll
        for (int ks = 0; ks < KS; ks++) {
            bf16x8 wv = *(const bf16x8*)(wrow + ks * 32);
            #pragma unroll
            for (int pt = 0; pt < 4; pt++)
                acc[pt] = __builtin_amdgcn_mfma_f32_16x16x32_bf16(wv, bfr[pt][ks], acc[pt], 0, 0, 0);
        }
        f32x4 b4 = *(const f32x4*)(bias + ct * 16 + g * 4);
        #pragma unroll
        for (int pt = 0; pt < 4; pt++) {
            uint2 s;
            s.x = cvt2(fmaxf(acc[pt][0] + b4[0], 0.f), fmaxf(acc[pt][1] + b4[1], 0.f));
            s.y = cvt2(fmaxf(acc[pt][2] + b4[2], 0.f), fmaxf(acc[pt][3] + b4[3], 0.f));
            *(uint2*)(actout + (pt * 16 + r) * OUTS + ct * 16 + g * 4) = s;
        }
    }
}

// MFMA point-MLP over sorted entries, 64 points/block, ~52.5 KB LDS (3 blocks/CU).
// L4: swapped-operand 32x32x16 MFMA (A=acts, B=W3): D col=channel, row=point.
// xd contribution (3 of K) via VALU from xdf + w3x. Seg-max in-register per lane.
__global__ __launch_bounds__(256, 3) void mlp1m(
        const float* __restrict__ x, const float* __restrict__ cm,
        const int* __restrict__ sorted, const int* __restrict__ msort,
        const unsigned short* __restrict__ wb, const float4* __restrict__ w3x,
        const float* __restrict__ bb0, const float* __restrict__ bb1,
        const float* __restrict__ bb2, const float* __restrict__ bb3,
        float* __restrict__ node_max, float* __restrict__ first0) {
    __shared__ __align__(16) char smem[50688];
    // arena A (0..16896): inb [64][40] -> a1 [64][132]
    // arena B (16896..50688): a0 [64][72] -> cat [64][264]
    unsigned short* inb = (unsigned short*)smem;
    unsigned short* a1  = (unsigned short*)smem;
    unsigned short* a0  = (unsigned short*)(smem + 16896);
    unsigned short* cat = (unsigned short*)(smem + 16896);
    __shared__ float4 xdf[64];
    __shared__ int segm[65], segstart[66];
    __shared__ int nseg, p0loc;
    int t = threadIdx.x, b = blockIdx.y, lane = t & 63, wave = t >> 6;
    int e0 = blockIdx.x * 64;
    for (int e = t; e < 1280; e += 256) ((unsigned*)inb)[e] = 0u;   // zero inb [64][40]
    __syncthreads();
    if (t < 64) {   // wave 0: per-point init + ballot segment scan
        int p = t;
        if (p == 0) p0loc = -1;
        int j = sorted[b * 12288 + e0 + p];
        int m = msort[b * 12288 + e0 + p];
        int n = j & (N_ - 1);
        float xd0 = x[(b * 3 + 0) * N_ + n] - cm[(b * 3 + 0) * M_ + m];
        float xd1 = x[(b * 3 + 1) * N_ + n] - cm[(b * 3 + 1) * M_ + m];
        float xd2 = x[(b * 3 + 2) * N_ + n] - cm[(b * 3 + 2) * M_ + m];
        xdf[p] = make_float4(xd0, xd1, xd2, 0.f);
        inb[p * 40 + 0] = f2b(xd0);
        inb[p * 40 + 1] = f2b(xd1);
        inb[p * 40 + 2] = f2b(xd2);
        int prev = __shfl_up(m, 1);
        bool flag = (p == 0) || (m != prev);
        unsigned long long mk = __ballot(flag);
        int sid = __popcll(mk & ((1ull << p) - 1ull));
        if (flag) { segstart[sid] = p; segm[sid] = m; }
        if (p == 63) { int ns2 = __popcll(mk); nseg = ns2; segstart[ns2] = 64; }
        if (j == 0) p0loc = p;
    }
    __syncthreads();
    layerB<1, 40, 72, 1>(wb + O_W0, bb0, inb, a0, wave, lane);     // inb -> a0
    __syncthreads();
    layerB<2, 72, 132, 2>(wb + O_W1, bb1, a0, a1, wave, lane);     // a0 -> a1 (over inb)
    __syncthreads();
    layerB<4, 132, 264, 4>(wb + O_W2, bb2, a1, cat, wave, lane);   // a1 -> cat (over a0)
    __syncthreads();
    // ---- L4: 12 co-tiles of 32 x 4 waves (3 each), 2 point-halves, K=256 ----
    int l31 = lane & 31, half = lane >> 5;
    f32x16 acc[6];   // [c3*2 + ph]
    #pragma unroll
    for (int q = 0; q < 6; q++) acc[q] = zero16();
    {
        const unsigned short* arow0 = cat + l31 * 264 + half * 8;
        const unsigned short* arow1 = cat + (32 + l31) * 264 + half * 8;
        const unsigned short* wrowb = wb + O_W3 + (wave * 96 + l31) * 288 + half * 8;
        #pragma unroll
        for (int ks = 0; ks < 16; ks++) {
            bf16x8 aA = *(const bf16x8*)(arow0 + ks * 16);
            bf16x8 aB = *(const bf16x8*)(arow1 + ks * 16);
            #pragma unroll
            for (int c3 = 0; c3 < 3; c3++) {
                bf16x8 wv = *(const bf16x8*)(wrowb + c3 * 32 * 288 + ks * 16);
                acc[c3 * 2 + 0] = __builtin_amdgcn_mfma_f32_32x32x16_bf16(aA, wv, acc[c3 * 2 + 0], 0, 0, 0);
                acc[c3 * 2 + 1] = __builtin_amdgcn_mfma_f32_32x32x16_bf16(aB, wv, acc[c3 * 2 + 1], 0, 0, 0);
            }
        }
    }
    int ns = nseg, p0l = p0loc;
    float bias3[3]; float4 wx3[3];
    #pragma unroll
    for (int c3 = 0; c3 < 3; c3++) {
        bias3[c3] = bb3[(wave * 3 + c3) * 32 + l31];
        wx3[c3]   = w3x[(wave * 3 + c3) * 32 + l31];
    }
    // bias + xd-contrib + ReLU, in place
    #pragma unroll
    for (int ph = 0; ph < 2; ph++) {
        #pragma unroll
        for (int rg = 0; rg < 16; rg++) {
            int row = ph * 32 + (rg & 3) + 8 * (rg >> 2) + 4 * half;
            float4 xv = xdf[row];
            #pragma unroll
            for (int c3 = 0; c3 < 3; c3++) {
                float s = acc[c3 * 2 + ph][rg] + bias3[c3]
                        + wx3[c3].x * xv.x + wx3[c3].y * xv.y + wx3[c3].z * xv.z;
                acc[c3 * 2 + ph][rg] = fmaxf(s, 0.f);
            }
        }
    }
    if (p0l >= 0) {   // first-point channel values (one block per batch)
        #pragma unroll
        for (int ph = 0; ph < 2; ph++)
            #pragma unroll
            for (int rg = 0; rg < 16; rg++) {
                int row = ph * 32 + (rg & 3) + 8 * (rg >> 2) + 4 * half;
                if (row == p0l) {
                    #pragma unroll
                    for (int c3 = 0; c3 < 3; c3++)
                        first0[b * 384 + (wave * 3 + c3) * 32 + l31] = acc[c3 * 2 + ph][rg];
                }
            }
    }
    for (int s = 0; s < ns; s++) {
        int s0 = segstart[s], s1 = segstart[s + 1];
        float m0 = 0.f, m1 = 0.f, m2 = 0.f;
        if (s0 < 32) {
            #pragma unroll
            for (int rg = 0; rg < 16; rg++) {
                int row = (rg & 3) + 8 * (rg >> 2) + 4 * half;
                bool in = (row >= s0) && (row < s1);
                m0 = fmaxf(m0, in ? acc[0][rg] : 0.f);
                m1 = fmaxf(m1, in ? acc[2][rg] : 0.f);
                m2 = fmaxf(m2, in ? acc[4][rg] : 0.f);
            }
        }
        if (s1 > 32) {
            #pragma unroll
            for (int rg = 0; rg < 16; rg++) {
                int row = 32 + (rg & 3) + 8 * (rg >> 2) + 4 * half;
                bool in = (row >= s0) && (row < s1);
                m0 = fmaxf(m0, in ? acc[1][rg] : 0.f);
                m1 = fmaxf(m1, in ? acc[3][rg] : 0.f);
                m2 = fmaxf(m2, in ? acc[5][rg] : 0.f);
            }
        }
        m0 = fmaxf(m0, __shfl_xor(m0, 32));
        m1 = fmaxf(m1, __shfl_xor(m1, 32));
        m2 = fmaxf(m2, __shfl_xor(m2, 32));
        if (lane < 32) {
            float* dstp = &node_max[(size_t)(b * M_ + segm[s]) * 384 + wave * 96];
            atomicMax((int*)(dstp + l31),      __float_as_int(m0));
            atomicMax((int*)(dstp + 32 + l31), __float_as_int(m1));
            atomicMax((int*)(dstp + 64 + l31), __float_as_int(m2));
        }
    }
}

// masked node features -> bf16 fin2 [2048][416] and cat tail cols 768..1183
__global__ void build_fin2(const float* __restrict__ cm, const float* __restrict__ counts,
                           const float* __restrict__ nmax, const float* __restrict__ first0,
                           unsigned short* __restrict__ fin2, unsigned short* __restrict__ cat) {
    int tot = 2048 * 416;
    int i = blockIdx.x * blockDim.x + threadIdx.x;
    int st = gridDim.x * blockDim.x;
    for (; i < tot; i += st) {
        int n = i / 416, ch = i - n * 416;
        int b = n >> 8, m = n & 255;
        float v = 0.f;
        if (ch < 3) v = cm[(b * 3 + ch) * M_ + m];
        else if (ch < 387)
            v = (counts[n] > 0.f) ? nmax[(size_t)n * 384 + (ch - 3)]
                                  : first0[b * 384 + (ch - 3)];
        unsigned short u = f2b(v);
        fin2[n * 416 + ch] = u;
        cat[(size_t)n * 1184 + 768 + ch] = u;
    }
}

// node-MLP layer: one wave = 4 co-tiles sharing one act-frag set (4 indep chains)
template<int KS, int CTQ>
__global__ __launch_bounds__(256, 2) void nlayer4(const unsigned short* __restrict__ W,
        const float* __restrict__ bias, const unsigned short* __restrict__ actin,
        unsigned short* __restrict__ actout, int outs) {
    int wave = threadIdx.x >> 6, lane = threadIdx.x & 63;
    int id = blockIdx.x * 4 + wave;
    int nt = id / CTQ, cq = id - nt * CTQ;
    int r = lane & 15, g = lane >> 4;
    const unsigned short* arow = actin + (size_t)(nt * 16 + r) * (KS * 32) + g * 8;
    bf16x8 afr[KS];
    #pragma unroll
    for (int ks = 0; ks < KS; ks++) afr[ks] = *(const bf16x8*)(arow + ks * 32);
    const unsigned short* w0 = W + (cq * 64 + r) * (KS * 32) + g * 8;
    f32x4 acc[4];
    #pragma unroll
    for (int c = 0; c < 4; c++) acc[c] = (f32x4){0.f, 0.f, 0.f, 0.f};
    #pragma unroll
    for (int ks = 0; ks < KS; ks++) {
        #pragma unroll
        for (int c = 0; c < 4; c++) {
            bf16x8 wv = *(const bf16x8*)(w0 + c * 16 * KS * 32 + ks * 32);
            acc[c] = __builtin_amdgcn_mfma_f32_16x16x32_bf16(wv, afr[ks], acc[c], 0, 0, 0);
        }
    }
    #pragma unroll
    for (int c = 0; c < 4; c++) {
        f32x4 b4 = *(const f32x4*)(bias + cq * 64 + c * 16 + g * 4);
        uint2 s;
        s.x = cvt2(fmaxf(acc[c][0] + b4[0], 0.f), fmaxf(acc[c][1] + b4[1], 0.f));
        s.y = cvt2(fmaxf(acc[c][2] + b4[2], 0.f), fmaxf(acc[c][3] + b4[3], 0.f));
        *(uint2*)(actout + (size_t)(nt * 16 + r) * outs + cq * 64 + c * 16 + g * 4) = s;
    }
}

// last node layer (4 co-tiles/wave) + global max over nodes
template<int KS, int CTQ>
__global__ __launch_bounds__(256, 2) void nlayer_max4(const unsigned short* __restrict__ W,
        const float* __restrict__ bias, const unsigned short* __restrict__ actin,
        float* __restrict__ out) {
    int wave = threadIdx.x >> 6, lane = threadIdx.x & 63;
    int id = blockIdx.x * 4 + wave;
    int nt = id / CTQ, cq = id - nt * CTQ;
    int r = lane & 15, g = lane >> 4;
    const unsigned short* arow = actin + (size_t)(nt * 16 + r) * (KS * 32) + g * 8;
    bf16x8 afr[KS];
    #pragma unroll
    for (int ks = 0; ks < KS; ks++) afr[ks] = *(const bf16x8*)(arow + ks * 32);
    const unsigned short* w0 = W + (cq * 64 + r) * (KS * 32) + g * 8;
    f32x4 acc[4];
    #pragma unroll
    for (int c = 0; c < 4; c++) acc[c] = (f32x4){0.f, 0.f, 0.f, 0.f};
    #pragma unroll
    for (int ks = 0; ks < KS; ks++) {
        #pragma unroll
        for (int c = 0; c < 4; c++) {
            bf16x8 wv = *(const bf16x8*)(w0 + c * 16 * KS * 32 + ks * 32);
            acc[c] = __builtin_amdgcn_mfma_f32_16x16x32_bf16(wv, afr[ks], acc[c], 0, 0, 0);
        }
    }
    int b = nt >> 4;
    #pragma unroll
    for (int c = 0; c < 4; c++) {
        f32x4 b4 = *(const f32x4*)(bias + cq * 64 + c * 16 + g * 4);
        #pragma unroll
        for (int i = 0; i < 4; i++) {
            float v = fmaxf(acc[c][i] + b4[i], 0.f);
            v = fmaxf(v, __shfl_xor(v, 1));
            v = fmaxf(v, __shfl_xor(v, 2));
            v = fmaxf(v, __shfl_xor(v, 4));
            v = fmaxf(v, __shfl_xor(v, 8));
            if (r == 0)
                atomicMax((int*)&out[b * 1024 + cq * 64 + c * 16 + g * 4 + i],
                          __float_as_int(v));
        }
    }
}

extern "C" void kernel_launch(void* const* d_in, const int* in_sizes, int n_in,
                              void* d_out, int out_size, void* d_ws, size_t ws_size,
                              hipStream_t stream) {
    (void)in_sizes; (void)n_in; (void)out_size; (void)ws_size;
    const float* x    = (const float*)d_in[0];
    const float* node = (const float*)d_in[2];
    const float* fpw[4] = {(const float*)d_in[4], (const float*)d_in[6],
                           (const float*)d_in[8], (const float*)d_in[10]};
    const float* fpb[4] = {(const float*)d_in[5], (const float*)d_in[7],
                           (const float*)d_in[9], (const float*)d_in[11]};
    const float* fnw[4] = {(const float*)d_in[12], (const float*)d_in[14],
                           (const float*)d_in[16], (const float*)d_in[18]};
    const float* fnb[4] = {(const float*)d_in[13], (const float*)d_in[15],
                           (const float*)d_in[17], (const float*)d_in[19]};
    float* ws  = (float*)d_ws;
    float* out = (float*)d_out;
    unsigned short* wb   = (unsigned short*)(ws + OFF_WBF);
    unsigned short* fin2 = (unsigned short*)(ws + OFF_FIN2);
    unsigned short* h0   = (unsigned short*)(ws + OFF_H0);
    unsigned short* h1   = (unsigned short*)(ws + OFF_H1);
    unsigned short* catb = (unsigned short*)(ws + OFF_CAT);

    hipMemsetAsync(ws, 0, (size_t)ZERO_COUNT * 4, stream);
    hipMemsetAsync(out, 0, (size_t)B_ * 1024 * 4, stream);

    knn_setup<<<128 + 2048, 256, 0, stream>>>(
        x, node, (int*)(ws + OFF_KNN), ws + OFF_COUNTS, ws + OFF_SUMS,
        fpw[0], fpw[1], fpw[2], fpw[3], fnw[0], fnw[1], fnw[2], fnw[3],
        wb, ws + OFF_W3X);
    cmean_scan<<<B_, 256, 0, stream>>>(
        ws + OFF_COUNTS, ws + OFF_SUMS, ws + OFF_CM, (int*)(ws + OFF_OFFS));
    scatter<<<B_ * KNN_ * N_ / 256, 256, 0, stream>>>(
        (int*)(ws + OFF_KNN), (int*)(ws + OFF_OFFS), (int*)(ws + OFF_CURSOR),
        (int*)(ws + OFF_SORTED), (int*)(ws + OFF_MSORT));
    mlp1m<<<dim3(KNN_ * N_ / 64, B_), 256, 0, stream>>>(
        x, ws + OFF_CM, (int*)(ws + OFF_SORTED), (int*)(ws + OFF_MSORT), wb,
        (const float4*)(ws + OFF_W3X),
        fpb[0], fpb[1], fpb[2], fpb[3], ws + OFF_NODEMAX, ws + OFF_FIRST0);
    build_fin2<<<3328, 256, 0, stream>>>(
        ws + OFF_CM, ws + OFF_COUNTS, ws + OFF_NODEMAX, ws + OFF_FIRST0, fin2, catb);
    nlayer4<13, 8><<<256,  256, 0, stream>>>(wb + O_V0, fnb[0], fin2, h0, 512);
    nlayer4<16, 8><<<256,  256, 0, stream>>>(wb + O_V1, fnb[1], h0, h1, 512);
    nlayer4<16, 12><<<384, 256, 0, stream>>>(wb + O_V2, fnb[2], h1, catb, 1184);
    nlayer_max4<37, 16><<<512, 256, 0, stream>>>(wb + O_V3, fnb[3], catb, out);
}

// Round 9
// 193.847 us; speedup vs baseline: 5.6801x; 1.0035x over previous
//
#include <hip/hip_runtime.h>
#include <math.h>

#define B_   8
#define N_   4096
#define M_   256
#define KNN_ 3

// ---- workspace layout (float element offsets) ----
#define OFF_COUNTS   0          // [8][256] f32
#define OFF_SUMS     2048       // [8][256][3] f32
#define OFF_CM       8192       // [8][3][256] f32
#define OFF_NODEMAX  14336      // [8][256][384] f32 ; H0 aliases (phase2)
#define OFF_H0       14336      // ushort [2048][512]
#define OFF_FIRST0   800768     // [8][384] f32
#define OFF_CURSOR   803840     // [8][256] int
#define ZERO_COUNT   805888     // memset range (floats)
#define OFF_OFFS     805888     // [8][257] int
#define OFF_KNN      807944     // [8][4096][3] int ; CAT aliases (phase2)
#define OFF_CAT      807944     // ushort [2048][1184]
#define OFF_SORTED   906248     // [8][12288] int
#define OFF_MSORT    1004552    // [8][12288] int
#define OFF_FIN2     2020360    // ushort [2048][416] ; H1 aliases
#define OFF_H1       2020360    // ushort [2048][512]
#define OFF_WBF      2544648    // bf16 weights (ushort)
#define OFF_W3X      3661832    // f32x4 [384] (W3 cols 256..258)
// bf16 padded weight offsets (USHORT units, relative to wb base; contiguous)
#define O_W0 0         // 64   x 32
#define O_W1 2048      // 128  x 64
#define O_W2 10240     // 256  x 128
#define O_W3 43008     // 384  x 288
#define O_V0 153600    // 512  x 416
#define O_V1 366592    // 512  x 512
#define O_V2 628736    // 768  x 512
#define O_V3 1021952   // 1024 x 1184
#define W_TOTAL 2234368

typedef short  bf16x8 __attribute__((ext_vector_type(8)));
typedef float  f32x4  __attribute__((ext_vector_type(4)));
typedef float  f32x16 __attribute__((ext_vector_type(16)));

__device__ __forceinline__ unsigned short f2b(float f) {
    unsigned u = __float_as_uint(f);
    return (unsigned short)((u + 0x7FFFu + ((u >> 16) & 1u)) >> 16);
}
// HW packed bf16 convert (RNE), 2 f32 -> 1 dword
__device__ __forceinline__ unsigned cvt2(float lo, float hi) {
    unsigned r;
    asm("v_cvt_pk_bf16_f32 %0, %1, %2" : "=v"(r) : "v"(lo), "v"(hi));
    return r;
}
__device__ __forceinline__ f32x16 zero16() {
    f32x16 z;
    #pragma unroll
    for (int i = 0; i < 16; i++) z[i] = 0.f;
    return z;
}

// fused: blocks 0..127 = KNN assign; blocks 128+ = weight pad/convert + w3x
__global__ __launch_bounds__(256) void knn_setup(
        const float* __restrict__ x, const float* __restrict__ node,
        int* __restrict__ knn, float* __restrict__ counts, float* __restrict__ sums,
        const float* s0, const float* s1, const float* s2, const float* s3,
        const float* s4, const float* s5, const float* s6, const float* s7,
        unsigned short* __restrict__ dst, float* __restrict__ w3x) {
    __shared__ float nd0[M_], nd1[M_], nd2[M_], nn2[M_];
    int t = threadIdx.x;
    if (blockIdx.x < 128) {
        int b = blockIdx.x >> 4, xblk = blockIdx.x & 15;
        {
            float c0 = node[(b * 3 + 0) * M_ + t];
            float c1 = node[(b * 3 + 1) * M_ + t];
            float c2 = node[(b * 3 + 2) * M_ + t];
            nd0[t] = c0; nd1[t] = c1; nd2[t] = c2;
            nn2[t] = c0 * c0 + c1 * c1 + c2 * c2;
        }
        __syncthreads();
        int n = xblk * 256 + t;
        float x0 = x[(b * 3 + 0) * N_ + n];
        float x1 = x[(b * 3 + 1) * N_ + n];
        float x2 = x[(b * 3 + 2) * N_ + n];
        float xx = x0 * x0 + x1 * x1 + x2 * x2;
        float d0 = 1e30f, d1 = 1e30f, d2b = 1e30f;
        int i0 = 0, i1 = 0, i2 = 0;
        for (int m = 0; m < M_; m++) {
            float cross = x0 * nd0[m] + x1 * nd1[m] + x2 * nd2[m];
            float d = xx + nn2[m] - 2.f * cross;
            bool c0 = d < d0, c1 = d < d1, c2 = d < d2b;
            d2b = c1 ? d1 : (c2 ? d : d2b);
            i2  = c1 ? i1 : (c2 ? m : i2);
            d1  = c0 ? d0 : (c1 ? d : d1);
            i1  = c0 ? i0 : (c1 ? m : i1);
            d0  = c0 ? d  : d0;
            i0  = c0 ? m  : i0;
        }
        int base = (b * N_ + n) * 3;
        knn[base + 0] = i0; knn[base + 1] = i1; knn[base + 2] = i2;
        int mm[3] = {i0, i1, i2};
        #pragma unroll
        for (int k = 0; k < 3; k++) {
            int m = mm[k];
            atomicAdd(&counts[b * M_ + m], 1.f);
            atomicAdd(&sums[(b * M_ + m) * 3 + 0], x0);
            atomicAdd(&sums[(b * M_ + m) * 3 + 1], x1);
            atomicAdd(&sums[(b * M_ + m) * 3 + 2], x2);
        }
    } else {
        int i = (blockIdx.x - 128) * 256 + t;
        int st = (gridDim.x - 128) * 256;
        for (int j = i; j < 1536; j += st) {
            int ch = j >> 2, c = j & 3;
            w3x[j] = (c < 3) ? s3[ch * 259 + 256 + c] : 0.f;
        }
        for (; i < W_TOTAL; i += st) {
            const float* src; int base, cin, cinp;
            if      (i < O_W1) { src = s0; base = O_W0; cin = 3;    cinp = 32; }
            else if (i < O_W2) { src = s1; base = O_W1; cin = 64;   cinp = 64; }
            else if (i < O_W3) { src = s2; base = O_W2; cin = 128;  cinp = 128; }
            else if (i < O_V0) { src = s3; base = O_W3; cin = 259;  cinp = 288; }
            else if (i < O_V1) { src = s4; base = O_V0; cin = 387;  cinp = 416; }
            else if (i < O_V2) { src = s5; base = O_V1; cin = 512;  cinp = 512; }
            else if (i < O_V3) { src = s6; base = O_V2; cin = 512;  cinp = 512; }
            else               { src = s7; base = O_V3; cin = 1155; cinp = 1184; }
            int loc = i - base;
            int co = loc / cinp, k = loc - co * cinp;
            dst[i] = (k < cin) ? f2b(src[co * cin + k]) : (unsigned short)0;
        }
    }
}

// cluster means + exclusive scan of counts, one block per batch
__global__ __launch_bounds__(256) void cmean_scan(const float* __restrict__ counts,
        const float* __restrict__ sums, float* __restrict__ cm, int* __restrict__ offs) {
    __shared__ int tmp[256];
    int t = threadIdx.x, b = blockIdx.x;
    float cnt = counts[b * M_ + t];
    float inv = 1.f / (cnt + 1e-5f);
    #pragma unroll
    for (int c = 0; c < 3; c++)
        cm[(b * 3 + c) * M_ + t] = sums[(b * M_ + t) * 3 + c] * inv;
    int v = (int)cnt;
    tmp[t] = v;
    __syncthreads();
    for (int off = 1; off < 256; off <<= 1) {
        int u = (t >= off) ? tmp[t - off] : 0;
        __syncthreads();
        tmp[t] += u;
        __syncthreads();
    }
    offs[b * 257 + t] = tmp[t] - v;
    if (t == 255) offs[b * 257 + 256] = tmp[255];
}

__global__ __launch_bounds__(256) void scatter(const int* __restrict__ knn,
        const int* __restrict__ offs, int* __restrict__ cursor,
        int* __restrict__ sorted, int* __restrict__ msort) {
    int g = blockIdx.x * 256 + threadIdx.x;
    int b = g / (KNN_ * N_), j = g % (KNN_ * N_);
    int n = j & (N_ - 1), k = j >> 12;
    int m = knn[(b * N_ + n) * 3 + k];
    int pos = atomicAdd(&cursor[b * M_ + m], 1);
    int dst = offs[b * 257 + m] + pos;
    sorted[b * (KNN_ * N_) + dst] = j;
    msort[b * (KNN_ * N_) + dst] = m;
}

// B-stationary layer: wave holds B-frags for ALL 4 p-tiles in regs,
// owns CTW co-tiles, streams W. 4 independent MFMA chains.
template<int KS, int INS, int OUTS, int CTW>
__device__ __forceinline__ void layerB(const unsigned short* __restrict__ Wg,
        const float* __restrict__ bias, const unsigned short* actin,
        unsigned short* actout, int wave, int lane) {
    int r = lane & 15, g = lane >> 4;
    bf16x8 bfr[4][KS];
    #pragma unroll
    for (int pt = 0; pt < 4; pt++) {
        const unsigned short* arow = actin + (pt * 16 + r) * INS + g * 8;
        #pragma unroll
        for (int ks = 0; ks < KS; ks++)
            bfr[pt][ks] = *(const bf16x8*)(arow + ks * 32);
    }
    #pragma unroll
    for (int c = 0; c < CTW; c++) {
        int ct = wave * CTW + c;
        const unsigned short* wrow = Wg + (ct * 16 + r) * (KS * 32) + g * 8;
        f32x4 acc[4];
        #pragma unroll
        for (int pt = 0; pt < 4; pt++) acc[pt] = (f32x4){0.f, 0.f, 0.f, 0.f};
        #pragma unroll
        for (int ks = 0; ks < KS; ks++) {
            bf16x8 wv = *(const bf16x8*)(wrow + ks * 32);
            #pragma unroll
            for (int pt = 0; pt < 4; pt++)
                acc[pt] = __builtin_amdgcn_mfma_f32_16x16x32_bf16(wv, bfr[pt][ks], acc[pt], 0, 0, 0);
        }
        f32x4 b4 = *(const f32x4*)(bias + ct * 16 + g * 4);
        #pragma unroll
        for (int pt = 0; pt < 4; pt++) {
            uint2 s;
            s.x = cvt2(fmaxf(acc[pt][0] + b4[0], 0.f), fmaxf(acc[pt][1] + b4[1], 0.f));
            s.y = cvt2(fmaxf(acc[pt][2] + b4[2], 0.f), fmaxf(acc[pt][3] + b4[3], 0.f));
            *(uint2*)(actout + (pt * 16 + r) * OUTS + ct * 16 + g * 4) = s;
        }
    }
}

// MFMA point-MLP over sorted entries, 64 points/block, ~52.5 KB LDS (3 blocks/CU).
// L4: swapped-operand 32x32x16 MFMA (A=acts, B=W3): D col=channel, row=point.
// xd contribution (3 of K) via VALU from xdf + w3x. Seg-max in-register per lane.
__global__ __launch_bounds__(256, 3) void mlp1m(
        const float* __restrict__ x, const float* __restrict__ cm,
        const int* __restrict__ sorted, const int* __restrict__ msort,
        const unsigned short* __restrict__ wb, const float4* __restrict__ w3x,
        const float* __restrict__ bb0, const float* __restrict__ bb1,
        const float* __restrict__ bb2, const float* __restrict__ bb3,
        float* __restrict__ node_max, float* __restrict__ first0) {
    __shared__ __align__(16) char smem[50688];
    // arena A (0..16896): inb [64][40] -> a1 [64][132]
    // arena B (16896..50688): a0 [64][72] -> cat [64][264]
    unsigned short* inb = (unsigned short*)smem;
    unsigned short* a1  = (unsigned short*)smem;
    unsigned short* a0  = (unsigned short*)(smem + 16896);
    unsigned short* cat = (unsigned short*)(smem + 16896);
    __shared__ float4 xdf[64];
    __shared__ int segm[65], segstart[66];
    __shared__ int nseg, p0loc;
    int t = threadIdx.x, b = blockIdx.y, lane = t & 63, wave = t >> 6;
    int e0 = blockIdx.x * 64;
    for (int e = t; e < 1280; e += 256) ((unsigned*)inb)[e] = 0u;   // zero inb [64][40]
    __syncthreads();
    if (t < 64) {   // wave 0: per-point init + ballot segment scan
        int p = t;
        if (p == 0) p0loc = -1;
        int j = sorted[b * 12288 + e0 + p];
        int m = msort[b * 12288 + e0 + p];
        int n = j & (N_ - 1);
        float xd0 = x[(b * 3 + 0) * N_ + n] - cm[(b * 3 + 0) * M_ + m];
        float xd1 = x[(b * 3 + 1) * N_ + n] - cm[(b * 3 + 1) * M_ + m];
        float xd2 = x[(b * 3 + 2) * N_ + n] - cm[(b * 3 + 2) * M_ + m];
        xdf[p] = make_float4(xd0, xd1, xd2, 0.f);
        inb[p * 40 + 0] = f2b(xd0);
        inb[p * 40 + 1] = f2b(xd1);
        inb[p * 40 + 2] = f2b(xd2);
        int prev = __shfl_up(m, 1);
        bool flag = (p == 0) || (m != prev);
        unsigned long long mk = __ballot(flag);
        int sid = __popcll(mk & ((1ull << p) - 1ull));
        if (flag) { segstart[sid] = p; segm[sid] = m; }
        if (p == 63) { int ns2 = __popcll(mk); nseg = ns2; segstart[ns2] = 64; }
        if (j == 0) p0loc = p;
    }
    __syncthreads();
    layerB<1, 40, 72, 1>(wb + O_W0, bb0, inb, a0, wave, lane);     // inb -> a0
    __syncthreads();
    layerB<2, 72, 132, 2>(wb + O_W1, bb1, a0, a1, wave, lane);     // a0 -> a1 (over inb)
    __syncthreads();
    layerB<4, 132, 264, 4>(wb + O_W2, bb2, a1, cat, wave, lane);   // a1 -> cat (over a0)
    __syncthreads();
    // ---- L4: 12 co-tiles of 32 x 4 waves (3 each), 2 point-halves, K=256 ----
    int l31 = lane & 31, half = lane >> 5;
    f32x16 acc[6];   // [c3*2 + ph]
    #pragma unroll
    for (int q = 0; q < 6; q++) acc[q] = zero16();
    {
        const unsigned short* arow0 = cat + l31 * 264 + half * 8;
        const unsigned short* arow1 = cat + (32 + l31) * 264 + half * 8;
        const unsigned short* wrowb = wb + O_W3 + (wave * 96 + l31) * 288 + half * 8;
        #pragma unroll
        for (int ks = 0; ks < 16; ks++) {
            bf16x8 aA = *(const bf16x8*)(arow0 + ks * 16);
            bf16x8 aB = *(const bf16x8*)(arow1 + ks * 16);
            #pragma unroll
            for (int c3 = 0; c3 < 3; c3++) {
                bf16x8 wv = *(const bf16x8*)(wrowb + c3 * 32 * 288 + ks * 16);
                acc[c3 * 2 + 0] = __builtin_amdgcn_mfma_f32_32x32x16_bf16(aA, wv, acc[c3 * 2 + 0], 0, 0, 0);
                acc[c3 * 2 + 1] = __builtin_amdgcn_mfma_f32_32x32x16_bf16(aB, wv, acc[c3 * 2 + 1], 0, 0, 0);
            }
        }
    }
    int ns = nseg, p0l = p0loc;
    float bias3[3]; float4 wx3[3];
    #pragma unroll
    for (int c3 = 0; c3 < 3; c3++) {
        bias3[c3] = bb3[(wave * 3 + c3) * 32 + l31];
        wx3[c3]   = w3x[(wave * 3 + c3) * 32 + l31];
    }
    // bias + xd-contrib + ReLU, in place
    #pragma unroll
    for (int ph = 0; ph < 2; ph++) {
        #pragma unroll
        for (int rg = 0; rg < 16; rg++) {
            int row = ph * 32 + (rg & 3) + 8 * (rg >> 2) + 4 * half;
            float4 xv = xdf[row];
            #pragma unroll
            for (int c3 = 0; c3 < 3; c3++) {
                float s = acc[c3 * 2 + ph][rg] + bias3[c3]
                        + wx3[c3].x * xv.x + wx3[c3].y * xv.y + wx3[c3].z * xv.z;
                acc[c3 * 2 + ph][rg] = fmaxf(s, 0.f);
            }
        }
    }
    if (p0l >= 0) {   // first-point channel values (one block per batch)
        #pragma unroll
        for (int ph = 0; ph < 2; ph++)
            #pragma unroll
            for (int rg = 0; rg < 16; rg++) {
                int row = ph * 32 + (rg & 3) + 8 * (rg >> 2) + 4 * half;
                if (row == p0l) {
                    #pragma unroll
                    for (int c3 = 0; c3 < 3; c3++)
                        first0[b * 384 + (wave * 3 + c3) * 32 + l31] = acc[c3 * 2 + ph][rg];
                }
            }
    }
    for (int s = 0; s < ns; s++) {
        int s0 = segstart[s], s1 = segstart[s + 1];
        float m0 = 0.f, m1 = 0.f, m2 = 0.f;
        if (s0 < 32) {
            #pragma unroll
            for (int rg = 0; rg < 16; rg++) {
                int row = (rg & 3) + 8 * (rg >> 2) + 4 * half;
                bool in = (row >= s0) && (row < s1);
                m0 = fmaxf(m0, in ? acc[0][rg] : 0.f);
                m1 = fmaxf(m1, in ? acc[2][rg] : 0.f);
                m2 = fmaxf(m2, in ? acc[4][rg] : 0.f);
            }
        }
        if (s1 > 32) {
            #pragma unroll
            for (int rg = 0; rg < 16; rg++) {
                int row = 32 + (rg & 3) + 8 * (rg >> 2) + 4 * half;
                bool in = (row >= s0) && (row < s1);
                m0 = fmaxf(m0, in ? acc[1][rg] : 0.f);
                m1 = fmaxf(m1, in ? acc[3][rg] : 0.f);
                m2 = fmaxf(m2, in ? acc[5][rg] : 0.f);
            }
        }
        m0 = fmaxf(m0, __shfl_xor(m0, 32));
        m1 = fmaxf(m1, __shfl_xor(m1, 32));
        m2 = fmaxf(m2, __shfl_xor(m2, 32));
        if (lane < 32) {
            float* dstp = &node_max[(size_t)(b * M_ + segm[s]) * 384 + wave * 96];
            atomicMax((int*)(dstp + l31),      __float_as_int(m0));
            atomicMax((int*)(dstp + 32 + l31), __float_as_int(m1));
            atomicMax((int*)(dstp + 64 + l31), __float_as_int(m2));
        }
    }
}

// masked node features -> bf16 fin2 [2048][416] and cat tail cols 768..1183
__global__ void build_fin2(const float* __restrict__ cm, const float* __restrict__ counts,
                           const float* __restrict__ nmax, const float* __restrict__ first0,
                           unsigned short* __restrict__ fin2, unsigned short* __restrict__ cat) {
    int tot = 2048 * 416;
    int i = blockIdx.x * blockDim.x + threadIdx.x;
    int st = gridDim.x * blockDim.x;
    for (; i < tot; i += st) {
        int n = i / 416, ch = i - n * 416;
        int b = n >> 8, m = n & 255;
        float v = 0.f;
        if (ch < 3) v = cm[(b * 3 + ch) * M_ + m];
        else if (ch < 387)
            v = (counts[n] > 0.f) ? nmax[(size_t)n * 384 + (ch - 3)]
                                  : first0[b * 384 + (ch - 3)];
        unsigned short u = f2b(v);
        fin2[n * 416 + ch] = u;
        cat[(size_t)n * 1184 + 768 + ch] = u;
    }
}

// node-MLP layer: one wave = 4 co-tiles sharing one act-frag set (4 indep chains)
template<int KS, int CTQ>
__global__ __launch_bounds__(256, 2) void nlayer4(const unsigned short* __restrict__ W,
        const float* __restrict__ bias, const unsigned short* __restrict__ actin,
        unsigned short* __restrict__ actout, int outs) {
    int wave = threadIdx.x >> 6, lane = threadIdx.x & 63;
    int id = blockIdx.x * 4 + wave;
    int nt = id / CTQ, cq = id - nt * CTQ;
    int r = lane & 15, g = lane >> 4;
    const unsigned short* arow = actin + (size_t)(nt * 16 + r) * (KS * 32) + g * 8;
    bf16x8 afr[KS];
    #pragma unroll
    for (int ks = 0; ks < KS; ks++) afr[ks] = *(const bf16x8*)(arow + ks * 32);
    const unsigned short* w0 = W + (cq * 64 + r) * (KS * 32) + g * 8;
    f32x4 acc[4];
    #pragma unroll
    for (int c = 0; c < 4; c++) acc[c] = (f32x4){0.f, 0.f, 0.f, 0.f};
    #pragma unroll
    for (int ks = 0; ks < KS; ks++) {
        #pragma unroll
        for (int c = 0; c < 4; c++) {
            bf16x8 wv = *(const bf16x8*)(w0 + c * 16 * KS * 32 + ks * 32);
            acc[c] = __builtin_amdgcn_mfma_f32_16x16x32_bf16(wv, afr[ks], acc[c], 0, 0, 0);
        }
    }
    #pragma unroll
    for (int c = 0; c < 4; c++) {
        f32x4 b4 = *(const f32x4*)(bias + cq * 64 + c * 16 + g * 4);
        uint2 s;
        s.x = cvt2(fmaxf(acc[c][0] + b4[0], 0.f), fmaxf(acc[c][1] + b4[1], 0.f));
        s.y = cvt2(fmaxf(acc[c][2] + b4[2], 0.f), fmaxf(acc[c][3] + b4[3], 0.f));
        *(uint2*)(actout + (size_t)(nt * 16 + r) * outs + cq * 64 + c * 16 + g * 4) = s;
    }
}

// last node layer, STREAMING (no act residency -> no spill):
// wave = 16 nodes x 32 couts (2 chains), K=1184 streamed; + global max over nodes
__global__ __launch_bounds__(256) void nlayer_max_s(const unsigned short* __restrict__ W,
        const float* __restrict__ bias, const unsigned short* __restrict__ actin,
        float* __restrict__ out) {
    int wave = threadIdx.x >> 6, lane = threadIdx.x & 63;
    int id = blockIdx.x * 4 + wave;          // 4096 waves
    int nt = id >> 5, cp = id & 31;          // nt: 0..127 (16 nodes), cp: 0..31 (32 couts)
    int r = lane & 15, g = lane >> 4;
    const unsigned short* arow = actin + (size_t)(nt * 16 + r) * 1184 + g * 8;
    const unsigned short* w0 = W + (size_t)(cp * 32 + r) * 1184 + g * 8;
    const unsigned short* w1 = w0 + 16 * 1184;
    f32x4 a0 = {0.f, 0.f, 0.f, 0.f}, a1 = {0.f, 0.f, 0.f, 0.f};
    #pragma unroll 4
    for (int ks = 0; ks < 37; ks++) {
        bf16x8 av = *(const bf16x8*)(arow + ks * 32);
        a0 = __builtin_amdgcn_mfma_f32_16x16x32_bf16(*(const bf16x8*)(w0 + ks * 32), av, a0, 0, 0, 0);
        a1 = __builtin_amdgcn_mfma_f32_16x16x32_bf16(*(const bf16x8*)(w1 + ks * 32), av, a1, 0, 0, 0);
    }
    int b = nt >> 4;
    #pragma unroll
    for (int c = 0; c < 2; c++) {
        f32x4 acc = c ? a1 : a0;
        f32x4 b4 = *(const f32x4*)(bias + cp * 32 + c * 16 + g * 4);
        #pragma unroll
        for (int i = 0; i < 4; i++) {
            float v = fmaxf(acc[i] + b4[i], 0.f);
            v = fmaxf(v, __shfl_xor(v, 1));
            v = fmaxf(v, __shfl_xor(v, 2));
            v = fmaxf(v, __shfl_xor(v, 4));
            v = fmaxf(v, __shfl_xor(v, 8));
            if (r == 0)
                atomicMax((int*)&out[b * 1024 + cp * 32 + c * 16 + g * 4 + i],
                          __float_as_int(v));
        }
    }
}

extern "C" void kernel_launch(void* const* d_in, const int* in_sizes, int n_in,
                              void* d_out, int out_size, void* d_ws, size_t ws_size,
                              hipStream_t stream) {
    (void)in_sizes; (void)n_in; (void)out_size; (void)ws_size;
    const float* x    = (const float*)d_in[0];
    const float* node = (const float*)d_in[2];
    const float* fpw[4] = {(const float*)d_in[4], (const float*)d_in[6],
                           (const float*)d_in[8], (const float*)d_in[10]};
    const float* fpb[4] = {(const float*)d_in[5], (const float*)d_in[7],
                           (const float*)d_in[9], (const float*)d_in[11]};
    const float* fnw[4] = {(const float*)d_in[12], (const float*)d_in[14],
                           (const float*)d_in[16], (const float*)d_in[18]};
    const float* fnb[4] = {(const float*)d_in[13], (const float*)d_in[15],
                           (const float*)d_in[17], (const float*)d_in[19]};
    float* ws  = (float*)d_ws;
    float* out = (float*)d_out;
    unsigned short* wb   = (unsigned short*)(ws + OFF_WBF);
    unsigned short* fin2 = (unsigned short*)(ws + OFF_FIN2);
    unsigned short* h0   = (unsigned short*)(ws + OFF_H0);
    unsigned short* h1   = (unsigned short*)(ws + OFF_H1);
    unsigned short* catb = (unsigned short*)(ws + OFF_CAT);

    hipMemsetAsync(ws, 0, (size_t)ZERO_COUNT * 4, stream);
    hipMemsetAsync(out, 0, (size_t)B_ * 1024 * 4, stream);

    knn_setup<<<128 + 2048, 256, 0, stream>>>(
        x, node, (int*)(ws + OFF_KNN), ws + OFF_COUNTS, ws + OFF_SUMS,
        fpw[0], fpw[1], fpw[2], fpw[3], fnw[0], fnw[1], fnw[2], fnw[3],
        wb, ws + OFF_W3X);
    cmean_scan<<<B_, 256, 0, stream>>>(
        ws + OFF_COUNTS, ws + OFF_SUMS, ws + OFF_CM, (int*)(ws + OFF_OFFS));
    scatter<<<B_ * KNN_ * N_ / 256, 256, 0, stream>>>(
        (int*)(ws + OFF_KNN), (int*)(ws + OFF_OFFS), (int*)(ws + OFF_CURSOR),
        (int*)(ws + OFF_SORTED), (int*)(ws + OFF_MSORT));
    mlp1m<<<dim3(KNN_ * N_ / 64, B_), 256, 0, stream>>>(
        x, ws + OFF_CM, (int*)(ws + OFF_SORTED), (int*)(ws + OFF_MSORT), wb,
        (const float4*)(ws + OFF_W3X),
        fpb[0], fpb[1], fpb[2], fpb[3], ws + OFF_NODEMAX, ws + OFF_FIRST0);
    build_fin2<<<3328, 256, 0, stream>>>(
        ws + OFF_CM, ws + OFF_COUNTS, ws + OFF_NODEMAX, ws + OFF_FIRST0, fin2, catb);
    nlayer4<13, 8><<<256,  256, 0, stream>>>(wb + O_V0, fnb[0], fin2, h0, 512);
    nlayer4<16, 8><<<256,  256, 0, stream>>>(wb + O_V1, fnb[1], h0, h1, 512);
    nlayer4<16, 12><<<384, 256, 0, stream>>>(wb + O_V2, fnb[2], h1, catb, 1184);
    nlayer_max_s<<<1024, 256, 0, stream>>>(wb + O_V3, fnb[3], catb, out);
}